// Round 18
// baseline (711.775 us; speedup 1.0000x reference)
//
#include <hip/hip_runtime.h>
#include <math.h>
#include <float.h>

#define B_ 64
#define N_ 197
#define C_ 768
#define H_ 12
#define CH_ 64
#define RC_ 32
#define RN_ 24

typedef __attribute__((ext_vector_type(8))) short short8;
typedef __attribute__((ext_vector_type(4))) float f32x4;
typedef __attribute__((address_space(3))) void  lds_void;
typedef __attribute__((address_space(1))) const void g_void;

__device__ __forceinline__ float warp_sum(float v){
  #pragma unroll
  for(int o=32;o>=1;o>>=1) v += __shfl_xor(v,o);
  return v;
}
__device__ __forceinline__ float warp_max(float v){
  #pragma unroll
  for(int o=32;o>=1;o>>=1) v = fmaxf(v,__shfl_xor(v,o));
  return v;
}
__device__ __forceinline__ unsigned short f2bf(float f){
  union{float f; unsigned u;} c; c.f = f;
  unsigned r = c.u + 0x7FFF + ((c.u>>16)&1);
  return (unsigned short)(r>>16);
}
__device__ __forceinline__ float bf2f(unsigned short u){
  union{unsigned u; float f;} c; c.u = ((unsigned)u)<<16; return c.f;
}
// bijective XCD-aware block swizzle (m204)
__device__ __forceinline__ int2 xcd_swz(int gx, int gy){
  int nwg = gx*gy;
  int id = blockIdx.x + gx*blockIdx.y;
  int xcd = id & 7, loc = id >> 3;
  int q = nwg >> 3, r = nwg & 7;
  int swz = (xcd < r ? xcd*(q+1) : r*(q+1) + (xcd-r)*q) + loc;
  return make_int2(swz % gx, swz / gx);
}

// ---------------- LayerNorm: one block per row of 768, bf16 out ----------------
__global__ __launch_bounds__(256) void ln_kernel(const float* __restrict__ x,
    const float* __restrict__ g, const float* __restrict__ bb, unsigned short* __restrict__ out){
  int r = blockIdx.x; int tid = threadIdx.x;
  const float* xr = x + (size_t)r*C_;
  float v0=xr[tid], v1=xr[tid+256], v2=xr[tid+512];
  __shared__ float red[8];
  float s = warp_sum(v0+v1+v2);
  if((tid&63)==0) red[tid>>6]=s;
  __syncthreads();
  float mu = (red[0]+red[1]+red[2]+red[3]) * (1.f/768.f);
  float d0=v0-mu,d1=v1-mu,d2=v2-mu;
  float s2 = warp_sum(d0*d0+d1*d1+d2*d2);
  if((tid&63)==0) red[4+(tid>>6)]=s2;
  __syncthreads();
  float rinv = rsqrtf((red[4]+red[5]+red[6]+red[7])*(1.f/768.f)+1e-5f);
  unsigned short* orow = out + (size_t)r*C_;
  orow[tid]     = f2bf(d0*rinv*g[tid]    +bb[tid]);
  orow[tid+256] = f2bf(d1*rinv*g[tid+256]+bb[tid+256]);
  orow[tid+512] = f2bf(d2*rinv*g[tid+512]+bb[tid+512]);
}

// ---------------- transpose+convert: in f32 [K][N] -> out bf16 [N][K] ----------------
__global__ __launch_bounds__(256) void wtrans_kernel(const float* __restrict__ in,
    unsigned short* __restrict__ out, int K, int N){
  __shared__ float tile[32][33];
  int n0 = blockIdx.x*32, k0 = blockIdx.y*32;
  int tx = threadIdx.x&31, ty = threadIdx.x>>5;
  #pragma unroll
  for(int i=0;i<4;++i) tile[ty+8*i][tx] = in[(size_t)(k0+ty+8*i)*N + n0+tx];
  __syncthreads();
  #pragma unroll
  for(int i=0;i<4;++i) out[(size_t)(n0+ty+8*i)*K + k0+tx] = f2bf(tile[tx][ty+8*i]);
}

// ---------------- Wcq/Wck f32[64][32] -> bf16 transposed [32][64] ----------------
__global__ __launch_bounds__(256) void wcprep_kernel(const float* __restrict__ Wcq,
    const float* __restrict__ Wck, unsigned short* __restrict__ WcqT,
    unsigned short* __restrict__ WckT){
  int t = blockIdx.x*256 + threadIdx.x;
  if(t < 2048){
    int c = t>>6, k = t&63;
    WcqT[t] = f2bf(Wcq[k*32+c]);
    WckT[t] = f2bf(Wck[k*32+c]);
  }
}

// ---------------- bf16 MFMA GEMM 128x128, BK=64, dbuf, chunk-XOR swizzle + XCD swz ----------------
// Round-13-validated (row&7)-XOR layout: inverse-swizzled global src, linear
// gload_lds dest, swizzled frag reads -> conflict-free. Half the barriers of BK=32.
// K-chunk accumulation order unchanged (ascending 32-steps) -> bit-identical.
template<int ACT, int RESID, int OUTBF16>
__global__ __launch_bounds__(256, 2) void gemm_bf16(
    const unsigned short* __restrict__ A, const unsigned short* __restrict__ WT,
    const float* __restrict__ bias, const float* __restrict__ resid,
    void* __restrict__ Cout, int M, int K, int Nc){
  __shared__ unsigned short As[2*128*64];   // 32 KB
  __shared__ unsigned short Bs[2*128*64];   // 32 KB
  int tid = threadIdx.x, lane = tid&63, wid = tid>>6;
  int2 bxy = xcd_swz(gridDim.x, gridDim.y);
  int m0 = bxy.y*128, n0 = bxy.x*128;
  int wr = wid>>1, wc = wid&1;
  int lm = lane&15, lg = lane>>4;
  // staging: 1024 16B-chunks per matrix per tile; thread does 4 (cid = tid+256i)
  const unsigned short *gA[4], *gB[4];
  #pragma unroll
  for(int i=0;i<4;++i){
    int cid = tid + 256*i;
    int srow = cid>>3;
    int sc = (cid&7) ^ (srow&7);            // inverse-swizzled source chunk
    int ar = m0 + srow; if(ar > M-1) ar = M-1;
    gA[i] = A  + (size_t)ar*K + sc*8;
    gB[i] = WT + (size_t)(n0+srow)*K + sc*8;
  }
  unsigned short* lAb = As + wid*512;       // + i*2048 + buf*8192 (shorts)
  unsigned short* lBb = Bs + wid*512;

#define STAGE_(buf, kt) do{ \
    _Pragma("unroll") \
    for(int i=0;i<4;++i){ \
      __builtin_amdgcn_global_load_lds((g_void*)(gA[i] + (kt)), (lds_void*)(lAb + (buf)*8192 + i*2048), 16, 0, 0); \
      __builtin_amdgcn_global_load_lds((g_void*)(gB[i] + (kt)), (lds_void*)(lBb + (buf)*8192 + i*2048), 16, 0, 0); \
    } \
  }while(0)

  f32x4 acc[4][4] = {};
  const int nt = K/64;
  STAGE_(0, 0);
  __syncthreads();
  for(int t=0; t<nt; ++t){
    int buf = t&1;
    if(t+1 < nt) STAGE_(buf^1, (t+1)*64);
    const unsigned short* abase = As + buf*8192;
    const unsigned short* bbase = Bs + buf*8192;
    #pragma unroll
    for(int s=0; s<2; ++s){
      int ch = ((s*4+lg) ^ (lm&7)) * 8;     // swizzled frag chunk (shorts)
      short8 af[4], bfv[4];
      #pragma unroll
      for(int i=0;i<4;++i)
        af[i]  = *(const short8*)(abase + (64*wr + 16*i + lm)*64 + ch);
      #pragma unroll
      for(int j=0;j<4;++j)
        bfv[j] = *(const short8*)(bbase + (64*wc + 16*j + lm)*64 + ch);
      __builtin_amdgcn_s_setprio(1);
      #pragma unroll
      for(int i=0;i<4;++i)
        #pragma unroll
        for(int j=0;j<4;++j)
          acc[i][j] = __builtin_amdgcn_mfma_f32_16x16x32_bf16(af[i], bfv[j], acc[i][j], 0,0,0);
      __builtin_amdgcn_s_setprio(0);
    }
    __syncthreads();
  }
#undef STAGE_
  #pragma unroll
  for(int i=0;i<4;++i){
    #pragma unroll
    for(int j=0;j<4;++j){
      int gcol = n0 + 64*wc + 16*j + lm;
      float bv = bias ? bias[gcol] : 0.f;
      #pragma unroll
      for(int r=0;r<4;++r){
        int grow = m0 + 64*wr + 16*i + lg*4 + r;
        if(grow < M){
          float cv = acc[i][j][r] + bv;
          if(ACT==1){
            float xx = cv;
            float p = xx*fmaf(xx*xx, 0.10294517f, 2.3022079f);
            float q = exp2f(p);
            cv = xx - xx*__builtin_amdgcn_rcpf(1.0f+q);
          }
          if(RESID) cv += resid[(size_t)grow*Nc + gcol];
          if(OUTBF16) ((unsigned short*)Cout)[(size_t)grow*Nc+gcol] = f2bf(cv);
          else        ((float*)Cout)[(size_t)grow*Nc+gcol] = cv;
        }
      }
    }
  }
}

// ---------------- bf16 MFMA GEMM 256x128, BK=32, 8 waves (4mx2n), dbuf + XCD swizzle ----------------
template<int ACT, int RESID, int OUTBF16>
__global__ __launch_bounds__(512, 4) void gemm256_bf16(
    const unsigned short* __restrict__ A, const unsigned short* __restrict__ WT,
    const float* __restrict__ bias, const float* __restrict__ resid,
    void* __restrict__ Cout, int M, int K, int Nc){
  __shared__ unsigned short As[2*256*32];   // 32 KB
  __shared__ unsigned short Bs[2*128*32];   // 16 KB
  int tid = threadIdx.x, lane = tid&63, wid = tid>>6;
  int2 bxy = xcd_swz(gridDim.x, gridDim.y);
  int m0 = bxy.y*256, n0 = bxy.x*128;
  int wm = wid>>1, wn = wid&1;
  int lm = lane&15, lg = lane>>4;
  int rowA0 = tid>>2, rowA1 = 128 + (tid>>2), rowB = tid>>2;
  int kc = (tid&3)*8;
  int arA0 = m0+rowA0; if(arA0 > M-1) arA0 = M-1;
  int arA1 = m0+rowA1; if(arA1 > M-1) arA1 = M-1;
  const unsigned short* gA0 = A  + (size_t)arA0*K + kc;
  const unsigned short* gA1 = A  + (size_t)arA1*K + kc;
  const unsigned short* gB0 = WT + (size_t)(n0+rowB)*K + kc;
  unsigned short* lA0 = As + wid*512;
  unsigned short* lA1 = As + 4096 + wid*512;
  unsigned short* lB0 = Bs + wid*512;

#define STAGE2_(buf, kt) do{ \
    __builtin_amdgcn_global_load_lds((g_void*)(gA0 + (kt)), (lds_void*)(lA0 + (buf)*8192), 16, 0, 0); \
    __builtin_amdgcn_global_load_lds((g_void*)(gB0 + (kt)), (lds_void*)(lB0 + (buf)*4096), 16, 0, 0); \
    __builtin_amdgcn_global_load_lds((g_void*)(gA1 + (kt)), (lds_void*)(lA1 + (buf)*8192), 16, 0, 0); \
  }while(0)

  f32x4 acc[4][4] = {};
  const int nt = K/32;
  STAGE2_(0, 0);
  __syncthreads();
  for(int t=0; t<nt; ++t){
    int buf = t&1;
    if(t+1 < nt) STAGE2_(buf^1, (t+1)*32);
    const unsigned short* abase = As + buf*8192;
    const unsigned short* bbase = Bs + buf*4096;
    short8 af[4], bfv[4];
    #pragma unroll
    for(int i=0;i<4;++i)
      af[i] = *(const short8*)(abase + (wm*64 + i*16 + lm)*32 + lg*8);
    #pragma unroll
    for(int j=0;j<4;++j)
      bfv[j] = *(const short8*)(bbase + (wn*64 + j*16 + lm)*32 + lg*8);
    __builtin_amdgcn_s_setprio(1);
    #pragma unroll
    for(int i=0;i<4;++i)
      #pragma unroll
      for(int j=0;j<4;++j)
        acc[i][j] = __builtin_amdgcn_mfma_f32_16x16x32_bf16(af[i], bfv[j], acc[i][j], 0,0,0);
    __builtin_amdgcn_s_setprio(0);
    __syncthreads();
  }
#undef STAGE2_
  #pragma unroll
  for(int i=0;i<4;++i){
    #pragma unroll
    for(int j=0;j<4;++j){
      int gcol = n0 + wn*64 + j*16 + lm;
      float bv = bias ? bias[gcol] : 0.f;
      #pragma unroll
      for(int r=0;r<4;++r){
        int grow = m0 + wm*64 + i*16 + lg*4 + r;
        if(grow < M){
          float cv = acc[i][j][r] + bv;
          if(ACT==1){
            float xx = cv;
            float p = xx*fmaf(xx*xx, 0.10294517f, 2.3022079f);
            float q = exp2f(p);
            cv = xx - xx*__builtin_amdgcn_rcpf(1.0f+q);
          }
          if(RESID) cv += resid[(size_t)grow*Nc + gcol];
          if(OUTBF16) ((unsigned short*)Cout)[(size_t)grow*Nc+gcol] = f2bf(cv);
          else        ((float*)Cout)[(size_t)grow*Nc+gcol] = cv;
        }
      }
    }
  }
}

// ---------------- fused cheap path v3: MFMA kp/qp + float4 kk + 2-row coef ----------------
__global__ __launch_bounds__(512) void cheap_kernel(
    const unsigned short* __restrict__ qkv,
    const unsigned short* __restrict__ WcqT, const float* __restrict__ bcq,
    const unsigned short* __restrict__ WckT, const float* __restrict__ bck,
    const float* __restrict__ proj_n, float* __restrict__ coef){
  int bh = blockIdx.x; int b = bh/H_, h = bh%H_;
  int tid = threadIdx.x, lane = tid&63, wv = tid>>6;
  int lm = lane&15, lg = lane>>4;
  __shared__ __align__(16) unsigned short KQ[208*64];
  __shared__ __align__(16) float P2T[32*212];
  __shared__ __align__(16) float PNT[24*200];
  __shared__ float KK[768];
  const unsigned short* Kbase = qkv + ((size_t)(b*N_)*3 + 1)*C_ + h*CH_;
  const unsigned short* Qbase = qkv + ((size_t)(b*N_)*3 + 0)*C_ + h*CH_;
  for(int idx = tid; idx < 208*32; idx += 512){
    int k = idx>>5, cp = idx&31;
    unsigned v = (k < N_) ? *(const unsigned*)(Kbase + (size_t)k*3*C_ + cp*2) : 0u;
    unsigned off = (unsigned)(k*128 + cp*4) ^ ((unsigned)(k&7)<<4);
    *(unsigned*)((char*)KQ + off) = v;
  }
  for(int idx = tid; idx < 24*200; idx += 512){
    int r = idx/200, n = idx - r*200;
    PNT[idx] = (n < N_) ? proj_n[n*24+r] : 0.f;
  }
  __syncthreads();
  {
    short8 bfr[2][2];
    #pragma unroll
    for(int j=0;j<2;++j)
      #pragma unroll
      for(int s=0;s<2;++s)
        bfr[j][s] = *(const short8*)(WckT + (j*16+lm)*64 + s*32 + lg*8);
    float bias[2] = { bck[lm], bck[16+lm] };
    for(int t=wv; t<13; t+=8){
      int row = t*16 + lm;
      unsigned o0 = (unsigned)(row*128 + lg*16) ^ ((unsigned)(row&7)<<4);
      unsigned o1 = (unsigned)(row*128 + 64 + lg*16) ^ ((unsigned)(row&7)<<4);
      short8 a0 = *(const short8*)((char*)KQ + o0);
      short8 a1 = *(const short8*)((char*)KQ + o1);
      #pragma unroll
      for(int j=0;j<2;++j){
        f32x4 acc = (f32x4){0.f,0.f,0.f,0.f};
        acc = __builtin_amdgcn_mfma_f32_16x16x32_bf16(a0, bfr[j][0], acc, 0,0,0);
        acc = __builtin_amdgcn_mfma_f32_16x16x32_bf16(a1, bfr[j][1], acc, 0,0,0);
        #pragma unroll
        for(int r=0;r<4;++r)
          P2T[(j*16+lm)*212 + t*16 + lg*4 + r] = acc[r] + bias[j];
      }
    }
  }
  __syncthreads();
  {
    int i0 = tid, i1 = tid + 512;
    bool has1 = (i1 < 768);
    int c0 = i0/24, r0 = i0 - c0*24;
    int c1 = has1 ? i1/24 : 0, r1 = has1 ? (i1 - (i1/24)*24) : 0;
    float a0=0.f, a1=0.f;
    for(int n=0;n<200;n+=4){
      float4 x0 = *(const float4*)&P2T[c0*212+n];
      float4 p0 = *(const float4*)&PNT[r0*200+n];
      a0 += x0.x*p0.x; a0 += x0.y*p0.y; a0 += x0.z*p0.z; a0 += x0.w*p0.w;
      if(has1){
        float4 x1 = *(const float4*)&P2T[c1*212+n];
        float4 p1 = *(const float4*)&PNT[r1*200+n];
        a1 += x1.x*p1.x; a1 += x1.y*p1.y; a1 += x1.z*p1.z; a1 += x1.w*p1.w;
      }
    }
    KK[i0] = a0;
    if(has1) KK[i1] = a1;
    for(int idx = tid; idx < 197*32; idx += 512){
      int k = idx>>5, cp = idx&31;
      unsigned v = *(const unsigned*)(Qbase + (size_t)k*3*C_ + cp*2);
      unsigned off = (unsigned)(k*128 + cp*4) ^ ((unsigned)(k&7)<<4);
      *(unsigned*)((char*)KQ + off) = v;
    }
  }
  __syncthreads();
  float* QP = P2T;
  {
    short8 bfr[2][2];
    #pragma unroll
    for(int j=0;j<2;++j)
      #pragma unroll
      for(int s=0;s<2;++s)
        bfr[j][s] = *(const short8*)(WcqT + (j*16+lm)*64 + s*32 + lg*8);
    float bias[2] = { bcq[lm], bcq[16+lm] };
    for(int t=wv; t<13; t+=8){
      int row = t*16 + lm;
      unsigned o0 = (unsigned)(row*128 + lg*16) ^ ((unsigned)(row&7)<<4);
      unsigned o1 = (unsigned)(row*128 + 64 + lg*16) ^ ((unsigned)(row&7)<<4);
      short8 a0 = *(const short8*)((char*)KQ + o0);
      short8 a1 = *(const short8*)((char*)KQ + o1);
      #pragma unroll
      for(int j=0;j<2;++j){
        f32x4 acc = (f32x4){0.f,0.f,0.f,0.f};
        acc = __builtin_amdgcn_mfma_f32_16x16x32_bf16(a0, bfr[j][0], acc, 0,0,0);
        acc = __builtin_amdgcn_mfma_f32_16x16x32_bf16(a1, bfr[j][1], acc, 0,0,0);
        #pragma unroll
        for(int r=0;r<4;++r)
          QP[(t*16 + lg*4 + r)*32 + j*16 + lm] = acc[r] + bias[j];
      }
    }
  }
  __syncthreads();
  int l32 = lane & 31, half = lane >> 5;
  bool act = l32 < RN_;
  int ll = act ? l32 : 0;
  float kkreg[32];
  #pragma unroll
  for(int c=0;c<32;++c) kkreg[c] = KK[c*24 + ll];
  for(int i2 = wv*2; i2 < 196; i2 += 16){
    int i = i2 + half;
    int n = i + 1;
    float accv = 0.f;
    #pragma unroll
    for(int q=0;q<8;++q){
      float4 v4 = *(const float4*)&QP[n*32 + q*4];
      accv += v4.x*kkreg[q*4];   accv += v4.y*kkreg[q*4+1];
      accv += v4.z*kkreg[q*4+2]; accv += v4.w*kkreg[q*4+3];
    }
    float val = act ? accv * 0.28867513459481287f : -INFINITY;
    float m = val;
    #pragma unroll
    for(int o=16;o>=1;o>>=1) m = fmaxf(m, __shfl_xor(m, o));
    float e = act ? expf(val - m) : 0.f;
    float ssum = e;
    #pragma unroll
    for(int o=16;o>=1;o>>=1) ssum += __shfl_xor(ssum, o);
    float p = e/ssum;
    unsigned u = __float_as_uint(e);
    unsigned pL=0, pH=0;
    #pragma unroll
    for(int bit=30; bit>=0; --bit){
      unsigned tL = pL | (1u<<bit), tH = pH | (1u<<bit);
      unsigned thr = half ? tH : tL;
      unsigned long long bal = __ballot(u >= thr);
      int cL = __popcll(bal & 0xFFFFFFull);
      int cH = __popcll((bal>>32) & 0xFFFFFFull);
      if(cL>=8) pL=tL;
      if(cH>=8) pH=tH;
    }
    unsigned myp = half ? pH : pL;
    if(act) coef[((size_t)bh*196 + i)*24 + l32] = (u >= myp) ? p : 0.f;
  }
}

// ---------------- basis[r][j] = thresh(|proj_back_n[j][r]|) ----------------
__global__ __launch_bounds__(256) void basis_kernel(const float* __restrict__ pb,
    float* __restrict__ basis){
  int t = blockIdx.x*256 + threadIdx.x;
  if(t < RN_*N_){
    int r = t/N_, j = t%N_;
    float v = fabsf(pb[(size_t)j*RN_ + r]);
    basis[t] = (v > 0.02f) ? v : 0.f;
  }
}

// ---------------- mask v6: batched dot loads + interleaved radix + early exit ----------------
// Dot phase: pre-extract <=8 nonzero (r,c) pairs (SALU), issue 8 independent
// ds_read_b128s, then FMA in same ascending-r order (zero-pad tail adds +0.0)
// -> bit-identical to v5, latency pipelined.
__global__ __launch_bounds__(256) void mask6_kernel(const float* __restrict__ coef,
    const float* __restrict__ basis, unsigned int* __restrict__ maskw){
  __shared__ float Bs[24*256];
  int tid = threadIdx.x, lane = tid&63, wv = tid>>6;
  for(int idx = tid; idx < 24*256; idx += 256){
    int r = idx>>8, q = idx&255;
    int e = ((q&3)<<6) | (q>>2);
    Bs[idx] = (e < N_) ? basis[r*N_ + e] : 0.f;
  }
  __syncthreads();
  int rowbase = blockIdx.x*16 + wv*4;
  float4 av[4];
  unsigned done = 0;
  #pragma unroll
  for(int j=0;j<4;++j){
    int row = rowbase + j;
    int qi = row % N_; int bh = row / N_;
    if(qi==0){
      if(lane<8){
        unsigned v = (lane<6)?0xFFFFFFFFu:((lane==6)?0x1Fu:0u);
        maskw[(size_t)row*8+lane]=v;
      }
      av[j] = make_float4(0.f,0.f,0.f,0.f);
      done |= (1u<<j);
    } else {
      float cfv = (lane<24) ? coef[((size_t)bh*196 + (qi-1))*24 + lane] : 0.f;
      unsigned long long nz = __ballot(cfv != 0.f);
      int rr[8];
      #pragma unroll
      for(int s=0;s<8;++s){
        rr[s] = nz ? (__ffsll(nz)-1) : 64;
        nz &= nz - 1;
      }
      float cc[8]; float4 bv[8];
      #pragma unroll
      for(int s=0;s<8;++s){
        int r = (rr[s] < 64) ? rr[s] : 0;
        float c = __uint_as_float(__builtin_amdgcn_readlane(__float_as_uint(cfv), r));
        cc[s] = (rr[s] < 64) ? c : 0.f;
        bv[s] = *(const float4*)&Bs[r*256 + lane*4];
      }
      float4 a = make_float4(0.f,0.f,0.f,0.f);
      #pragma unroll
      for(int s=0;s<8;++s){
        a.x += cc[s]*bv[s].x; a.y += cc[s]*bv[s].y;
        a.z += cc[s]*bv[s].z; a.w += cc[s]*bv[s].w;
      }
      av[j] = a;
    }
  }
  unsigned u[4][4];
  #pragma unroll
  for(int j=0;j<4;++j){
    u[j][0]=__float_as_uint(av[j].x); u[j][1]=__float_as_uint(av[j].y);
    u[j][2]=__float_as_uint(av[j].z); u[j][3]=__float_as_uint(av[j].w);
  }
  unsigned prefix[4] = {0,0,0,0};
  for(int bit=30; bit>=0; --bit){
    if(done == 0xFu) break;
    #pragma unroll
    for(int j=0;j<4;++j){
      unsigned t = prefix[j] | (1u<<bit);
      int c = __popcll(__ballot(u[j][0] >= t)) + __popcll(__ballot(u[j][1] >= t))
            + __popcll(__ballot(u[j][2] >= t)) + __popcll(__ballot(u[j][3] >= t));
      bool actj = !((done>>j)&1u);
      if(actj && c >= 50) prefix[j] = t;
      if(actj && c == 50) done |= (1u<<j);
    }
  }
  #pragma unroll
  for(int j=0;j<4;++j){
    int row = rowbase + j;
    if(row % N_ == 0) continue;
    #pragma unroll
    for(int r=0;r<4;++r){
      bool valid = (r<3) | (lane<5);
      bool keep = valid && (u[j][r] >= prefix[j]);
      unsigned long long bal = __ballot(keep);
      if(lane==0){
        maskw[(size_t)row*8 + 2*r]   = (unsigned)(bal & 0xFFFFFFFFull);
        maskw[(size_t)row*8 + 2*r+1] = (unsigned)(bal>>32);
      }
    }
  }
}

// ---------------- masked attention v3: MFMA flash-style, one block per (b,h) ----------------
__global__ __launch_bounds__(512) void attn3_kernel(const unsigned short* __restrict__ qkv,
    const unsigned int* __restrict__ maskw, unsigned short* __restrict__ attn_out){
  int bh = blockIdx.x; int b = bh/H_, h = bh%H_;
  int tid = threadIdx.x, lane = tid&63, wv = tid>>6;
  int g = lane>>4, c16 = lane&15;
  __shared__ unsigned short Kb[208*64];
  __shared__ unsigned short Vt[64*220];
  __shared__ unsigned short Pl[8*16*224];
  __shared__ unsigned int   Ml[8][16][8];
  const unsigned short* Kbase = qkv + ((size_t)(b*N_)*3 + 1)*C_ + h*CH_;
  const unsigned short* Vbase = qkv + ((size_t)(b*N_)*3 + 2)*C_ + h*CH_;
  for(int idx = tid; idx < 208*32; idx += 512){
    int k = idx>>5, cp = idx&31;
    unsigned pk = 0;
    if(k < N_) pk = *(const unsigned*)(Kbase + (size_t)k*3*C_ + cp*2);
    unsigned off = (unsigned)(k*128 + cp*4) ^ ((unsigned)(k&7)<<4);
    *(unsigned*)((char*)Kb + off) = pk;
  }
  for(int idx = tid; idx < 64*110; idx += 512){
    int kp = idx>>6, c = idx&63;
    int k0 = kp*2, k1 = kp*2+1;
    unsigned v0 = (k0<N_) ? Vbase[(size_t)k0*3*C_ + c] : 0;
    unsigned v1 = (k1<N_) ? Vbase[(size_t)k1*3*C_ + c] : 0;
    *(unsigned*)((char*)Vt + c*440 + kp*4) = v0 | (v1<<16);
  }
  __syncthreads();
  size_t pbase = (size_t)wv*16*448;
  for(int i=lane;i<128;i+=64){
    int ql = i>>3; int kk = 208 + (i&7)*2;
    unsigned off = (unsigned)(ql*448 + kk*2) ^ ((unsigned)(ql&7)<<4);
    *(unsigned*)((char*)Pl + pbase + off) = 0u;
  }
  for(int t = wv; t < 13; t += 8){
    int qb = t*16;
    for(int i = lane; i < 128; i += 64){
      int row = i>>3, word = i&7;
      int qr = qb+row; if(qr>196) qr=196;
      Ml[wv][row][word] = maskw[(size_t)(bh*N_+qr)*8 + word];
    }
    int qrow = qb + c16; if(qrow>196) qrow=196;
    const unsigned short* Qr = qkv + ((size_t)(b*N_+qrow)*3)*C_ + h*CH_ + g*8;
    short8 af[2];
    af[0] = *(const short8*)(Qr);
    af[1] = *(const short8*)(Qr + 32);
    f32x4 sf[13];
    #pragma unroll
    for(int f=0;f<13;++f){
      sf[f] = (f32x4){0.f,0.f,0.f,0.f};
      #pragma unroll
      for(int s=0;s<2;++s){
        int row = f*16 + c16;
        unsigned off = (unsigned)(row*128 + s*64 + g*16) ^ ((unsigned)(row&7)<<4);
        short8 bfr = *(const short8*)((char*)Kb + off);
        sf[f] = __builtin_amdgcn_mfma_f32_16x16x32_bf16(af[s], bfr, sf[f], 0,0,0);
      }
      sf[f][0]*=0.125f; sf[f][1]*=0.125f; sf[f][2]*=0.125f; sf[f][3]*=0.125f;
    }
    unsigned keep[4] = {0,0,0,0};
    float m[4] = {-FLT_MAX,-FLT_MAX,-FLT_MAX,-FLT_MAX};
    #pragma unroll
    for(int f=0;f<13;++f)
      #pragma unroll
      for(int r=0;r<4;++r){
        unsigned bit = (Ml[wv][g*4+r][f>>1] >> ((f&1)*16 + c16)) & 1u;
        keep[r] |= bit<<f;
        if(bit) m[r] = fmaxf(m[r], sf[f][r]);
      }
    #pragma unroll
    for(int r=0;r<4;++r){
      #pragma unroll
      for(int o=8;o>=1;o>>=1) m[r] = fmaxf(m[r], __shfl_xor(m[r], o));
    }
    float sum[4] = {0,0,0,0};
    #pragma unroll
    for(int f=0;f<13;++f)
      #pragma unroll
      for(int r=0;r<4;++r){
        float e = ((keep[r]>>f)&1u) ? expf(sf[f][r]-m[r]) : 0.f;
        sf[f][r] = e; sum[r] += e;
      }
    #pragma unroll
    for(int r=0;r<4;++r){
      #pragma unroll
      for(int o=8;o>=1;o>>=1) sum[r] += __shfl_xor(sum[r], o);
      sum[r] = 1.f/sum[r];
    }
    #pragma unroll
    for(int f=0;f<13;++f)
      #pragma unroll
      for(int r=0;r<4;++r){
        int ql = g*4+r;
        unsigned off = (unsigned)(ql*448 + (f*16+c16)*2) ^ ((unsigned)(ql&7)<<4);
        *(unsigned short*)((char*)Pl + pbase + off) = f2bf(sf[f][r]*sum[r]);
      }
    #pragma unroll
    for(int ct=0;ct<4;++ct){
      f32x4 oa = (f32x4){0.f,0.f,0.f,0.f};
      #pragma unroll
      for(int ks=0;ks<7;++ks){
        unsigned offa = (unsigned)(c16*448 + (ks*32+g*8)*2) ^ ((unsigned)(c16&7)<<4);
        short8 pa = *(const short8*)((char*)Pl + pbase + offa);
        short8 vb = *(const short8*)((char*)Vt + (size_t)(ct*16+c16)*440 + (ks*32+g*8)*2);
        oa = __builtin_amdgcn_mfma_f32_16x16x32_bf16(pa, vb, oa, 0,0,0);
      }
      #pragma unroll
      for(int r=0;r<4;++r){
        int qq = qb + g*4 + r;
        if(qq < N_)
          attn_out[((size_t)(b*N_+qq))*C_ + h*CH_ + ct*16 + c16] = f2bf(oa[r]);
      }
    }
  }
}

extern "C" void kernel_launch(void* const* d_in, const int* in_sizes, int n_in,
                              void* d_out, int out_size, void* d_ws, size_t ws_size,
                              hipStream_t stream){
  const float* x    =(const float*)d_in[0];
  const float* Wqkv =(const float*)d_in[1];
  const float* Wcq  =(const float*)d_in[2];
  const float* bcq  =(const float*)d_in[3];
  const float* Wck  =(const float*)d_in[4];
  const float* bck  =(const float*)d_in[5];
  const float* proj_n=(const float*)d_in[6];
  const float* proj_back_n=(const float*)d_in[7];
  const float* Wproj=(const float*)d_in[8];
  const float* bproj=(const float*)d_in[9];
  const float* g1=(const float*)d_in[10];
  const float* b1=(const float*)d_in[11];
  const float* g2=(const float*)d_in[12];
  const float* b2=(const float*)d_in[13];
  const float* W1=(const float*)d_in[14];
  const float* bfc1=(const float*)d_in[15];
  const float* W2=(const float*)d_in[16];
  const float* bfc2=(const float*)d_in[17];
  float* out=(float*)d_out;

  float* ws=(float*)d_ws;
  size_t off=0;
  unsigned short* hbuf = (unsigned short*)(ws+off); off += (size_t)12608*768/2;
  size_t qkv_off = off;
  unsigned short* qkv = (unsigned short*)(ws+off); off += (size_t)12608*2304/2;
  off += (size_t)768*197*32;   // padding (hidden alias headroom)
  off += (size_t)768*197*32;
  off += (size_t)768*32*24;
  float* coef = ws+off;        off += (size_t)768*196*24;
  float* basis= ws+off;        off += 4736;
  unsigned int* maskw=(unsigned int*)(ws+off); off += (size_t)768*197*8;
  unsigned short* WqkvT = (unsigned short*)(ws+off); off += (size_t)2304*768/2;
  unsigned short* WprojT= (unsigned short*)(ws+off); off += (size_t)768*768/2;
  unsigned short* W1T   = (unsigned short*)(ws+off); off += (size_t)3072*768/2;
  unsigned short* W2T   = (unsigned short*)(ws+off); off += (size_t)768*3072/2;
  unsigned short* WcqT  = (unsigned short*)(ws+off); off += 1024;
  unsigned short* WckT  = (unsigned short*)(ws+off); off += 1024;
  unsigned short* attn_out = hbuf;                    // alias (hbuf dead after qkv GEMM)
  unsigned short* hidden = (unsigned short*)(ws+qkv_off); // alias (qkv dead by MLP)
  float* x1 = out;

  // 0. weight transpose+bf16 conversions
  wtrans_kernel<<<dim3(72,24),256,0,stream>>>(Wqkv, WqkvT, 768, 2304);
  wtrans_kernel<<<dim3(24,24),256,0,stream>>>(Wproj, WprojT, 768, 768);
  wtrans_kernel<<<dim3(96,24),256,0,stream>>>(W1, W1T, 768, 3072);
  wtrans_kernel<<<dim3(24,96),256,0,stream>>>(W2, W2T, 3072, 768);
  wcprep_kernel<<<8,256,0,stream>>>(Wcq, Wck, WcqT, WckT);
  // 1. h = LN(x) -> bf16
  ln_kernel<<<12608,256,0,stream>>>(x,g1,b1,hbuf);
  // 2. qkv = h @ Wqkv (bf16 out)  [256x128 tiles: 18 x 50 = 900 blocks]
  gemm256_bf16<0,0,1><<<dim3(18,50),512,0,stream>>>(hbuf,WqkvT,nullptr,nullptr,qkv,12608,768,2304);
  // 3. fused cheap path v3 (MFMA kp/qp)
  cheap_kernel<<<768,512,0,stream>>>(qkv,WcqT,bcq,WckT,bck,proj_n,coef);
  // 4. basis
  basis_kernel<<<19,256,0,stream>>>(proj_back_n,basis);
  // 5. approx_attn + budget mask (batched-load dot + interleaved radix)
  mask6_kernel<<<9456,256,0,stream>>>(coef,basis,maskw);
  // 6. masked attention (MFMA)
  attn3_kernel<<<768,512,0,stream>>>(qkv,maskw,attn_out);
  // 7. x1 = x + attn_out @ Wproj + bproj   (x1 == d_out) [128^2 BK=64, 594 blocks]
  gemm_bf16<0,1,0><<<dim3(6,99),256,0,stream>>>(attn_out,WprojT,bproj,x,x1,12608,768,768);
  // 8. h2 = LN(x1) -> bf16 (reuse hbuf)
  ln_kernel<<<12608,256,0,stream>>>(x1,g2,b2,hbuf);
  // 9. hidden = gelu(h2 @ W1 + bfc1) -> bf16 [256x128 tiles: 24 x 50 = 1200 blocks]
  gemm256_bf16<1,0,1><<<dim3(24,50),512,0,stream>>>(hbuf,W1T,bfc1,nullptr,hidden,12608,768,3072);
  // 10. out = x1 + hidden @ W2 + bfc2 [128^2 BK=64, 594 blocks]
  gemm_bf16<0,1,0><<<dim3(6,99),256,0,stream>>>(hidden,W2T,bfc2,x1,out,12608,3072,768);
}

// Round 19
// 691.139 us; speedup vs baseline: 1.0299x; 1.0299x over previous
//
#include <hip/hip_runtime.h>
#include <math.h>
#include <float.h>

#define B_ 64
#define N_ 197
#define C_ 768
#define H_ 12
#define CH_ 64
#define RC_ 32
#define RN_ 24

typedef __attribute__((ext_vector_type(8))) short short8;
typedef __attribute__((ext_vector_type(4))) float f32x4;
typedef __attribute__((address_space(3))) void  lds_void;
typedef __attribute__((address_space(1))) const void g_void;

__device__ __forceinline__ float warp_sum(float v){
  #pragma unroll
  for(int o=32;o>=1;o>>=1) v += __shfl_xor(v,o);
  return v;
}
__device__ __forceinline__ float warp_max(float v){
  #pragma unroll
  for(int o=32;o>=1;o>>=1) v = fmaxf(v,__shfl_xor(v,o));
  return v;
}
__device__ __forceinline__ unsigned short f2bf(float f){
  union{float f; unsigned u;} c; c.f = f;
  unsigned r = c.u + 0x7FFF + ((c.u>>16)&1);
  return (unsigned short)(r>>16);
}
__device__ __forceinline__ float bf2f(unsigned short u){
  union{unsigned u; float f;} c; c.u = ((unsigned)u)<<16; return c.f;
}
// bijective XCD-aware block swizzle (m204)
__device__ __forceinline__ int2 xcd_swz(int gx, int gy){
  int nwg = gx*gy;
  int id = blockIdx.x + gx*blockIdx.y;
  int xcd = id & 7, loc = id >> 3;
  int q = nwg >> 3, r = nwg & 7;
  int swz = (xcd < r ? xcd*(q+1) : r*(q+1) + (xcd-r)*q) + loc;
  return make_int2(swz % gx, swz / gx);
}

// ---------------- LayerNorm: one block per row of 768, bf16 out ----------------
__global__ __launch_bounds__(256) void ln_kernel(const float* __restrict__ x,
    const float* __restrict__ g, const float* __restrict__ bb, unsigned short* __restrict__ out){
  int r = blockIdx.x; int tid = threadIdx.x;
  const float* xr = x + (size_t)r*C_;
  float v0=xr[tid], v1=xr[tid+256], v2=xr[tid+512];
  __shared__ float red[8];
  float s = warp_sum(v0+v1+v2);
  if((tid&63)==0) red[tid>>6]=s;
  __syncthreads();
  float mu = (red[0]+red[1]+red[2]+red[3]) * (1.f/768.f);
  float d0=v0-mu,d1=v1-mu,d2=v2-mu;
  float s2 = warp_sum(d0*d0+d1*d1+d2*d2);
  if((tid&63)==0) red[4+(tid>>6)]=s2;
  __syncthreads();
  float rinv = rsqrtf((red[4]+red[5]+red[6]+red[7])*(1.f/768.f)+1e-5f);
  unsigned short* orow = out + (size_t)r*C_;
  orow[tid]     = f2bf(d0*rinv*g[tid]    +bb[tid]);
  orow[tid+256] = f2bf(d1*rinv*g[tid+256]+bb[tid+256]);
  orow[tid+512] = f2bf(d2*rinv*g[tid+512]+bb[tid+512]);
}

// ---------------- transpose+convert: in f32 [K][N] -> out bf16 [N][K] ----------------
__global__ __launch_bounds__(256) void wtrans_kernel(const float* __restrict__ in,
    unsigned short* __restrict__ out, int K, int N){
  __shared__ float tile[32][33];
  int n0 = blockIdx.x*32, k0 = blockIdx.y*32;
  int tx = threadIdx.x&31, ty = threadIdx.x>>5;
  #pragma unroll
  for(int i=0;i<4;++i) tile[ty+8*i][tx] = in[(size_t)(k0+ty+8*i)*N + n0+tx];
  __syncthreads();
  #pragma unroll
  for(int i=0;i<4;++i) out[(size_t)(n0+ty+8*i)*K + k0+tx] = f2bf(tile[tx][ty+8*i]);
}

// ---------------- Wcq/Wck f32[64][32] -> bf16 transposed [32][64] ----------------
__global__ __launch_bounds__(256) void wcprep_kernel(const float* __restrict__ Wcq,
    const float* __restrict__ Wck, unsigned short* __restrict__ WcqT,
    unsigned short* __restrict__ WckT){
  int t = blockIdx.x*256 + threadIdx.x;
  if(t < 2048){
    int c = t>>6, k = t&63;
    WcqT[t] = f2bf(Wcq[k*32+c]);
    WckT[t] = f2bf(Wck[k*32+c]);
  }
}

// ---------------- bf16 MFMA GEMM 128x128, BK=32, dbuf + XCD swizzle (round-17 proven) ----------------
template<int ACT, int RESID, int OUTBF16>
__global__ __launch_bounds__(256) void gemm_bf16(
    const unsigned short* __restrict__ A, const unsigned short* __restrict__ WT,
    const float* __restrict__ bias, const float* __restrict__ resid,
    void* __restrict__ Cout, int M, int K, int Nc){
  __shared__ unsigned short As[2*128*32];
  __shared__ unsigned short Bs[2*128*32];
  int tid = threadIdx.x, lane = tid&63, wid = tid>>6;
  int2 bxy = xcd_swz(gridDim.x, gridDim.y);
  int m0 = bxy.y*128, n0 = bxy.x*128;
  int wr = wid>>1, wc = wid&1;
  int lm = lane&15, lg = lane>>4;
  int row0 = tid>>2,         kc0 = (tid&3)*8;
  int row1 = (256+tid)>>2,   kc1 = (tid&3)*8;
  int ar0 = m0+row0; if(ar0 > M-1) ar0 = M-1;
  int ar1 = m0+row1; if(ar1 > M-1) ar1 = M-1;
  const unsigned short* gA0 = A  + (size_t)ar0*K + kc0;
  const unsigned short* gA1 = A  + (size_t)ar1*K + kc1;
  const unsigned short* gB0 = WT + (size_t)(n0+row0)*K + kc0;
  const unsigned short* gB1 = WT + (size_t)(n0+row1)*K + kc1;
  unsigned short* lA0 = As + (wid*64)*8;
  unsigned short* lA1 = As + (256 + wid*64)*8;
  unsigned short* lB0 = Bs + (wid*64)*8;
  unsigned short* lB1 = Bs + (256 + wid*64)*8;

#define STAGE_(buf, kt) do{ \
    __builtin_amdgcn_global_load_lds((g_void*)(gA0 + (kt)), (lds_void*)(lA0 + (buf)*4096), 16, 0, 0); \
    __builtin_amdgcn_global_load_lds((g_void*)(gB0 + (kt)), (lds_void*)(lB0 + (buf)*4096), 16, 0, 0); \
    __builtin_amdgcn_global_load_lds((g_void*)(gA1 + (kt)), (lds_void*)(lA1 + (buf)*4096), 16, 0, 0); \
    __builtin_amdgcn_global_load_lds((g_void*)(gB1 + (kt)), (lds_void*)(lB1 + (buf)*4096), 16, 0, 0); \
  }while(0)

  f32x4 acc[4][4] = {};
  const int nt = K/32;
  STAGE_(0, 0);
  __syncthreads();
  for(int t=0; t<nt; t+=2){
    STAGE_(1, (t+1)*32);
    {
      short8 af[4], bfv[4];
      #pragma unroll
      for(int i=0;i<4;++i){
        af[i]  = *(const short8*)(As + (64*wr + 16*i + lm)*32 + lg*8);
        bfv[i] = *(const short8*)(Bs + (64*wc + 16*i + lm)*32 + lg*8);
      }
      #pragma unroll
      for(int i=0;i<4;++i)
        #pragma unroll
        for(int j=0;j<4;++j)
          acc[i][j] = __builtin_amdgcn_mfma_f32_16x16x32_bf16(af[i], bfv[j], acc[i][j], 0,0,0);
    }
    __syncthreads();
    if(t+2 < nt) STAGE_(0, (t+2)*32);
    {
      short8 af[4], bfv[4];
      #pragma unroll
      for(int i=0;i<4;++i){
        af[i]  = *(const short8*)(As + 4096 + (64*wr + 16*i + lm)*32 + lg*8);
        bfv[i] = *(const short8*)(Bs + 4096 + (64*wc + 16*i + lm)*32 + lg*8);
      }
      #pragma unroll
      for(int i=0;i<4;++i)
        #pragma unroll
        for(int j=0;j<4;++j)
          acc[i][j] = __builtin_amdgcn_mfma_f32_16x16x32_bf16(af[i], bfv[j], acc[i][j], 0,0,0);
    }
    __syncthreads();
  }
#undef STAGE_
  #pragma unroll
  for(int i=0;i<4;++i){
    #pragma unroll
    for(int j=0;j<4;++j){
      int gcol = n0 + 64*wc + 16*j + lm;
      float bv = bias ? bias[gcol] : 0.f;
      #pragma unroll
      for(int r=0;r<4;++r){
        int grow = m0 + 64*wr + 16*i + lg*4 + r;
        if(grow < M){
          float cv = acc[i][j][r] + bv;
          if(ACT==1){
            float xx = cv;
            float p = xx*fmaf(xx*xx, 0.10294517f, 2.3022079f);
            float q = exp2f(p);
            cv = xx - xx*__builtin_amdgcn_rcpf(1.0f+q);
          }
          if(RESID) cv += resid[(size_t)grow*Nc + gcol];
          if(OUTBF16) ((unsigned short*)Cout)[(size_t)grow*Nc+gcol] = f2bf(cv);
          else        ((float*)Cout)[(size_t)grow*Nc+gcol] = cv;
        }
      }
    }
  }
}

// ---------------- bf16 MFMA GEMM 256x128, BK=32, 8 waves (4mx2n), dbuf + XCD swizzle ----------------
template<int ACT, int RESID, int OUTBF16>
__global__ __launch_bounds__(512, 4) void gemm256_bf16(
    const unsigned short* __restrict__ A, const unsigned short* __restrict__ WT,
    const float* __restrict__ bias, const float* __restrict__ resid,
    void* __restrict__ Cout, int M, int K, int Nc){
  __shared__ unsigned short As[2*256*32];   // 32 KB
  __shared__ unsigned short Bs[2*128*32];   // 16 KB
  int tid = threadIdx.x, lane = tid&63, wid = tid>>6;
  int2 bxy = xcd_swz(gridDim.x, gridDim.y);
  int m0 = bxy.y*256, n0 = bxy.x*128;
  int wm = wid>>1, wn = wid&1;
  int lm = lane&15, lg = lane>>4;
  int rowA0 = tid>>2, rowA1 = 128 + (tid>>2), rowB = tid>>2;
  int kc = (tid&3)*8;
  int arA0 = m0+rowA0; if(arA0 > M-1) arA0 = M-1;
  int arA1 = m0+rowA1; if(arA1 > M-1) arA1 = M-1;
  const unsigned short* gA0 = A  + (size_t)arA0*K + kc;
  const unsigned short* gA1 = A  + (size_t)arA1*K + kc;
  const unsigned short* gB0 = WT + (size_t)(n0+rowB)*K + kc;
  unsigned short* lA0 = As + wid*512;
  unsigned short* lA1 = As + 4096 + wid*512;
  unsigned short* lB0 = Bs + wid*512;

#define STAGE2_(buf, kt) do{ \
    __builtin_amdgcn_global_load_lds((g_void*)(gA0 + (kt)), (lds_void*)(lA0 + (buf)*8192), 16, 0, 0); \
    __builtin_amdgcn_global_load_lds((g_void*)(gB0 + (kt)), (lds_void*)(lB0 + (buf)*4096), 16, 0, 0); \
    __builtin_amdgcn_global_load_lds((g_void*)(gA1 + (kt)), (lds_void*)(lA1 + (buf)*8192), 16, 0, 0); \
  }while(0)

  f32x4 acc[4][4] = {};
  const int nt = K/32;
  STAGE2_(0, 0);
  __syncthreads();
  for(int t=0; t<nt; ++t){
    int buf = t&1;
    if(t+1 < nt) STAGE2_(buf^1, (t+1)*32);
    const unsigned short* abase = As + buf*8192;
    const unsigned short* bbase = Bs + buf*4096;
    short8 af[4], bfv[4];
    #pragma unroll
    for(int i=0;i<4;++i)
      af[i] = *(const short8*)(abase + (wm*64 + i*16 + lm)*32 + lg*8);
    #pragma unroll
    for(int j=0;j<4;++j)
      bfv[j] = *(const short8*)(bbase + (wn*64 + j*16 + lm)*32 + lg*8);
    __builtin_amdgcn_s_setprio(1);
    #pragma unroll
    for(int i=0;i<4;++i)
      #pragma unroll
      for(int j=0;j<4;++j)
        acc[i][j] = __builtin_amdgcn_mfma_f32_16x16x32_bf16(af[i], bfv[j], acc[i][j], 0,0,0);
    __builtin_amdgcn_s_setprio(0);
    __syncthreads();
  }
#undef STAGE2_
  #pragma unroll
  for(int i=0;i<4;++i){
    #pragma unroll
    for(int j=0;j<4;++j){
      int gcol = n0 + wn*64 + j*16 + lm;
      float bv = bias ? bias[gcol] : 0.f;
      #pragma unroll
      for(int r=0;r<4;++r){
        int grow = m0 + wm*64 + i*16 + lg*4 + r;
        if(grow < M){
          float cv = acc[i][j][r] + bv;
          if(ACT==1){
            float xx = cv;
            float p = xx*fmaf(xx*xx, 0.10294517f, 2.3022079f);
            float q = exp2f(p);
            cv = xx - xx*__builtin_amdgcn_rcpf(1.0f+q);
          }
          if(RESID) cv += resid[(size_t)grow*Nc + gcol];
          if(OUTBF16) ((unsigned short*)Cout)[(size_t)grow*Nc+gcol] = f2bf(cv);
          else        ((float*)Cout)[(size_t)grow*Nc+gcol] = cv;
        }
      }
    }
  }
}

// ---------------- fused cheap+mask v4: MFMA kp/qp + kk + coef + approx_attn + top-50 mask ----------------
// coef never leaves registers; basis staged into dead KQ region; maskw written directly.
// Selection math verbatim from verified mask5/6 (+residual loop for >8 ties, early exits).
__global__ __launch_bounds__(512) void cheap_kernel(
    const unsigned short* __restrict__ qkv,
    const unsigned short* __restrict__ WcqT, const float* __restrict__ bcq,
    const unsigned short* __restrict__ WckT, const float* __restrict__ bck,
    const float* __restrict__ proj_n, const float* __restrict__ basis,
    unsigned int* __restrict__ maskw){
  int bh = blockIdx.x; int b = bh/H_, h = bh%H_;
  int tid = threadIdx.x, lane = tid&63, wv = tid>>6;
  int lm = lane&15, lg = lane>>4;
  __shared__ __align__(16) unsigned short KQ[208*64];   // K, then Q, then basis (float)
  __shared__ __align__(16) float P2T[32*212];
  __shared__ __align__(16) float PNT[24*200];
  __shared__ float KK[768];
  const unsigned short* Kbase = qkv + ((size_t)(b*N_)*3 + 1)*C_ + h*CH_;
  const unsigned short* Qbase = qkv + ((size_t)(b*N_)*3 + 0)*C_ + h*CH_;
  for(int idx = tid; idx < 208*32; idx += 512){
    int k = idx>>5, cp = idx&31;
    unsigned v = (k < N_) ? *(const unsigned*)(Kbase + (size_t)k*3*C_ + cp*2) : 0u;
    unsigned off = (unsigned)(k*128 + cp*4) ^ ((unsigned)(k&7)<<4);
    *(unsigned*)((char*)KQ + off) = v;
  }
  for(int idx = tid; idx < 24*200; idx += 512){
    int r = idx/200, n = idx - r*200;
    PNT[idx] = (n < N_) ? proj_n[n*24+r] : 0.f;
  }
  __syncthreads();
  // kp = K @ Wck -> P2T[c][n]
  {
    short8 bfr[2][2];
    #pragma unroll
    for(int j=0;j<2;++j)
      #pragma unroll
      for(int s=0;s<2;++s)
        bfr[j][s] = *(const short8*)(WckT + (j*16+lm)*64 + s*32 + lg*8);
    float bias[2] = { bck[lm], bck[16+lm] };
    for(int t=wv; t<13; t+=8){
      int row = t*16 + lm;
      unsigned o0 = (unsigned)(row*128 + lg*16) ^ ((unsigned)(row&7)<<4);
      unsigned o1 = (unsigned)(row*128 + 64 + lg*16) ^ ((unsigned)(row&7)<<4);
      short8 a0 = *(const short8*)((char*)KQ + o0);
      short8 a1 = *(const short8*)((char*)KQ + o1);
      #pragma unroll
      for(int j=0;j<2;++j){
        f32x4 acc = (f32x4){0.f,0.f,0.f,0.f};
        acc = __builtin_amdgcn_mfma_f32_16x16x32_bf16(a0, bfr[j][0], acc, 0,0,0);
        acc = __builtin_amdgcn_mfma_f32_16x16x32_bf16(a1, bfr[j][1], acc, 0,0,0);
        #pragma unroll
        for(int r=0;r<4;++r)
          P2T[(j*16+lm)*212 + t*16 + lg*4 + r] = acc[r] + bias[j];
      }
    }
  }
  __syncthreads();
  // kk -> KK; stage Q over dead K region
  {
    int i0 = tid, i1 = tid + 512;
    bool has1 = (i1 < 768);
    int c0 = i0/24, r0 = i0 - c0*24;
    int c1 = has1 ? i1/24 : 0, r1 = has1 ? (i1 - (i1/24)*24) : 0;
    float a0=0.f, a1=0.f;
    for(int n=0;n<200;n+=4){
      float4 x0 = *(const float4*)&P2T[c0*212+n];
      float4 p0 = *(const float4*)&PNT[r0*200+n];
      a0 += x0.x*p0.x; a0 += x0.y*p0.y; a0 += x0.z*p0.z; a0 += x0.w*p0.w;
      if(has1){
        float4 x1 = *(const float4*)&P2T[c1*212+n];
        float4 p1 = *(const float4*)&PNT[r1*200+n];
        a1 += x1.x*p1.x; a1 += x1.y*p1.y; a1 += x1.z*p1.z; a1 += x1.w*p1.w;
      }
    }
    KK[i0] = a0;
    if(has1) KK[i1] = a1;
    for(int idx = tid; idx < 197*32; idx += 512){
      int k = idx>>5, cp = idx&31;
      unsigned v = *(const unsigned*)(Qbase + (size_t)k*3*C_ + cp*2);
      unsigned off = (unsigned)(k*128 + cp*4) ^ ((unsigned)(k&7)<<4);
      *(unsigned*)((char*)KQ + off) = v;
    }
  }
  __syncthreads();
  // qp = Q @ Wcq -> QP row-major (P2T region)
  float* QP = P2T;
  {
    short8 bfr[2][2];
    #pragma unroll
    for(int j=0;j<2;++j)
      #pragma unroll
      for(int s=0;s<2;++s)
        bfr[j][s] = *(const short8*)(WcqT + (j*16+lm)*64 + s*32 + lg*8);
    float bias[2] = { bcq[lm], bcq[16+lm] };
    for(int t=wv; t<13; t+=8){
      int row = t*16 + lm;
      unsigned o0 = (unsigned)(row*128 + lg*16) ^ ((unsigned)(row&7)<<4);
      unsigned o1 = (unsigned)(row*128 + 64 + lg*16) ^ ((unsigned)(row&7)<<4);
      short8 a0 = *(const short8*)((char*)KQ + o0);
      short8 a1 = *(const short8*)((char*)KQ + o1);
      #pragma unroll
      for(int j=0;j<2;++j){
        f32x4 acc = (f32x4){0.f,0.f,0.f,0.f};
        acc = __builtin_amdgcn_mfma_f32_16x16x32_bf16(a0, bfr[j][0], acc, 0,0,0);
        acc = __builtin_amdgcn_mfma_f32_16x16x32_bf16(a1, bfr[j][1], acc, 0,0,0);
        #pragma unroll
        for(int r=0;r<4;++r)
          QP[(t*16 + lg*4 + r)*32 + j*16 + lm] = acc[r] + bias[j];
      }
    }
  }
  __syncthreads();
  // stage basis into dead KQ region (mask6 layout: elem e at [r*256 + (e&63)*4 + (e>>6)])
  float* Bs2 = (float*)KQ;    // 24*256 floats = 24.6 KB <= 26.6 KB
  for(int idx = tid; idx < 24*256; idx += 512){
    int r = idx>>8, q = idx&255;
    int e = ((q&3)<<6) | (q>>2);
    Bs2[idx] = (e < N_) ? basis[r*N_ + e] : 0.f;
  }
  if(tid < 8){   // CLS row (qi=0) constant mask
    unsigned v = (tid<6)?0xFFFFFFFFu:((tid==6)?0x1Fu:0u);
    maskw[(size_t)(bh*N_)*8 + tid] = v;
  }
  __syncthreads();
  // KK columns for coef dot
  int l32 = lane & 31, half = lane >> 5;
  bool act = l32 < RN_;
  int ll = act ? l32 : 0;
  float kkreg[32];
  #pragma unroll
  for(int c=0;c<32;++c) kkreg[c] = KK[c*24 + ll];
  // row loop: half0 -> row i2 (qi=i2+1), half1 -> row i2+1 (qi=i2+2)
  for(int i2 = wv*2; i2 < 196; i2 += 16){
    int i = i2 + half;
    int n = i + 1;
    float accv = 0.f;
    #pragma unroll
    for(int q=0;q<8;++q){
      float4 v4 = *(const float4*)&QP[n*32 + q*4];
      accv += v4.x*kkreg[q*4];   accv += v4.y*kkreg[q*4+1];
      accv += v4.z*kkreg[q*4+2]; accv += v4.w*kkreg[q*4+3];
    }
    float val = act ? accv * 0.28867513459481287f : -INFINITY;
    float m = val;
    #pragma unroll
    for(int o=16;o>=1;o>>=1) m = fmaxf(m, __shfl_xor(m, o));
    float e = act ? expf(val - m) : 0.f;
    float ssum = e;
    #pragma unroll
    for(int o=16;o>=1;o>>=1) ssum += __shfl_xor(ssum, o);
    float p = e/ssum;
    // top-8 select (dual prefix, early exit when count==8: identical keep-set)
    unsigned u = __float_as_uint(e);
    unsigned pL=0, pH=0; bool dL=false, dH=false;
    for(int bit=30; bit>=0; --bit){
      if(dL && dH) break;
      unsigned tL = pL | (1u<<bit), tH = pH | (1u<<bit);
      unsigned thr = half ? tH : tL;
      unsigned long long bal = __ballot(u >= thr);
      int cL = __popcll(bal & 0xFFFFFFull);
      int cH = __popcll((bal>>32) & 0xFFFFFFull);
      if(!dL && cL>=8){ pL=tL; if(cL==8) dL=true; }
      if(!dH && cH>=8){ pH=tH; if(cH==8) dH=true; }
    }
    unsigned myp = half ? pH : pL;
    float cf = (act && u >= myp) ? p : 0.f;   // coef value, stays in registers
    // ---- fused mask: approx_attn dot (batched-8 + residual) for both rows ----
    unsigned long long nzall = __ballot(cf != 0.f);
    float4 aAB[2];
    #pragma unroll
    for(int rw=0; rw<2; ++rw){
      unsigned nz = (unsigned)((nzall >> (rw*32)) & 0xFFFFFFull);
      int base = rw*32;
      int rr[8];
      #pragma unroll
      for(int s=0;s<8;++s){ rr[s] = nz ? (__ffs(nz)-1) : 64; nz &= nz ? (nz-1) : 0; }
      float cc[8]; float4 bv[8];
      #pragma unroll
      for(int s=0;s<8;++s){
        int r = (rr[s] < 64) ? rr[s] : 0;
        float c = __uint_as_float(__builtin_amdgcn_readlane(__float_as_uint(cf), base + r));
        cc[s] = (rr[s] < 64) ? c : 0.f;
        bv[s] = *(const float4*)&Bs2[r*256 + lane*4];
      }
      float4 a = make_float4(0.f,0.f,0.f,0.f);
      #pragma unroll
      for(int s=0;s<8;++s){
        a.x += cc[s]*bv[s].x; a.y += cc[s]*bv[s].y;
        a.z += cc[s]*bv[s].z; a.w += cc[s]*bv[s].w;
      }
      while(nz){   // rare: >8 kept (ties) — ascending order continues
        int r = __ffs(nz)-1; nz &= nz-1;
        float c = __uint_as_float(__builtin_amdgcn_readlane(__float_as_uint(cf), base + r));
        float4 b4 = *(const float4*)&Bs2[r*256 + lane*4];
        a.x += c*b4.x; a.y += c*b4.y; a.z += c*b4.z; a.w += c*b4.w;
      }
      aAB[rw] = a;
    }
    unsigned uA[4] = {__float_as_uint(aAB[0].x),__float_as_uint(aAB[0].y),
                      __float_as_uint(aAB[0].z),__float_as_uint(aAB[0].w)};
    unsigned uB[4] = {__float_as_uint(aAB[1].x),__float_as_uint(aAB[1].y),
                      __float_as_uint(aAB[1].z),__float_as_uint(aAB[1].w)};
    // top-50 compare-radix, 2 interleaved chains + early exit
    unsigned qA=0, qB=0; bool dA=false, dB=false;
    for(int bit=30; bit>=0; --bit){
      if(dA && dB) break;
      unsigned tA = qA | (1u<<bit), tB = qB | (1u<<bit);
      int cA = __popcll(__ballot(uA[0] >= tA)) + __popcll(__ballot(uA[1] >= tA))
             + __popcll(__ballot(uA[2] >= tA)) + __popcll(__ballot(uA[3] >= tA));
      int cB = __popcll(__ballot(uB[0] >= tB)) + __popcll(__ballot(uB[1] >= tB))
             + __popcll(__ballot(uB[2] >= tB)) + __popcll(__ballot(uB[3] >= tB));
      if(!dA && cA>=50){ qA=tA; if(cA==50) dA=true; }
      if(!dB && cB>=50){ qB=tB; if(cB==50) dB=true; }
    }
    size_t rowA = (size_t)bh*N_ + (i2+1);
    size_t rowB = (size_t)bh*N_ + (i2+2);
    #pragma unroll
    for(int r=0;r<4;++r){
      bool valid = (r<3) | (lane<5);
      unsigned long long balA = __ballot(valid && (uA[r] >= qA));
      unsigned long long balB = __ballot(valid && (uB[r] >= qB));
      if(lane==0){
        maskw[rowA*8 + 2*r]   = (unsigned)(balA & 0xFFFFFFFFull);
        maskw[rowA*8 + 2*r+1] = (unsigned)(balA>>32);
        maskw[rowB*8 + 2*r]   = (unsigned)(balB & 0xFFFFFFFFull);
        maskw[rowB*8 + 2*r+1] = (unsigned)(balB>>32);
      }
    }
  }
}

// ---------------- basis[r][j] = thresh(|proj_back_n[j][r]|) ----------------
__global__ __launch_bounds__(256) void basis_kernel(const float* __restrict__ pb,
    float* __restrict__ basis){
  int t = blockIdx.x*256 + threadIdx.x;
  if(t < RN_*N_){
    int r = t/N_, j = t%N_;
    float v = fabsf(pb[(size_t)j*RN_ + r]);
    basis[t] = (v > 0.02f) ? v : 0.f;
  }
}

// ---------------- masked attention v3: MFMA flash-style, one block per (b,h) ----------------
__global__ __launch_bounds__(512) void attn3_kernel(const unsigned short* __restrict__ qkv,
    const unsigned int* __restrict__ maskw, unsigned short* __restrict__ attn_out){
  int bh = blockIdx.x; int b = bh/H_, h = bh%H_;
  int tid = threadIdx.x, lane = tid&63, wv = tid>>6;
  int g = lane>>4, c16 = lane&15;
  __shared__ unsigned short Kb[208*64];
  __shared__ unsigned short Vt[64*220];
  __shared__ unsigned short Pl[8*16*224];
  __shared__ unsigned int   Ml[8][16][8];
  const unsigned short* Kbase = qkv + ((size_t)(b*N_)*3 + 1)*C_ + h*CH_;
  const unsigned short* Vbase = qkv + ((size_t)(b*N_)*3 + 2)*C_ + h*CH_;
  for(int idx = tid; idx < 208*32; idx += 512){
    int k = idx>>5, cp = idx&31;
    unsigned pk = 0;
    if(k < N_) pk = *(const unsigned*)(Kbase + (size_t)k*3*C_ + cp*2);
    unsigned off = (unsigned)(k*128 + cp*4) ^ ((unsigned)(k&7)<<4);
    *(unsigned*)((char*)Kb + off) = pk;
  }
  for(int idx = tid; idx < 64*110; idx += 512){
    int kp = idx>>6, c = idx&63;
    int k0 = kp*2, k1 = kp*2+1;
    unsigned v0 = (k0<N_) ? Vbase[(size_t)k0*3*C_ + c] : 0;
    unsigned v1 = (k1<N_) ? Vbase[(size_t)k1*3*C_ + c] : 0;
    *(unsigned*)((char*)Vt + c*440 + kp*4) = v0 | (v1<<16);
  }
  __syncthreads();
  size_t pbase = (size_t)wv*16*448;
  for(int i=lane;i<128;i+=64){
    int ql = i>>3; int kk = 208 + (i&7)*2;
    unsigned off = (unsigned)(ql*448 + kk*2) ^ ((unsigned)(ql&7)<<4);
    *(unsigned*)((char*)Pl + pbase + off) = 0u;
  }
  for(int t = wv; t < 13; t += 8){
    int qb = t*16;
    for(int i = lane; i < 128; i += 64){
      int row = i>>3, word = i&7;
      int qr = qb+row; if(qr>196) qr=196;
      Ml[wv][row][word] = maskw[(size_t)(bh*N_+qr)*8 + word];
    }
    int qrow = qb + c16; if(qrow>196) qrow=196;
    const unsigned short* Qr = qkv + ((size_t)(b*N_+qrow)*3)*C_ + h*CH_ + g*8;
    short8 af[2];
    af[0] = *(const short8*)(Qr);
    af[1] = *(const short8*)(Qr + 32);
    f32x4 sf[13];
    #pragma unroll
    for(int f=0;f<13;++f){
      sf[f] = (f32x4){0.f,0.f,0.f,0.f};
      #pragma unroll
      for(int s=0;s<2;++s){
        int row = f*16 + c16;
        unsigned off = (unsigned)(row*128 + s*64 + g*16) ^ ((unsigned)(row&7)<<4);
        short8 bfr = *(const short8*)((char*)Kb + off);
        sf[f] = __builtin_amdgcn_mfma_f32_16x16x32_bf16(af[s], bfr, sf[f], 0,0,0);
      }
      sf[f][0]*=0.125f; sf[f][1]*=0.125f; sf[f][2]*=0.125f; sf[f][3]*=0.125f;
    }
    unsigned keep[4] = {0,0,0,0};
    float m[4] = {-FLT_MAX,-FLT_MAX,-FLT_MAX,-FLT_MAX};
    #pragma unroll
    for(int f=0;f<13;++f)
      #pragma unroll
      for(int r=0;r<4;++r){
        unsigned bit = (Ml[wv][g*4+r][f>>1] >> ((f&1)*16 + c16)) & 1u;
        keep[r] |= bit<<f;
        if(bit) m[r] = fmaxf(m[r], sf[f][r]);
      }
    #pragma unroll
    for(int r=0;r<4;++r){
      #pragma unroll
      for(int o=8;o>=1;o>>=1) m[r] = fmaxf(m[r], __shfl_xor(m[r], o));
    }
    float sum[4] = {0,0,0,0};
    #pragma unroll
    for(int f=0;f<13;++f)
      #pragma unroll
      for(int r=0;r<4;++r){
        float e = ((keep[r]>>f)&1u) ? expf(sf[f][r]-m[r]) : 0.f;
        sf[f][r] = e; sum[r] += e;
      }
    #pragma unroll
    for(int r=0;r<4;++r){
      #pragma unroll
      for(int o=8;o>=1;o>>=1) sum[r] += __shfl_xor(sum[r], o);
      sum[r] = 1.f/sum[r];
    }
    #pragma unroll
    for(int f=0;f<13;++f)
      #pragma unroll
      for(int r=0;r<4;++r){
        int ql = g*4+r;
        unsigned off = (unsigned)(ql*448 + (f*16+c16)*2) ^ ((unsigned)(ql&7)<<4);
        *(unsigned short*)((char*)Pl + pbase + off) = f2bf(sf[f][r]*sum[r]);
      }
    #pragma unroll
    for(int ct=0;ct<4;++ct){
      f32x4 oa = (f32x4){0.f,0.f,0.f,0.f};
      #pragma unroll
      for(int ks=0;ks<7;++ks){
        unsigned offa = (unsigned)(c16*448 + (ks*32+g*8)*2) ^ ((unsigned)(c16&7)<<4);
        short8 pa = *(const short8*)((char*)Pl + pbase + offa);
        short8 vb = *(const short8*)((char*)Vt + (size_t)(ct*16+c16)*440 + (ks*32+g*8)*2);
        oa = __builtin_amdgcn_mfma_f32_16x16x32_bf16(pa, vb, oa, 0,0,0);
      }
      #pragma unroll
      for(int r=0;r<4;++r){
        int qq = qb + g*4 + r;
        if(qq < N_)
          attn_out[((size_t)(b*N_+qq))*C_ + h*CH_ + ct*16 + c16] = f2bf(oa[r]);
      }
    }
  }
}

extern "C" void kernel_launch(void* const* d_in, const int* in_sizes, int n_in,
                              void* d_out, int out_size, void* d_ws, size_t ws_size,
                              hipStream_t stream){
  const float* x    =(const float*)d_in[0];
  const float* Wqkv =(const float*)d_in[1];
  const float* Wcq  =(const float*)d_in[2];
  const float* bcq  =(const float*)d_in[3];
  const float* Wck  =(const float*)d_in[4];
  const float* bck  =(const float*)d_in[5];
  const float* proj_n=(const float*)d_in[6];
  const float* proj_back_n=(const float*)d_in[7];
  const float* Wproj=(const float*)d_in[8];
  const float* bproj=(const float*)d_in[9];
  const float* g1=(const float*)d_in[10];
  const float* b1=(const float*)d_in[11];
  const float* g2=(const float*)d_in[12];
  const float* b2=(const float*)d_in[13];
  const float* W1=(const float*)d_in[14];
  const float* bfc1=(const float*)d_in[15];
  const float* W2=(const float*)d_in[16];
  const float* bfc2=(const float*)d_in[17];
  float* out=(float*)d_out;

  float* ws=(float*)d_ws;
  size_t off=0;
  unsigned short* hbuf = (unsigned short*)(ws+off); off += (size_t)12608*768/2;
  size_t qkv_off = off;
  unsigned short* qkv = (unsigned short*)(ws+off); off += (size_t)12608*2304/2;
  off += (size_t)768*197*32;   // padding (hidden alias headroom)
  off += (size_t)768*197*32;
  off += (size_t)768*32*24;
  off += (size_t)768*196*24;   // (was coef — now unused)
  float* basis= ws+off;        off += 4736;
  unsigned int* maskw=(unsigned int*)(ws+off); off += (size_t)768*197*8;
  unsigned short* WqkvT = (unsigned short*)(ws+off); off += (size_t)2304*768/2;
  unsigned short* WprojT= (unsigned short*)(ws+off); off += (size_t)768*768/2;
  unsigned short* W1T   = (unsigned short*)(ws+off); off += (size_t)3072*768/2;
  unsigned short* W2T   = (unsigned short*)(ws+off); off += (size_t)768*3072/2;
  unsigned short* WcqT  = (unsigned short*)(ws+off); off += 1024;
  unsigned short* WckT  = (unsigned short*)(ws+off); off += 1024;
  unsigned short* attn_out = hbuf;                    // alias (hbuf dead after qkv GEMM)
  unsigned short* hidden = (unsigned short*)(ws+qkv_off); // alias (qkv dead by MLP)
  float* x1 = out;

  // 0. weight transpose+bf16 conversions
  wtrans_kernel<<<dim3(72,24),256,0,stream>>>(Wqkv, WqkvT, 768, 2304);
  wtrans_kernel<<<dim3(24,24),256,0,stream>>>(Wproj, WprojT, 768, 768);
  wtrans_kernel<<<dim3(96,24),256,0,stream>>>(W1, W1T, 768, 3072);
  wtrans_kernel<<<dim3(24,96),256,0,stream>>>(W2, W2T, 3072, 768);
  wcprep_kernel<<<8,256,0,stream>>>(Wcq, Wck, WcqT, WckT);
  // 1. h = LN(x) -> bf16
  ln_kernel<<<12608,256,0,stream>>>(x,g1,b1,hbuf);
  // 2. qkv = h @ Wqkv (bf16 out)
  gemm256_bf16<0,0,1><<<dim3(18,50),512,0,stream>>>(hbuf,WqkvT,nullptr,nullptr,qkv,12608,768,2304);
  // 3. basis (before fused cheap)
  basis_kernel<<<19,256,0,stream>>>(proj_back_n,basis);
  // 4. fused cheap path v4 (kp/qp + kk + coef + approx_attn + top-50 mask)
  cheap_kernel<<<768,512,0,stream>>>(qkv,WcqT,bcq,WckT,bck,proj_n,basis,maskw);
  // 5. masked attention (MFMA)
  attn3_kernel<<<768,512,0,stream>>>(qkv,maskw,attn_out);
  // 6. x1 = x + attn_out @ Wproj + bproj   (x1 == d_out)
  gemm_bf16<0,1,0><<<dim3(6,99),256,0,stream>>>(attn_out,WprojT,bproj,x,x1,12608,768,768);
  // 7. h2 = LN(x1) -> bf16 (reuse hbuf)
  ln_kernel<<<12608,256,0,stream>>>(x1,g2,b2,hbuf);
  // 8. hidden = gelu(h2 @ W1 + bfc1) -> bf16
  gemm256_bf16<1,0,1><<<dim3(24,50),512,0,stream>>>(hbuf,W1T,bfc1,nullptr,hidden,12608,768,3072);
  // 9. out = x1 + hidden @ W2 + bfc2
  gemm_bf16<0,1,0><<<dim3(6,99),256,0,stream>>>(hidden,W2T,bfc2,x1,out,12608,3072,768);
}

// Round 20
// 666.797 us; speedup vs baseline: 1.0675x; 1.0365x over previous
//
#include <hip/hip_runtime.h>
#include <math.h>
#include <float.h>

#define B_ 64
#define N_ 197
#define C_ 768
#define H_ 12
#define CH_ 64
#define RC_ 32
#define RN_ 24

typedef __attribute__((ext_vector_type(8))) short short8;
typedef __attribute__((ext_vector_type(4))) float f32x4;
typedef __attribute__((address_space(3))) void  lds_void;
typedef __attribute__((address_space(1))) const void g_void;

__device__ __forceinline__ float warp_sum(float v){
  #pragma unroll
  for(int o=32;o>=1;o>>=1) v += __shfl_xor(v,o);
  return v;
}
__device__ __forceinline__ float warp_max(float v){
  #pragma unroll
  for(int o=32;o>=1;o>>=1) v = fmaxf(v,__shfl_xor(v,o));
  return v;
}
__device__ __forceinline__ unsigned short f2bf(float f){
  union{float f; unsigned u;} c; c.f = f;
  unsigned r = c.u + 0x7FFF + ((c.u>>16)&1);
  return (unsigned short)(r>>16);
}
__device__ __forceinline__ float bf2f(unsigned short u){
  union{unsigned u; float f;} c; c.u = ((unsigned)u)<<16; return c.f;
}
// bijective XCD-aware block swizzle (m204)
__device__ __forceinline__ int2 xcd_swz(int gx, int gy){
  int nwg = gx*gy;
  int id = blockIdx.x + gx*blockIdx.y;
  int xcd = id & 7, loc = id >> 3;
  int q = nwg >> 3, r = nwg & 7;
  int swz = (xcd < r ? xcd*(q+1) : r*(q+1) + (xcd-r)*q) + loc;
  return make_int2(swz % gx, swz / gx);
}

// ---------------- LayerNorm: one block per row of 768, bf16 out ----------------
__global__ __launch_bounds__(256) void ln_kernel(const float* __restrict__ x,
    const float* __restrict__ g, const float* __restrict__ bb, unsigned short* __restrict__ out){
  int r = blockIdx.x; int tid = threadIdx.x;
  const float* xr = x + (size_t)r*C_;
  float v0=xr[tid], v1=xr[tid+256], v2=xr[tid+512];
  __shared__ float red[8];
  float s = warp_sum(v0+v1+v2);
  if((tid&63)==0) red[tid>>6]=s;
  __syncthreads();
  float mu = (red[0]+red[1]+red[2]+red[3]) * (1.f/768.f);
  float d0=v0-mu,d1=v1-mu,d2=v2-mu;
  float s2 = warp_sum(d0*d0+d1*d1+d2*d2);
  if((tid&63)==0) red[4+(tid>>6)]=s2;
  __syncthreads();
  float rinv = rsqrtf((red[4]+red[5]+red[6]+red[7])*(1.f/768.f)+1e-5f);
  unsigned short* orow = out + (size_t)r*C_;
  orow[tid]     = f2bf(d0*rinv*g[tid]    +bb[tid]);
  orow[tid+256] = f2bf(d1*rinv*g[tid+256]+bb[tid+256]);
  orow[tid+512] = f2bf(d2*rinv*g[tid+512]+bb[tid+512]);
}

// ---------------- transpose+convert: in f32 [K][N] -> out bf16 [N][K] ----------------
__global__ __launch_bounds__(256) void wtrans_kernel(const float* __restrict__ in,
    unsigned short* __restrict__ out, int K, int N){
  __shared__ float tile[32][33];
  int n0 = blockIdx.x*32, k0 = blockIdx.y*32;
  int tx = threadIdx.x&31, ty = threadIdx.x>>5;
  #pragma unroll
  for(int i=0;i<4;++i) tile[ty+8*i][tx] = in[(size_t)(k0+ty+8*i)*N + n0+tx];
  __syncthreads();
  #pragma unroll
  for(int i=0;i<4;++i) out[(size_t)(n0+ty+8*i)*K + k0+tx] = f2bf(tile[tx][ty+8*i]);
}

// ---------------- Wcq/Wck f32[64][32] -> bf16 transposed [32][64] ----------------
__global__ __launch_bounds__(256) void wcprep_kernel(const float* __restrict__ Wcq,
    const float* __restrict__ Wck, unsigned short* __restrict__ WcqT,
    unsigned short* __restrict__ WckT){
  int t = blockIdx.x*256 + threadIdx.x;
  if(t < 2048){
    int c = t>>6, k = t&63;
    WcqT[t] = f2bf(Wcq[k*32+c]);
    WckT[t] = f2bf(Wck[k*32+c]);
  }
}

// ---------------- bf16 MFMA GEMM 128x128, BK=32, dbuf + XCD swizzle (round-17 proven) ----------------
template<int ACT, int RESID, int OUTBF16>
__global__ __launch_bounds__(256) void gemm_bf16(
    const unsigned short* __restrict__ A, const unsigned short* __restrict__ WT,
    const float* __restrict__ bias, const float* __restrict__ resid,
    void* __restrict__ Cout, int M, int K, int Nc){
  __shared__ unsigned short As[2*128*32];
  __shared__ unsigned short Bs[2*128*32];
  int tid = threadIdx.x, lane = tid&63, wid = tid>>6;
  int2 bxy = xcd_swz(gridDim.x, gridDim.y);
  int m0 = bxy.y*128, n0 = bxy.x*128;
  int wr = wid>>1, wc = wid&1;
  int lm = lane&15, lg = lane>>4;
  int row0 = tid>>2,         kc0 = (tid&3)*8;
  int row1 = (256+tid)>>2,   kc1 = (tid&3)*8;
  int ar0 = m0+row0; if(ar0 > M-1) ar0 = M-1;
  int ar1 = m0+row1; if(ar1 > M-1) ar1 = M-1;
  const unsigned short* gA0 = A  + (size_t)ar0*K + kc0;
  const unsigned short* gA1 = A  + (size_t)ar1*K + kc1;
  const unsigned short* gB0 = WT + (size_t)(n0+row0)*K + kc0;
  const unsigned short* gB1 = WT + (size_t)(n0+row1)*K + kc1;
  unsigned short* lA0 = As + (wid*64)*8;
  unsigned short* lA1 = As + (256 + wid*64)*8;
  unsigned short* lB0 = Bs + (wid*64)*8;
  unsigned short* lB1 = Bs + (256 + wid*64)*8;

#define STAGE_(buf, kt) do{ \
    __builtin_amdgcn_global_load_lds((g_void*)(gA0 + (kt)), (lds_void*)(lA0 + (buf)*4096), 16, 0, 0); \
    __builtin_amdgcn_global_load_lds((g_void*)(gB0 + (kt)), (lds_void*)(lB0 + (buf)*4096), 16, 0, 0); \
    __builtin_amdgcn_global_load_lds((g_void*)(gA1 + (kt)), (lds_void*)(lA1 + (buf)*4096), 16, 0, 0); \
    __builtin_amdgcn_global_load_lds((g_void*)(gB1 + (kt)), (lds_void*)(lB1 + (buf)*4096), 16, 0, 0); \
  }while(0)

  f32x4 acc[4][4] = {};
  const int nt = K/32;
  STAGE_(0, 0);
  __syncthreads();
  for(int t=0; t<nt; t+=2){
    STAGE_(1, (t+1)*32);
    {
      short8 af[4], bfv[4];
      #pragma unroll
      for(int i=0;i<4;++i){
        af[i]  = *(const short8*)(As + (64*wr + 16*i + lm)*32 + lg*8);
        bfv[i] = *(const short8*)(Bs + (64*wc + 16*i + lm)*32 + lg*8);
      }
      #pragma unroll
      for(int i=0;i<4;++i)
        #pragma unroll
        for(int j=0;j<4;++j)
          acc[i][j] = __builtin_amdgcn_mfma_f32_16x16x32_bf16(af[i], bfv[j], acc[i][j], 0,0,0);
    }
    __syncthreads();
    if(t+2 < nt) STAGE_(0, (t+2)*32);
    {
      short8 af[4], bfv[4];
      #pragma unroll
      for(int i=0;i<4;++i){
        af[i]  = *(const short8*)(As + 4096 + (64*wr + 16*i + lm)*32 + lg*8);
        bfv[i] = *(const short8*)(Bs + 4096 + (64*wc + 16*i + lm)*32 + lg*8);
      }
      #pragma unroll
      for(int i=0;i<4;++i)
        #pragma unroll
        for(int j=0;j<4;++j)
          acc[i][j] = __builtin_amdgcn_mfma_f32_16x16x32_bf16(af[i], bfv[j], acc[i][j], 0,0,0);
    }
    __syncthreads();
  }
#undef STAGE_
  #pragma unroll
  for(int i=0;i<4;++i){
    #pragma unroll
    for(int j=0;j<4;++j){
      int gcol = n0 + 64*wc + 16*j + lm;
      float bv = bias ? bias[gcol] : 0.f;
      #pragma unroll
      for(int r=0;r<4;++r){
        int grow = m0 + 64*wr + 16*i + lg*4 + r;
        if(grow < M){
          float cv = acc[i][j][r] + bv;
          if(ACT==1){
            float xx = cv;
            float p = xx*fmaf(xx*xx, 0.10294517f, 2.3022079f);
            float q = exp2f(p);
            cv = xx - xx*__builtin_amdgcn_rcpf(1.0f+q);
          }
          if(RESID) cv += resid[(size_t)grow*Nc + gcol];
          if(OUTBF16) ((unsigned short*)Cout)[(size_t)grow*Nc+gcol] = f2bf(cv);
          else        ((float*)Cout)[(size_t)grow*Nc+gcol] = cv;
        }
      }
    }
  }
}

// ---------------- bf16 MFMA GEMM 256x128, BK=32, 8 waves (4mx2n), dbuf + XCD swizzle ----------------
template<int ACT, int RESID, int OUTBF16>
__global__ __launch_bounds__(512, 4) void gemm256_bf16(
    const unsigned short* __restrict__ A, const unsigned short* __restrict__ WT,
    const float* __restrict__ bias, const float* __restrict__ resid,
    void* __restrict__ Cout, int M, int K, int Nc){
  __shared__ unsigned short As[2*256*32];   // 32 KB
  __shared__ unsigned short Bs[2*128*32];   // 16 KB
  int tid = threadIdx.x, lane = tid&63, wid = tid>>6;
  int2 bxy = xcd_swz(gridDim.x, gridDim.y);
  int m0 = bxy.y*256, n0 = bxy.x*128;
  int wm = wid>>1, wn = wid&1;
  int lm = lane&15, lg = lane>>4;
  int rowA0 = tid>>2, rowA1 = 128 + (tid>>2), rowB = tid>>2;
  int kc = (tid&3)*8;
  int arA0 = m0+rowA0; if(arA0 > M-1) arA0 = M-1;
  int arA1 = m0+rowA1; if(arA1 > M-1) arA1 = M-1;
  const unsigned short* gA0 = A  + (size_t)arA0*K + kc;
  const unsigned short* gA1 = A  + (size_t)arA1*K + kc;
  const unsigned short* gB0 = WT + (size_t)(n0+rowB)*K + kc;
  unsigned short* lA0 = As + wid*512;
  unsigned short* lA1 = As + 4096 + wid*512;
  unsigned short* lB0 = Bs + wid*512;

#define STAGE2_(buf, kt) do{ \
    __builtin_amdgcn_global_load_lds((g_void*)(gA0 + (kt)), (lds_void*)(lA0 + (buf)*8192), 16, 0, 0); \
    __builtin_amdgcn_global_load_lds((g_void*)(gB0 + (kt)), (lds_void*)(lB0 + (buf)*4096), 16, 0, 0); \
    __builtin_amdgcn_global_load_lds((g_void*)(gA1 + (kt)), (lds_void*)(lA1 + (buf)*8192), 16, 0, 0); \
  }while(0)

  f32x4 acc[4][4] = {};
  const int nt = K/32;
  STAGE2_(0, 0);
  __syncthreads();
  for(int t=0; t<nt; ++t){
    int buf = t&1;
    if(t+1 < nt) STAGE2_(buf^1, (t+1)*32);
    const unsigned short* abase = As + buf*8192;
    const unsigned short* bbase = Bs + buf*4096;
    short8 af[4], bfv[4];
    #pragma unroll
    for(int i=0;i<4;++i)
      af[i] = *(const short8*)(abase + (wm*64 + i*16 + lm)*32 + lg*8);
    #pragma unroll
    for(int j=0;j<4;++j)
      bfv[j] = *(const short8*)(bbase + (wn*64 + j*16 + lm)*32 + lg*8);
    __builtin_amdgcn_s_setprio(1);
    #pragma unroll
    for(int i=0;i<4;++i)
      #pragma unroll
      for(int j=0;j<4;++j)
        acc[i][j] = __builtin_amdgcn_mfma_f32_16x16x32_bf16(af[i], bfv[j], acc[i][j], 0,0,0);
    __builtin_amdgcn_s_setprio(0);
    __syncthreads();
  }
#undef STAGE2_
  #pragma unroll
  for(int i=0;i<4;++i){
    #pragma unroll
    for(int j=0;j<4;++j){
      int gcol = n0 + wn*64 + j*16 + lm;
      float bv = bias ? bias[gcol] : 0.f;
      #pragma unroll
      for(int r=0;r<4;++r){
        int grow = m0 + wm*64 + i*16 + lg*4 + r;
        if(grow < M){
          float cv = acc[i][j][r] + bv;
          if(ACT==1){
            float xx = cv;
            float p = xx*fmaf(xx*xx, 0.10294517f, 2.3022079f);
            float q = exp2f(p);
            cv = xx - xx*__builtin_amdgcn_rcpf(1.0f+q);
          }
          if(RESID) cv += resid[(size_t)grow*Nc + gcol];
          if(OUTBF16) ((unsigned short*)Cout)[(size_t)grow*Nc+gcol] = f2bf(cv);
          else        ((float*)Cout)[(size_t)grow*Nc+gcol] = cv;
        }
      }
    }
  }
}

// ---------------- fused cheap path v3: MFMA kp/qp + float4 kk + 2-row coef ----------------
__global__ __launch_bounds__(512) void cheap_kernel(
    const unsigned short* __restrict__ qkv,
    const unsigned short* __restrict__ WcqT, const float* __restrict__ bcq,
    const unsigned short* __restrict__ WckT, const float* __restrict__ bck,
    const float* __restrict__ proj_n, float* __restrict__ coef){
  int bh = blockIdx.x; int b = bh/H_, h = bh%H_;
  int tid = threadIdx.x, lane = tid&63, wv = tid>>6;
  int lm = lane&15, lg = lane>>4;
  __shared__ __align__(16) unsigned short KQ[208*64];
  __shared__ __align__(16) float P2T[32*212];
  __shared__ __align__(16) float PNT[24*200];
  __shared__ float KK[768];
  const unsigned short* Kbase = qkv + ((size_t)(b*N_)*3 + 1)*C_ + h*CH_;
  const unsigned short* Qbase = qkv + ((size_t)(b*N_)*3 + 0)*C_ + h*CH_;
  for(int idx = tid; idx < 208*32; idx += 512){
    int k = idx>>5, cp = idx&31;
    unsigned v = (k < N_) ? *(const unsigned*)(Kbase + (size_t)k*3*C_ + cp*2) : 0u;
    unsigned off = (unsigned)(k*128 + cp*4) ^ ((unsigned)(k&7)<<4);
    *(unsigned*)((char*)KQ + off) = v;
  }
  for(int idx = tid; idx < 24*200; idx += 512){
    int r = idx/200, n = idx - r*200;
    PNT[idx] = (n < N_) ? proj_n[n*24+r] : 0.f;
  }
  __syncthreads();
  {
    short8 bfr[2][2];
    #pragma unroll
    for(int j=0;j<2;++j)
      #pragma unroll
      for(int s=0;s<2;++s)
        bfr[j][s] = *(const short8*)(WckT + (j*16+lm)*64 + s*32 + lg*8);
    float bias[2] = { bck[lm], bck[16+lm] };
    for(int t=wv; t<13; t+=8){
      int row = t*16 + lm;
      unsigned o0 = (unsigned)(row*128 + lg*16) ^ ((unsigned)(row&7)<<4);
      unsigned o1 = (unsigned)(row*128 + 64 + lg*16) ^ ((unsigned)(row&7)<<4);
      short8 a0 = *(const short8*)((char*)KQ + o0);
      short8 a1 = *(const short8*)((char*)KQ + o1);
      #pragma unroll
      for(int j=0;j<2;++j){
        f32x4 acc = (f32x4){0.f,0.f,0.f,0.f};
        acc = __builtin_amdgcn_mfma_f32_16x16x32_bf16(a0, bfr[j][0], acc, 0,0,0);
        acc = __builtin_amdgcn_mfma_f32_16x16x32_bf16(a1, bfr[j][1], acc, 0,0,0);
        #pragma unroll
        for(int r=0;r<4;++r)
          P2T[(j*16+lm)*212 + t*16 + lg*4 + r] = acc[r] + bias[j];
      }
    }
  }
  __syncthreads();
  {
    int i0 = tid, i1 = tid + 512;
    bool has1 = (i1 < 768);
    int c0 = i0/24, r0 = i0 - c0*24;
    int c1 = has1 ? i1/24 : 0, r1 = has1 ? (i1 - (i1/24)*24) : 0;
    float a0=0.f, a1=0.f;
    for(int n=0;n<200;n+=4){
      float4 x0 = *(const float4*)&P2T[c0*212+n];
      float4 p0 = *(const float4*)&PNT[r0*200+n];
      a0 += x0.x*p0.x; a0 += x0.y*p0.y; a0 += x0.z*p0.z; a0 += x0.w*p0.w;
      if(has1){
        float4 x1 = *(const float4*)&P2T[c1*212+n];
        float4 p1 = *(const float4*)&PNT[r1*200+n];
        a1 += x1.x*p1.x; a1 += x1.y*p1.y; a1 += x1.z*p1.z; a1 += x1.w*p1.w;
      }
    }
    KK[i0] = a0;
    if(has1) KK[i1] = a1;
    for(int idx = tid; idx < 197*32; idx += 512){
      int k = idx>>5, cp = idx&31;
      unsigned v = *(const unsigned*)(Qbase + (size_t)k*3*C_ + cp*2);
      unsigned off = (unsigned)(k*128 + cp*4) ^ ((unsigned)(k&7)<<4);
      *(unsigned*)((char*)KQ + off) = v;
    }
  }
  __syncthreads();
  float* QP = P2T;
  {
    short8 bfr[2][2];
    #pragma unroll
    for(int j=0;j<2;++j)
      #pragma unroll
      for(int s=0;s<2;++s)
        bfr[j][s] = *(const short8*)(WcqT + (j*16+lm)*64 + s*32 + lg*8);
    float bias[2] = { bcq[lm], bcq[16+lm] };
    for(int t=wv; t<13; t+=8){
      int row = t*16 + lm;
      unsigned o0 = (unsigned)(row*128 + lg*16) ^ ((unsigned)(row&7)<<4);
      unsigned o1 = (unsigned)(row*128 + 64 + lg*16) ^ ((unsigned)(row&7)<<4);
      short8 a0 = *(const short8*)((char*)KQ + o0);
      short8 a1 = *(const short8*)((char*)KQ + o1);
      #pragma unroll
      for(int j=0;j<2;++j){
        f32x4 acc = (f32x4){0.f,0.f,0.f,0.f};
        acc = __builtin_amdgcn_mfma_f32_16x16x32_bf16(a0, bfr[j][0], acc, 0,0,0);
        acc = __builtin_amdgcn_mfma_f32_16x16x32_bf16(a1, bfr[j][1], acc, 0,0,0);
        #pragma unroll
        for(int r=0;r<4;++r)
          QP[(t*16 + lg*4 + r)*32 + j*16 + lm] = acc[r] + bias[j];
      }
    }
  }
  __syncthreads();
  int l32 = lane & 31, half = lane >> 5;
  bool act = l32 < RN_;
  int ll = act ? l32 : 0;
  float kkreg[32];
  #pragma unroll
  for(int c=0;c<32;++c) kkreg[c] = KK[c*24 + ll];
  for(int i2 = wv*2; i2 < 196; i2 += 16){
    int i = i2 + half;
    int n = i + 1;
    float accv = 0.f;
    #pragma unroll
    for(int q=0;q<8;++q){
      float4 v4 = *(const float4*)&QP[n*32 + q*4];
      accv += v4.x*kkreg[q*4];   accv += v4.y*kkreg[q*4+1];
      accv += v4.z*kkreg[q*4+2]; accv += v4.w*kkreg[q*4+3];
    }
    float val = act ? accv * 0.28867513459481287f : -INFINITY;
    float m = val;
    #pragma unroll
    for(int o=16;o>=1;o>>=1) m = fmaxf(m, __shfl_xor(m, o));
    float e = act ? expf(val - m) : 0.f;
    float ssum = e;
    #pragma unroll
    for(int o=16;o>=1;o>>=1) ssum += __shfl_xor(ssum, o);
    float p = e/ssum;
    unsigned u = __float_as_uint(e);
    unsigned pL=0, pH=0;
    #pragma unroll
    for(int bit=30; bit>=0; --bit){
      unsigned tL = pL | (1u<<bit), tH = pH | (1u<<bit);
      unsigned thr = half ? tH : tL;
      unsigned long long bal = __ballot(u >= thr);
      int cL = __popcll(bal & 0xFFFFFFull);
      int cH = __popcll((bal>>32) & 0xFFFFFFull);
      if(cL>=8) pL=tL;
      if(cH>=8) pH=tH;
    }
    unsigned myp = half ? pH : pL;
    if(act) coef[((size_t)bh*196 + i)*24 + l32] = (u >= myp) ? p : 0.f;
  }
}

// ---------------- basis[r][j] = thresh(|proj_back_n[j][r]|) ----------------
__global__ __launch_bounds__(256) void basis_kernel(const float* __restrict__ pb,
    float* __restrict__ basis){
  int t = blockIdx.x*256 + threadIdx.x;
  if(t < RN_*N_){
    int r = t/N_, j = t%N_;
    float v = fabsf(pb[(size_t)j*RN_ + r]);
    basis[t] = (v > 0.02f) ? v : 0.f;
  }
}

// ---------------- mask v6b: batched dot loads (+residual for ties) + interleaved radix + early exit ----------------
__global__ __launch_bounds__(256) void mask6_kernel(const float* __restrict__ coef,
    const float* __restrict__ basis, unsigned int* __restrict__ maskw){
  __shared__ float Bs[24*256];
  int tid = threadIdx.x, lane = tid&63, wv = tid>>6;
  for(int idx = tid; idx < 24*256; idx += 256){
    int r = idx>>8, q = idx&255;
    int e = ((q&3)<<6) | (q>>2);
    Bs[idx] = (e < N_) ? basis[r*N_ + e] : 0.f;
  }
  __syncthreads();
  int rowbase = blockIdx.x*16 + wv*4;
  float4 av[4];
  unsigned done = 0;
  #pragma unroll
  for(int j=0;j<4;++j){
    int row = rowbase + j;
    int qi = row % N_; int bh = row / N_;
    if(qi==0){
      if(lane<8){
        unsigned v = (lane<6)?0xFFFFFFFFu:((lane==6)?0x1Fu:0u);
        maskw[(size_t)row*8+lane]=v;
      }
      av[j] = make_float4(0.f,0.f,0.f,0.f);
      done |= (1u<<j);
    } else {
      float cfv = (lane<24) ? coef[((size_t)bh*196 + (qi-1))*24 + lane] : 0.f;
      unsigned long long nz = __ballot(cfv != 0.f);
      int rr[8];
      #pragma unroll
      for(int s=0;s<8;++s){
        rr[s] = nz ? (__ffsll(nz)-1) : 64;
        nz &= nz ? (nz - 1) : 0;
      }
      float cc[8]; float4 bv[8];
      #pragma unroll
      for(int s=0;s<8;++s){
        int r = (rr[s] < 64) ? rr[s] : 0;
        float c = __uint_as_float(__builtin_amdgcn_readlane(__float_as_uint(cfv), r));
        cc[s] = (rr[s] < 64) ? c : 0.f;
        bv[s] = *(const float4*)&Bs[r*256 + lane*4];
      }
      float4 a = make_float4(0.f,0.f,0.f,0.f);
      #pragma unroll
      for(int s=0;s<8;++s){
        a.x += cc[s]*bv[s].x; a.y += cc[s]*bv[s].y;
        a.z += cc[s]*bv[s].z; a.w += cc[s]*bv[s].w;
      }
      while(nz){   // rare >8 (tie) case: continue ascending -> bit-identical
        int r = __ffsll(nz)-1; nz &= nz-1;
        float c = __uint_as_float(__builtin_amdgcn_readlane(__float_as_uint(cfv), r));
        float4 b4 = *(const float4*)&Bs[r*256 + lane*4];
        a.x += c*b4.x; a.y += c*b4.y; a.z += c*b4.z; a.w += c*b4.w;
      }
      av[j] = a;
    }
  }
  unsigned u[4][4];
  #pragma unroll
  for(int j=0;j<4;++j){
    u[j][0]=__float_as_uint(av[j].x); u[j][1]=__float_as_uint(av[j].y);
    u[j][2]=__float_as_uint(av[j].z); u[j][3]=__float_as_uint(av[j].w);
  }
  unsigned prefix[4] = {0,0,0,0};
  for(int bit=30; bit>=0; --bit){
    if(done == 0xFu) break;
    #pragma unroll
    for(int j=0;j<4;++j){
      unsigned t = prefix[j] | (1u<<bit);
      int c = __popcll(__ballot(u[j][0] >= t)) + __popcll(__ballot(u[j][1] >= t))
            + __popcll(__ballot(u[j][2] >= t)) + __popcll(__ballot(u[j][3] >= t));
      bool actj = !((done>>j)&1u);
      if(actj && c >= 50) prefix[j] = t;
      if(actj && c == 50) done |= (1u<<j);
    }
  }
  #pragma unroll
  for(int j=0;j<4;++j){
    int row = rowbase + j;
    if(row % N_ == 0) continue;
    #pragma unroll
    for(int r=0;r<4;++r){
      bool valid = (r<3) | (lane<5);
      bool keep = valid && (u[j][r] >= prefix[j]);
      unsigned long long bal = __ballot(keep);
      if(lane==0){
        maskw[(size_t)row*8 + 2*r]   = (unsigned)(bal & 0xFFFFFFFFull);
        maskw[(size_t)row*8 + 2*r+1] = (unsigned)(bal>>32);
      }
    }
  }
}

// ---------------- masked attention v3: MFMA flash-style, one block per (b,h) ----------------
__global__ __launch_bounds__(512) void attn3_kernel(const unsigned short* __restrict__ qkv,
    const unsigned int* __restrict__ maskw, unsigned short* __restrict__ attn_out){
  int bh = blockIdx.x; int b = bh/H_, h = bh%H_;
  int tid = threadIdx.x, lane = tid&63, wv = tid>>6;
  int g = lane>>4, c16 = lane&15;
  __shared__ unsigned short Kb[208*64];
  __shared__ unsigned short Vt[64*220];
  __shared__ unsigned short Pl[8*16*224];
  __shared__ unsigned int   Ml[8][16][8];
  const unsigned short* Kbase = qkv + ((size_t)(b*N_)*3 + 1)*C_ + h*CH_;
  const unsigned short* Vbase = qkv + ((size_t)(b*N_)*3 + 2)*C_ + h*CH_;
  for(int idx = tid; idx < 208*32; idx += 512){
    int k = idx>>5, cp = idx&31;
    unsigned pk = 0;
    if(k < N_) pk = *(const unsigned*)(Kbase + (size_t)k*3*C_ + cp*2);
    unsigned off = (unsigned)(k*128 + cp*4) ^ ((unsigned)(k&7)<<4);
    *(unsigned*)((char*)Kb + off) = pk;
  }
  for(int idx = tid; idx < 64*110; idx += 512){
    int kp = idx>>6, c = idx&63;
    int k0 = kp*2, k1 = kp*2+1;
    unsigned v0 = (k0<N_) ? Vbase[(size_t)k0*3*C_ + c] : 0;
    unsigned v1 = (k1<N_) ? Vbase[(size_t)k1*3*C_ + c] : 0;
    *(unsigned*)((char*)Vt + c*440 + kp*4) = v0 | (v1<<16);
  }
  __syncthreads();
  size_t pbase = (size_t)wv*16*448;
  for(int i=lane;i<128;i+=64){
    int ql = i>>3; int kk = 208 + (i&7)*2;
    unsigned off = (unsigned)(ql*448 + kk*2) ^ ((unsigned)(ql&7)<<4);
    *(unsigned*)((char*)Pl + pbase + off) = 0u;
  }
  for(int t = wv; t < 13; t += 8){
    int qb = t*16;
    for(int i = lane; i < 128; i += 64){
      int row = i>>3, word = i&7;
      int qr = qb+row; if(qr>196) qr=196;
      Ml[wv][row][word] = maskw[(size_t)(bh*N_+qr)*8 + word];
    }
    int qrow = qb + c16; if(qrow>196) qrow=196;
    const unsigned short* Qr = qkv + ((size_t)(b*N_+qrow)*3)*C_ + h*CH_ + g*8;
    short8 af[2];
    af[0] = *(const short8*)(Qr);
    af[1] = *(const short8*)(Qr + 32);
    f32x4 sf[13];
    #pragma unroll
    for(int f=0;f<13;++f){
      sf[f] = (f32x4){0.f,0.f,0.f,0.f};
      #pragma unroll
      for(int s=0;s<2;++s){
        int row = f*16 + c16;
        unsigned off = (unsigned)(row*128 + s*64 + g*16) ^ ((unsigned)(row&7)<<4);
        short8 bfr = *(const short8*)((char*)Kb + off);
        sf[f] = __builtin_amdgcn_mfma_f32_16x16x32_bf16(af[s], bfr, sf[f], 0,0,0);
      }
      sf[f][0]*=0.125f; sf[f][1]*=0.125f; sf[f][2]*=0.125f; sf[f][3]*=0.125f;
    }
    unsigned keep[4] = {0,0,0,0};
    float m[4] = {-FLT_MAX,-FLT_MAX,-FLT_MAX,-FLT_MAX};
    #pragma unroll
    for(int f=0;f<13;++f)
      #pragma unroll
      for(int r=0;r<4;++r){
        unsigned bit = (Ml[wv][g*4+r][f>>1] >> ((f&1)*16 + c16)) & 1u;
        keep[r] |= bit<<f;
        if(bit) m[r] = fmaxf(m[r], sf[f][r]);
      }
    #pragma unroll
    for(int r=0;r<4;++r){
      #pragma unroll
      for(int o=8;o>=1;o>>=1) m[r] = fmaxf(m[r], __shfl_xor(m[r], o));
    }
    float sum[4] = {0,0,0,0};
    #pragma unroll
    for(int f=0;f<13;++f)
      #pragma unroll
      for(int r=0;r<4;++r){
        float e = ((keep[r]>>f)&1u) ? expf(sf[f][r]-m[r]) : 0.f;
        sf[f][r] = e; sum[r] += e;
      }
    #pragma unroll
    for(int r=0;r<4;++r){
      #pragma unroll
      for(int o=8;o>=1;o>>=1) sum[r] += __shfl_xor(sum[r], o);
      sum[r] = 1.f/sum[r];
    }
    #pragma unroll
    for(int f=0;f<13;++f)
      #pragma unroll
      for(int r=0;r<4;++r){
        int ql = g*4+r;
        unsigned off = (unsigned)(ql*448 + (f*16+c16)*2) ^ ((unsigned)(ql&7)<<4);
        *(unsigned short*)((char*)Pl + pbase + off) = f2bf(sf[f][r]*sum[r]);
      }
    #pragma unroll
    for(int ct=0;ct<4;++ct){
      f32x4 oa = (f32x4){0.f,0.f,0.f,0.f};
      #pragma unroll
      for(int ks=0;ks<7;++ks){
        unsigned offa = (unsigned)(c16*448 + (ks*32+g*8)*2) ^ ((unsigned)(c16&7)<<4);
        short8 pa = *(const short8*)((char*)Pl + pbase + offa);
        short8 vb = *(const short8*)((char*)Vt + (size_t)(ct*16+c16)*440 + (ks*32+g*8)*2);
        oa = __builtin_amdgcn_mfma_f32_16x16x32_bf16(pa, vb, oa, 0,0,0);
      }
      #pragma unroll
      for(int r=0;r<4;++r){
        int qq = qb + g*4 + r;
        if(qq < N_)
          attn_out[((size_t)(b*N_+qq))*C_ + h*CH_ + ct*16 + c16] = f2bf(oa[r]);
      }
    }
  }
}

extern "C" void kernel_launch(void* const* d_in, const int* in_sizes, int n_in,
                              void* d_out, int out_size, void* d_ws, size_t ws_size,
                              hipStream_t stream){
  const float* x    =(const float*)d_in[0];
  const float* Wqkv =(const float*)d_in[1];
  const float* Wcq  =(const float*)d_in[2];
  const float* bcq  =(const float*)d_in[3];
  const float* Wck  =(const float*)d_in[4];
  const float* bck  =(const float*)d_in[5];
  const float* proj_n=(const float*)d_in[6];
  const float* proj_back_n=(const float*)d_in[7];
  const float* Wproj=(const float*)d_in[8];
  const float* bproj=(const float*)d_in[9];
  const float* g1=(const float*)d_in[10];
  const float* b1=(const float*)d_in[11];
  const float* g2=(const float*)d_in[12];
  const float* b2=(const float*)d_in[13];
  const float* W1=(const float*)d_in[14];
  const float* bfc1=(const float*)d_in[15];
  const float* W2=(const float*)d_in[16];
  const float* bfc2=(const float*)d_in[17];
  float* out=(float*)d_out;

  float* ws=(float*)d_ws;
  size_t off=0;
  unsigned short* hbuf = (unsigned short*)(ws+off); off += (size_t)12608*768/2;
  size_t qkv_off = off;
  unsigned short* qkv = (unsigned short*)(ws+off); off += (size_t)12608*2304/2;
  off += (size_t)768*197*32;   // padding (hidden alias headroom)
  off += (size_t)768*197*32;
  off += (size_t)768*32*24;
  float* coef = ws+off;        off += (size_t)768*196*24;
  float* basis= ws+off;        off += 4736;
  unsigned int* maskw=(unsigned int*)(ws+off); off += (size_t)768*197*8;
  unsigned short* WqkvT = (unsigned short*)(ws+off); off += (size_t)2304*768/2;
  unsigned short* WprojT= (unsigned short*)(ws+off); off += (size_t)768*768/2;
  unsigned short* W1T   = (unsigned short*)(ws+off); off += (size_t)3072*768/2;
  unsigned short* W2T   = (unsigned short*)(ws+off); off += (size_t)768*3072/2;
  unsigned short* WcqT  = (unsigned short*)(ws+off); off += 1024;
  unsigned short* WckT  = (unsigned short*)(ws+off); off += 1024;
  unsigned short* attn_out = hbuf;                    // alias (hbuf dead after qkv GEMM)
  unsigned short* hidden = (unsigned short*)(ws+qkv_off); // alias (qkv dead by MLP)
  float* x1 = out;

  // 0. weight transpose+bf16 conversions
  wtrans_kernel<<<dim3(72,24),256,0,stream>>>(Wqkv, WqkvT, 768, 2304);
  wtrans_kernel<<<dim3(24,24),256,0,stream>>>(Wproj, WprojT, 768, 768);
  wtrans_kernel<<<dim3(96,24),256,0,stream>>>(W1, W1T, 768, 3072);
  wtrans_kernel<<<dim3(24,96),256,0,stream>>>(W2, W2T, 3072, 768);
  wcprep_kernel<<<8,256,0,stream>>>(Wcq, Wck, WcqT, WckT);
  // 1. h = LN(x) -> bf16
  ln_kernel<<<12608,256,0,stream>>>(x,g1,b1,hbuf);
  // 2. qkv = h @ Wqkv (bf16 out)
  gemm256_bf16<0,0,1><<<dim3(18,50),512,0,stream>>>(hbuf,WqkvT,nullptr,nullptr,qkv,12608,768,2304);
  // 3. fused cheap path v3 (MFMA kp/qp)
  cheap_kernel<<<768,512,0,stream>>>(qkv,WcqT,bcq,WckT,bck,proj_n,coef);
  // 4. basis
  basis_kernel<<<19,256,0,stream>>>(proj_back_n,basis);
  // 5. approx_attn + budget mask (batched-load dot + interleaved radix + early exit)
  mask6_kernel<<<9456,256,0,stream>>>(coef,basis,maskw);
  // 6. masked attention (MFMA)
  attn3_kernel<<<768,512,0,stream>>>(qkv,maskw,attn_out);
  // 7. x1 = x + attn_out @ Wproj + bproj   (x1 == d_out)
  gemm_bf16<0,1,0><<<dim3(6,99),256,0,stream>>>(attn_out,WprojT,bproj,x,x1,12608,768,768);
  // 8. h2 = LN(x1) -> bf16 (reuse hbuf)
  ln_kernel<<<12608,256,0,stream>>>(x1,g2,b2,hbuf);
  // 9. hidden = gelu(h2 @ W1 + bfc1) -> bf16
  gemm256_bf16<1,0,1><<<dim3(24,50),512,0,stream>>>(hbuf,W1T,bfc1,nullptr,hidden,12608,768,3072);
  // 10. out = x1 + hidden @ W2 + bfc2
  gemm_bf16<0,1,0><<<dim3(6,99),256,0,stream>>>(hidden,W2T,bfc2,x1,out,12608,3072,768);
}

// Round 21
// 652.877 us; speedup vs baseline: 1.0902x; 1.0213x over previous
//
#include <hip/hip_runtime.h>
#include <math.h>
#include <float.h>

#define B_ 64
#define N_ 197
#define C_ 768
#define H_ 12
#define CH_ 64
#define RC_ 32
#define RN_ 24

typedef __attribute__((ext_vector_type(8))) short short8;
typedef __attribute__((ext_vector_type(4))) float f32x4;
typedef __attribute__((address_space(3))) void  lds_void;
typedef __attribute__((address_space(1))) const void g_void;

__device__ __forceinline__ float warp_sum(float v){
  #pragma unroll
  for(int o=32;o>=1;o>>=1) v += __shfl_xor(v,o);
  return v;
}
__device__ __forceinline__ float warp_max(float v){
  #pragma unroll
  for(int o=32;o>=1;o>>=1) v = fmaxf(v,__shfl_xor(v,o));
  return v;
}
__device__ __forceinline__ unsigned short f2bf(float f){
  union{float f; unsigned u;} c; c.f = f;
  unsigned r = c.u + 0x7FFF + ((c.u>>16)&1);
  return (unsigned short)(r>>16);
}
__device__ __forceinline__ float bf2f(unsigned short u){
  union{unsigned u; float f;} c; c.u = ((unsigned)u)<<16; return c.f;
}
// bijective XCD-aware block swizzle (m204)
__device__ __forceinline__ int2 xcd_swz(int gx, int gy){
  int nwg = gx*gy;
  int id = blockIdx.x + gx*blockIdx.y;
  int xcd = id & 7, loc = id >> 3;
  int q = nwg >> 3, r = nwg & 7;
  int swz = (xcd < r ? xcd*(q+1) : r*(q+1) + (xcd-r)*q) + loc;
  return make_int2(swz % gx, swz / gx);
}

// ---------------- LayerNorm: one block per row of 768, bf16 out ----------------
__global__ __launch_bounds__(256) void ln_kernel(const float* __restrict__ x,
    const float* __restrict__ g, const float* __restrict__ bb, unsigned short* __restrict__ out){
  int r = blockIdx.x; int tid = threadIdx.x;
  const float* xr = x + (size_t)r*C_;
  float v0=xr[tid], v1=xr[tid+256], v2=xr[tid+512];
  __shared__ float red[8];
  float s = warp_sum(v0+v1+v2);
  if((tid&63)==0) red[tid>>6]=s;
  __syncthreads();
  float mu = (red[0]+red[1]+red[2]+red[3]) * (1.f/768.f);
  float d0=v0-mu,d1=v1-mu,d2=v2-mu;
  float s2 = warp_sum(d0*d0+d1*d1+d2*d2);
  if((tid&63)==0) red[4+(tid>>6)]=s2;
  __syncthreads();
  float rinv = rsqrtf((red[4]+red[5]+red[6]+red[7])*(1.f/768.f)+1e-5f);
  unsigned short* orow = out + (size_t)r*C_;
  orow[tid]     = f2bf(d0*rinv*g[tid]    +bb[tid]);
  orow[tid+256] = f2bf(d1*rinv*g[tid+256]+bb[tid+256]);
  orow[tid+512] = f2bf(d2*rinv*g[tid+512]+bb[tid+512]);
}

// ---------------- transpose+convert: in f32 [K][N] -> out bf16 [N][K] ----------------
__global__ __launch_bounds__(256) void wtrans_kernel(const float* __restrict__ in,
    unsigned short* __restrict__ out, int K, int N){
  __shared__ float tile[32][33];
  int n0 = blockIdx.x*32, k0 = blockIdx.y*32;
  int tx = threadIdx.x&31, ty = threadIdx.x>>5;
  #pragma unroll
  for(int i=0;i<4;++i) tile[ty+8*i][tx] = in[(size_t)(k0+ty+8*i)*N + n0+tx];
  __syncthreads();
  #pragma unroll
  for(int i=0;i<4;++i) out[(size_t)(n0+ty+8*i)*K + k0+tx] = f2bf(tile[tx][ty+8*i]);
}

// ---------------- Wcq/Wck f32[64][32] -> bf16 transposed [32][64] ----------------
__global__ __launch_bounds__(256) void wcprep_kernel(const float* __restrict__ Wcq,
    const float* __restrict__ Wck, unsigned short* __restrict__ WcqT,
    unsigned short* __restrict__ WckT){
  int t = blockIdx.x*256 + threadIdx.x;
  if(t < 2048){
    int c = t>>6, k = t&63;
    WcqT[t] = f2bf(Wcq[k*32+c]);
    WckT[t] = f2bf(Wck[k*32+c]);
  }
}

// ---------------- bf16 MFMA GEMM 128x128, BK=32, dbuf + XCD swizzle (round-17 proven) ----------------
template<int ACT, int RESID, int OUTBF16>
__global__ __launch_bounds__(256) void gemm_bf16(
    const unsigned short* __restrict__ A, const unsigned short* __restrict__ WT,
    const float* __restrict__ bias, const float* __restrict__ resid,
    void* __restrict__ Cout, int M, int K, int Nc){
  __shared__ unsigned short As[2*128*32];
  __shared__ unsigned short Bs[2*128*32];
  int tid = threadIdx.x, lane = tid&63, wid = tid>>6;
  int2 bxy = xcd_swz(gridDim.x, gridDim.y);
  int m0 = bxy.y*128, n0 = bxy.x*128;
  int wr = wid>>1, wc = wid&1;
  int lm = lane&15, lg = lane>>4;
  int row0 = tid>>2,         kc0 = (tid&3)*8;
  int row1 = (256+tid)>>2,   kc1 = (tid&3)*8;
  int ar0 = m0+row0; if(ar0 > M-1) ar0 = M-1;
  int ar1 = m0+row1; if(ar1 > M-1) ar1 = M-1;
  const unsigned short* gA0 = A  + (size_t)ar0*K + kc0;
  const unsigned short* gA1 = A  + (size_t)ar1*K + kc1;
  const unsigned short* gB0 = WT + (size_t)(n0+row0)*K + kc0;
  const unsigned short* gB1 = WT + (size_t)(n0+row1)*K + kc1;
  unsigned short* lA0 = As + (wid*64)*8;
  unsigned short* lA1 = As + (256 + wid*64)*8;
  unsigned short* lB0 = Bs + (wid*64)*8;
  unsigned short* lB1 = Bs + (256 + wid*64)*8;

#define STAGE_(buf, kt) do{ \
    __builtin_amdgcn_global_load_lds((g_void*)(gA0 + (kt)), (lds_void*)(lA0 + (buf)*4096), 16, 0, 0); \
    __builtin_amdgcn_global_load_lds((g_void*)(gB0 + (kt)), (lds_void*)(lB0 + (buf)*4096), 16, 0, 0); \
    __builtin_amdgcn_global_load_lds((g_void*)(gA1 + (kt)), (lds_void*)(lA1 + (buf)*4096), 16, 0, 0); \
    __builtin_amdgcn_global_load_lds((g_void*)(gB1 + (kt)), (lds_void*)(lB1 + (buf)*4096), 16, 0, 0); \
  }while(0)

  f32x4 acc[4][4] = {};
  const int nt = K/32;
  STAGE_(0, 0);
  __syncthreads();
  for(int t=0; t<nt; t+=2){
    STAGE_(1, (t+1)*32);
    {
      short8 af[4], bfv[4];
      #pragma unroll
      for(int i=0;i<4;++i){
        af[i]  = *(const short8*)(As + (64*wr + 16*i + lm)*32 + lg*8);
        bfv[i] = *(const short8*)(Bs + (64*wc + 16*i + lm)*32 + lg*8);
      }
      #pragma unroll
      for(int i=0;i<4;++i)
        #pragma unroll
        for(int j=0;j<4;++j)
          acc[i][j] = __builtin_amdgcn_mfma_f32_16x16x32_bf16(af[i], bfv[j], acc[i][j], 0,0,0);
    }
    __syncthreads();
    if(t+2 < nt) STAGE_(0, (t+2)*32);
    {
      short8 af[4], bfv[4];
      #pragma unroll
      for(int i=0;i<4;++i){
        af[i]  = *(const short8*)(As + 4096 + (64*wr + 16*i + lm)*32 + lg*8);
        bfv[i] = *(const short8*)(Bs + 4096 + (64*wc + 16*i + lm)*32 + lg*8);
      }
      #pragma unroll
      for(int i=0;i<4;++i)
        #pragma unroll
        for(int j=0;j<4;++j)
          acc[i][j] = __builtin_amdgcn_mfma_f32_16x16x32_bf16(af[i], bfv[j], acc[i][j], 0,0,0);
    }
    __syncthreads();
  }
#undef STAGE_
  #pragma unroll
  for(int i=0;i<4;++i){
    #pragma unroll
    for(int j=0;j<4;++j){
      int gcol = n0 + 64*wc + 16*j + lm;
      float bv = bias ? bias[gcol] : 0.f;
      #pragma unroll
      for(int r=0;r<4;++r){
        int grow = m0 + 64*wr + 16*i + lg*4 + r;
        if(grow < M){
          float cv = acc[i][j][r] + bv;
          if(ACT==1){
            float xx = cv;
            float p = xx*fmaf(xx*xx, 0.10294517f, 2.3022079f);
            float q = exp2f(p);
            cv = xx - xx*__builtin_amdgcn_rcpf(1.0f+q);
          }
          if(RESID) cv += resid[(size_t)grow*Nc + gcol];
          if(OUTBF16) ((unsigned short*)Cout)[(size_t)grow*Nc+gcol] = f2bf(cv);
          else        ((float*)Cout)[(size_t)grow*Nc+gcol] = cv;
        }
      }
    }
  }
}

// ---------------- bf16 MFMA GEMM 256x128, BK=32, 8 waves (4mx2n), dbuf + XCD swizzle ----------------
template<int ACT, int RESID, int OUTBF16>
__global__ __launch_bounds__(512, 4) void gemm256_bf16(
    const unsigned short* __restrict__ A, const unsigned short* __restrict__ WT,
    const float* __restrict__ bias, const float* __restrict__ resid,
    void* __restrict__ Cout, int M, int K, int Nc){
  __shared__ unsigned short As[2*256*32];   // 32 KB
  __shared__ unsigned short Bs[2*128*32];   // 16 KB
  int tid = threadIdx.x, lane = tid&63, wid = tid>>6;
  int2 bxy = xcd_swz(gridDim.x, gridDim.y);
  int m0 = bxy.y*256, n0 = bxy.x*128;
  int wm = wid>>1, wn = wid&1;
  int lm = lane&15, lg = lane>>4;
  int rowA0 = tid>>2, rowA1 = 128 + (tid>>2), rowB = tid>>2;
  int kc = (tid&3)*8;
  int arA0 = m0+rowA0; if(arA0 > M-1) arA0 = M-1;
  int arA1 = m0+rowA1; if(arA1 > M-1) arA1 = M-1;
  const unsigned short* gA0 = A  + (size_t)arA0*K + kc;
  const unsigned short* gA1 = A  + (size_t)arA1*K + kc;
  const unsigned short* gB0 = WT + (size_t)(n0+rowB)*K + kc;
  unsigned short* lA0 = As + wid*512;
  unsigned short* lA1 = As + 4096 + wid*512;
  unsigned short* lB0 = Bs + wid*512;

#define STAGE2_(buf, kt) do{ \
    __builtin_amdgcn_global_load_lds((g_void*)(gA0 + (kt)), (lds_void*)(lA0 + (buf)*8192), 16, 0, 0); \
    __builtin_amdgcn_global_load_lds((g_void*)(gB0 + (kt)), (lds_void*)(lB0 + (buf)*4096), 16, 0, 0); \
    __builtin_amdgcn_global_load_lds((g_void*)(gA1 + (kt)), (lds_void*)(lA1 + (buf)*8192), 16, 0, 0); \
  }while(0)

  f32x4 acc[4][4] = {};
  const int nt = K/32;
  STAGE2_(0, 0);
  __syncthreads();
  for(int t=0; t<nt; ++t){
    int buf = t&1;
    if(t+1 < nt) STAGE2_(buf^1, (t+1)*32);
    const unsigned short* abase = As + buf*8192;
    const unsigned short* bbase = Bs + buf*4096;
    short8 af[4], bfv[4];
    #pragma unroll
    for(int i=0;i<4;++i)
      af[i] = *(const short8*)(abase + (wm*64 + i*16 + lm)*32 + lg*8);
    #pragma unroll
    for(int j=0;j<4;++j)
      bfv[j] = *(const short8*)(bbase + (wn*64 + j*16 + lm)*32 + lg*8);
    __builtin_amdgcn_s_setprio(1);
    #pragma unroll
    for(int i=0;i<4;++i)
      #pragma unroll
      for(int j=0;j<4;++j)
        acc[i][j] = __builtin_amdgcn_mfma_f32_16x16x32_bf16(af[i], bfv[j], acc[i][j], 0,0,0);
    __builtin_amdgcn_s_setprio(0);
    __syncthreads();
  }
#undef STAGE2_
  #pragma unroll
  for(int i=0;i<4;++i){
    #pragma unroll
    for(int j=0;j<4;++j){
      int gcol = n0 + wn*64 + j*16 + lm;
      float bv = bias ? bias[gcol] : 0.f;
      #pragma unroll
      for(int r=0;r<4;++r){
        int grow = m0 + wm*64 + i*16 + lg*4 + r;
        if(grow < M){
          float cv = acc[i][j][r] + bv;
          if(ACT==1){
            float xx = cv;
            float p = xx*fmaf(xx*xx, 0.10294517f, 2.3022079f);
            float q = exp2f(p);
            cv = xx - xx*__builtin_amdgcn_rcpf(1.0f+q);
          }
          if(RESID) cv += resid[(size_t)grow*Nc + gcol];
          if(OUTBF16) ((unsigned short*)Cout)[(size_t)grow*Nc+gcol] = f2bf(cv);
          else        ((float*)Cout)[(size_t)grow*Nc+gcol] = cv;
        }
      }
    }
  }
}

// ---------------- fused cheap path v3: MFMA kp/qp + float4 kk + 2-row coef ----------------
__global__ __launch_bounds__(512) void cheap_kernel(
    const unsigned short* __restrict__ qkv,
    const unsigned short* __restrict__ WcqT, const float* __restrict__ bcq,
    const unsigned short* __restrict__ WckT, const float* __restrict__ bck,
    const float* __restrict__ proj_n, float* __restrict__ coef){
  int bh = blockIdx.x; int b = bh/H_, h = bh%H_;
  int tid = threadIdx.x, lane = tid&63, wv = tid>>6;
  int lm = lane&15, lg = lane>>4;
  __shared__ __align__(16) unsigned short KQ[208*64];
  __shared__ __align__(16) float P2T[32*212];
  __shared__ __align__(16) float PNT[24*200];
  __shared__ float KK[768];
  const unsigned short* Kbase = qkv + ((size_t)(b*N_)*3 + 1)*C_ + h*CH_;
  const unsigned short* Qbase = qkv + ((size_t)(b*N_)*3 + 0)*C_ + h*CH_;
  for(int idx = tid; idx < 208*32; idx += 512){
    int k = idx>>5, cp = idx&31;
    unsigned v = (k < N_) ? *(const unsigned*)(Kbase + (size_t)k*3*C_ + cp*2) : 0u;
    unsigned off = (unsigned)(k*128 + cp*4) ^ ((unsigned)(k&7)<<4);
    *(unsigned*)((char*)KQ + off) = v;
  }
  for(int idx = tid; idx < 24*200; idx += 512){
    int r = idx/200, n = idx - r*200;
    PNT[idx] = (n < N_) ? proj_n[n*24+r] : 0.f;
  }
  __syncthreads();
  {
    short8 bfr[2][2];
    #pragma unroll
    for(int j=0;j<2;++j)
      #pragma unroll
      for(int s=0;s<2;++s)
        bfr[j][s] = *(const short8*)(WckT + (j*16+lm)*64 + s*32 + lg*8);
    float bias[2] = { bck[lm], bck[16+lm] };
    for(int t=wv; t<13; t+=8){
      int row = t*16 + lm;
      unsigned o0 = (unsigned)(row*128 + lg*16) ^ ((unsigned)(row&7)<<4);
      unsigned o1 = (unsigned)(row*128 + 64 + lg*16) ^ ((unsigned)(row&7)<<4);
      short8 a0 = *(const short8*)((char*)KQ + o0);
      short8 a1 = *(const short8*)((char*)KQ + o1);
      #pragma unroll
      for(int j=0;j<2;++j){
        f32x4 acc = (f32x4){0.f,0.f,0.f,0.f};
        acc = __builtin_amdgcn_mfma_f32_16x16x32_bf16(a0, bfr[j][0], acc, 0,0,0);
        acc = __builtin_amdgcn_mfma_f32_16x16x32_bf16(a1, bfr[j][1], acc, 0,0,0);
        #pragma unroll
        for(int r=0;r<4;++r)
          P2T[(j*16+lm)*212 + t*16 + lg*4 + r] = acc[r] + bias[j];
      }
    }
  }
  __syncthreads();
  {
    int i0 = tid, i1 = tid + 512;
    bool has1 = (i1 < 768);
    int c0 = i0/24, r0 = i0 - c0*24;
    int c1 = has1 ? i1/24 : 0, r1 = has1 ? (i1 - (i1/24)*24) : 0;
    float a0=0.f, a1=0.f;
    for(int n=0;n<200;n+=4){
      float4 x0 = *(const float4*)&P2T[c0*212+n];
      float4 p0 = *(const float4*)&PNT[r0*200+n];
      a0 += x0.x*p0.x; a0 += x0.y*p0.y; a0 += x0.z*p0.z; a0 += x0.w*p0.w;
      if(has1){
        float4 x1 = *(const float4*)&P2T[c1*212+n];
        float4 p1 = *(const float4*)&PNT[r1*200+n];
        a1 += x1.x*p1.x; a1 += x1.y*p1.y; a1 += x1.z*p1.z; a1 += x1.w*p1.w;
      }
    }
    KK[i0] = a0;
    if(has1) KK[i1] = a1;
    for(int idx = tid; idx < 197*32; idx += 512){
      int k = idx>>5, cp = idx&31;
      unsigned v = *(const unsigned*)(Qbase + (size_t)k*3*C_ + cp*2);
      unsigned off = (unsigned)(k*128 + cp*4) ^ ((unsigned)(k&7)<<4);
      *(unsigned*)((char*)KQ + off) = v;
    }
  }
  __syncthreads();
  float* QP = P2T;
  {
    short8 bfr[2][2];
    #pragma unroll
    for(int j=0;j<2;++j)
      #pragma unroll
      for(int s=0;s<2;++s)
        bfr[j][s] = *(const short8*)(WcqT + (j*16+lm)*64 + s*32 + lg*8);
    float bias[2] = { bcq[lm], bcq[16+lm] };
    for(int t=wv; t<13; t+=8){
      int row = t*16 + lm;
      unsigned o0 = (unsigned)(row*128 + lg*16) ^ ((unsigned)(row&7)<<4);
      unsigned o1 = (unsigned)(row*128 + 64 + lg*16) ^ ((unsigned)(row&7)<<4);
      short8 a0 = *(const short8*)((char*)KQ + o0);
      short8 a1 = *(const short8*)((char*)KQ + o1);
      #pragma unroll
      for(int j=0;j<2;++j){
        f32x4 acc = (f32x4){0.f,0.f,0.f,0.f};
        acc = __builtin_amdgcn_mfma_f32_16x16x32_bf16(a0, bfr[j][0], acc, 0,0,0);
        acc = __builtin_amdgcn_mfma_f32_16x16x32_bf16(a1, bfr[j][1], acc, 0,0,0);
        #pragma unroll
        for(int r=0;r<4;++r)
          QP[(t*16 + lg*4 + r)*32 + j*16 + lm] = acc[r] + bias[j];
      }
    }
  }
  __syncthreads();
  int l32 = lane & 31, half = lane >> 5;
  bool act = l32 < RN_;
  int ll = act ? l32 : 0;
  float kkreg[32];
  #pragma unroll
  for(int c=0;c<32;++c) kkreg[c] = KK[c*24 + ll];
  for(int i2 = wv*2; i2 < 196; i2 += 16){
    int i = i2 + half;
    int n = i + 1;
    float accv = 0.f;
    #pragma unroll
    for(int q=0;q<8;++q){
      float4 v4 = *(const float4*)&QP[n*32 + q*4];
      accv += v4.x*kkreg[q*4];   accv += v4.y*kkreg[q*4+1];
      accv += v4.z*kkreg[q*4+2]; accv += v4.w*kkreg[q*4+3];
    }
    float val = act ? accv * 0.28867513459481287f : -INFINITY;
    float m = val;
    #pragma unroll
    for(int o=16;o>=1;o>>=1) m = fmaxf(m, __shfl_xor(m, o));
    float e = act ? expf(val - m) : 0.f;
    float ssum = e;
    #pragma unroll
    for(int o=16;o>=1;o>>=1) ssum += __shfl_xor(ssum, o);
    float p = e/ssum;
    unsigned u = __float_as_uint(e);
    unsigned pL=0, pH=0;
    #pragma unroll
    for(int bit=30; bit>=0; --bit){
      unsigned tL = pL | (1u<<bit), tH = pH | (1u<<bit);
      unsigned thr = half ? tH : tL;
      unsigned long long bal = __ballot(u >= thr);
      int cL = __popcll(bal & 0xFFFFFFull);
      int cH = __popcll((bal>>32) & 0xFFFFFFull);
      if(cL>=8) pL=tL;
      if(cH>=8) pH=tH;
    }
    unsigned myp = half ? pH : pL;
    if(act) coef[((size_t)bh*196 + i)*24 + l32] = (u >= myp) ? p : 0.f;
  }
}

// ---------------- basis[r][j] = thresh(|proj_back_n[j][r]|) ----------------
__global__ __launch_bounds__(256) void basis_kernel(const float* __restrict__ pb,
    float* __restrict__ basis){
  int t = blockIdx.x*256 + threadIdx.x;
  if(t < RN_*N_){
    int r = t/N_, j = t%N_;
    float v = fabsf(pb[(size_t)j*RN_ + r]);
    basis[t] = (v > 0.02f) ? v : 0.f;
  }
}

// ---------------- mask v7: 8 rows per wave (mask5 dot + deep-interleaved radix) ----------------
// 8 independent radix chains per wave -> 32 ballots/step hides the step latency.
// Selection semantics identical to mask5 (greedy compare-radix + ==50 early exit).
__global__ __launch_bounds__(256) void mask7_kernel(const float* __restrict__ coef,
    const float* __restrict__ basis, unsigned int* __restrict__ maskw){
  __shared__ float Bs[24*256];
  int tid = threadIdx.x, lane = tid&63, wv = tid>>6;
  for(int idx = tid; idx < 24*256; idx += 256){
    int r = idx>>8, q = idx&255;
    int e = ((q&3)<<6) | (q>>2);
    Bs[idx] = (e < N_) ? basis[r*N_ + e] : 0.f;
  }
  __syncthreads();
  int rowbase = blockIdx.x*32 + wv*8;     // 4728 blocks * 32 rows = 151296
  float4 av[8];
  unsigned done = 0;
  #pragma unroll
  for(int j=0;j<8;++j){
    int row = rowbase + j;
    int qi = row % N_; int bh = row / N_;
    if(qi==0){
      if(lane<8){
        unsigned v = (lane<6)?0xFFFFFFFFu:((lane==6)?0x1Fu:0u);
        maskw[(size_t)row*8+lane]=v;
      }
      av[j] = make_float4(0.f,0.f,0.f,0.f);
      done |= (1u<<j);
    } else {
      float cfv = (lane<24) ? coef[((size_t)bh*196 + (qi-1))*24 + lane] : 0.f;
      unsigned long long nz = __ballot(cfv != 0.f);
      float4 a = make_float4(0.f,0.f,0.f,0.f);
      while(nz){
        int r = __ffsll((unsigned long long)nz) - 1;
        nz &= nz - 1;
        float c = __uint_as_float(__builtin_amdgcn_readlane(__float_as_uint(cfv), r));
        float4 bv = *(const float4*)&Bs[r*256 + lane*4];
        a.x += c*bv.x; a.y += c*bv.y; a.z += c*bv.z; a.w += c*bv.w;
      }
      av[j] = a;
    }
  }
  unsigned u[8][4];
  #pragma unroll
  for(int j=0;j<8;++j){
    u[j][0]=__float_as_uint(av[j].x); u[j][1]=__float_as_uint(av[j].y);
    u[j][2]=__float_as_uint(av[j].z); u[j][3]=__float_as_uint(av[j].w);
  }
  unsigned prefix[8] = {0,0,0,0,0,0,0,0};
  for(int bit=30; bit>=0; --bit){
    if(done == 0xFFu) break;
    #pragma unroll
    for(int j=0;j<8;++j){
      unsigned t = prefix[j] | (1u<<bit);
      int c = __popcll(__ballot(u[j][0] >= t)) + __popcll(__ballot(u[j][1] >= t))
            + __popcll(__ballot(u[j][2] >= t)) + __popcll(__ballot(u[j][3] >= t));
      bool actj = !((done>>j)&1u);
      if(actj && c >= 50) prefix[j] = t;
      if(actj && c == 50) done |= (1u<<j);
    }
  }
  #pragma unroll
  for(int j=0;j<8;++j){
    int row = rowbase + j;
    if(row % N_ == 0) continue;
    #pragma unroll
    for(int r=0;r<4;++r){
      bool valid = (r<3) | (lane<5);
      bool keep = valid && (u[j][r] >= prefix[j]);
      unsigned long long bal = __ballot(keep);
      if(lane==0){
        maskw[(size_t)row*8 + 2*r]   = (unsigned)(bal & 0xFFFFFFFFull);
        maskw[(size_t)row*8 + 2*r+1] = (unsigned)(bal>>32);
      }
    }
  }
}

// ---------------- masked attention v3: MFMA flash-style, one block per (b,h) ----------------
__global__ __launch_bounds__(512) void attn3_kernel(const unsigned short* __restrict__ qkv,
    const unsigned int* __restrict__ maskw, unsigned short* __restrict__ attn_out){
  int bh = blockIdx.x; int b = bh/H_, h = bh%H_;
  int tid = threadIdx.x, lane = tid&63, wv = tid>>6;
  int g = lane>>4, c16 = lane&15;
  __shared__ unsigned short Kb[208*64];
  __shared__ unsigned short Vt[64*220];
  __shared__ unsigned short Pl[8*16*224];
  __shared__ unsigned int   Ml[8][16][8];
  const unsigned short* Kbase = qkv + ((size_t)(b*N_)*3 + 1)*C_ + h*CH_;
  const unsigned short* Vbase = qkv + ((size_t)(b*N_)*3 + 2)*C_ + h*CH_;
  for(int idx = tid; idx < 208*32; idx += 512){
    int k = idx>>5, cp = idx&31;
    unsigned pk = 0;
    if(k < N_) pk = *(const unsigned*)(Kbase + (size_t)k*3*C_ + cp*2);
    unsigned off = (unsigned)(k*128 + cp*4) ^ ((unsigned)(k&7)<<4);
    *(unsigned*)((char*)Kb + off) = pk;
  }
  for(int idx = tid; idx < 64*110; idx += 512){
    int kp = idx>>6, c = idx&63;
    int k0 = kp*2, k1 = kp*2+1;
    unsigned v0 = (k0<N_) ? Vbase[(size_t)k0*3*C_ + c] : 0;
    unsigned v1 = (k1<N_) ? Vbase[(size_t)k1*3*C_ + c] : 0;
    *(unsigned*)((char*)Vt + c*440 + kp*4) = v0 | (v1<<16);
  }
  __syncthreads();
  size_t pbase = (size_t)wv*16*448;
  for(int i=lane;i<128;i+=64){
    int ql = i>>3; int kk = 208 + (i&7)*2;
    unsigned off = (unsigned)(ql*448 + kk*2) ^ ((unsigned)(ql&7)<<4);
    *(unsigned*)((char*)Pl + pbase + off) = 0u;
  }
  for(int t = wv; t < 13; t += 8){
    int qb = t*16;
    for(int i = lane; i < 128; i += 64){
      int row = i>>3, word = i&7;
      int qr = qb+row; if(qr>196) qr=196;
      Ml[wv][row][word] = maskw[(size_t)(bh*N_+qr)*8 + word];
    }
    int qrow = qb + c16; if(qrow>196) qrow=196;
    const unsigned short* Qr = qkv + ((size_t)(b*N_+qrow)*3)*C_ + h*CH_ + g*8;
    short8 af[2];
    af[0] = *(const short8*)(Qr);
    af[1] = *(const short8*)(Qr + 32);
    f32x4 sf[13];
    #pragma unroll
    for(int f=0;f<13;++f){
      sf[f] = (f32x4){0.f,0.f,0.f,0.f};
      #pragma unroll
      for(int s=0;s<2;++s){
        int row = f*16 + c16;
        unsigned off = (unsigned)(row*128 + s*64 + g*16) ^ ((unsigned)(row&7)<<4);
        short8 bfr = *(const short8*)((char*)Kb + off);
        sf[f] = __builtin_amdgcn_mfma_f32_16x16x32_bf16(af[s], bfr, sf[f], 0,0,0);
      }
      sf[f][0]*=0.125f; sf[f][1]*=0.125f; sf[f][2]*=0.125f; sf[f][3]*=0.125f;
    }
    unsigned keep[4] = {0,0,0,0};
    float m[4] = {-FLT_MAX,-FLT_MAX,-FLT_MAX,-FLT_MAX};
    #pragma unroll
    for(int f=0;f<13;++f)
      #pragma unroll
      for(int r=0;r<4;++r){
        unsigned bit = (Ml[wv][g*4+r][f>>1] >> ((f&1)*16 + c16)) & 1u;
        keep[r] |= bit<<f;
        if(bit) m[r] = fmaxf(m[r], sf[f][r]);
      }
    #pragma unroll
    for(int r=0;r<4;++r){
      #pragma unroll
      for(int o=8;o>=1;o>>=1) m[r] = fmaxf(m[r], __shfl_xor(m[r], o));
    }
    float sum[4] = {0,0,0,0};
    #pragma unroll
    for(int f=0;f<13;++f)
      #pragma unroll
      for(int r=0;r<4;++r){
        float e = ((keep[r]>>f)&1u) ? expf(sf[f][r]-m[r]) : 0.f;
        sf[f][r] = e; sum[r] += e;
      }
    #pragma unroll
    for(int r=0;r<4;++r){
      #pragma unroll
      for(int o=8;o>=1;o>>=1) sum[r] += __shfl_xor(sum[r], o);
      sum[r] = 1.f/sum[r];
    }
    #pragma unroll
    for(int f=0;f<13;++f)
      #pragma unroll
      for(int r=0;r<4;++r){
        int ql = g*4+r;
        unsigned off = (unsigned)(ql*448 + (f*16+c16)*2) ^ ((unsigned)(ql&7)<<4);
        *(unsigned short*)((char*)Pl + pbase + off) = f2bf(sf[f][r]*sum[r]);
      }
    #pragma unroll
    for(int ct=0;ct<4;++ct){
      f32x4 oa = (f32x4){0.f,0.f,0.f,0.f};
      #pragma unroll
      for(int ks=0;ks<7;++ks){
        unsigned offa = (unsigned)(c16*448 + (ks*32+g*8)*2) ^ ((unsigned)(c16&7)<<4);
        short8 pa = *(const short8*)((char*)Pl + pbase + offa);
        short8 vb = *(const short8*)((char*)Vt + (size_t)(ct*16+c16)*440 + (ks*32+g*8)*2);
        oa = __builtin_amdgcn_mfma_f32_16x16x32_bf16(pa, vb, oa, 0,0,0);
      }
      #pragma unroll
      for(int r=0;r<4;++r){
        int qq = qb + g*4 + r;
        if(qq < N_)
          attn_out[((size_t)(b*N_+qq))*C_ + h*CH_ + ct*16 + c16] = f2bf(oa[r]);
      }
    }
  }
}

extern "C" void kernel_launch(void* const* d_in, const int* in_sizes, int n_in,
                              void* d_out, int out_size, void* d_ws, size_t ws_size,
                              hipStream_t stream){
  const float* x    =(const float*)d_in[0];
  const float* Wqkv =(const float*)d_in[1];
  const float* Wcq  =(const float*)d_in[2];
  const float* bcq  =(const float*)d_in[3];
  const float* Wck  =(const float*)d_in[4];
  const float* bck  =(const float*)d_in[5];
  const float* proj_n=(const float*)d_in[6];
  const float* proj_back_n=(const float*)d_in[7];
  const float* Wproj=(const float*)d_in[8];
  const float* bproj=(const float*)d_in[9];
  const float* g1=(const float*)d_in[10];
  const float* b1=(const float*)d_in[11];
  const float* g2=(const float*)d_in[12];
  const float* b2=(const float*)d_in[13];
  const float* W1=(const float*)d_in[14];
  const float* bfc1=(const float*)d_in[15];
  const float* W2=(const float*)d_in[16];
  const float* bfc2=(const float*)d_in[17];
  float* out=(float*)d_out;

  float* ws=(float*)d_ws;
  size_t off=0;
  unsigned short* hbuf = (unsigned short*)(ws+off); off += (size_t)12608*768/2;
  size_t qkv_off = off;
  unsigned short* qkv = (unsigned short*)(ws+off); off += (size_t)12608*2304/2;
  off += (size_t)768*197*32;   // padding (hidden alias headroom)
  off += (size_t)768*197*32;
  off += (size_t)768*32*24;
  float* coef = ws+off;        off += (size_t)768*196*24;
  float* basis= ws+off;        off += 4736;
  unsigned int* maskw=(unsigned int*)(ws+off); off += (size_t)768*197*8;
  unsigned short* WqkvT = (unsigned short*)(ws+off); off += (size_t)2304*768/2;
  unsigned short* WprojT= (unsigned short*)(ws+off); off += (size_t)768*768/2;
  unsigned short* W1T   = (unsigned short*)(ws+off); off += (size_t)3072*768/2;
  unsigned short* W2T   = (unsigned short*)(ws+off); off += (size_t)768*3072/2;
  unsigned short* WcqT  = (unsigned short*)(ws+off); off += 1024;
  unsigned short* WckT  = (unsigned short*)(ws+off); off += 1024;
  unsigned short* attn_out = hbuf;                    // alias (hbuf dead after qkv GEMM)
  unsigned short* hidden = (unsigned short*)(ws+qkv_off); // alias (qkv dead by MLP)
  float* x1 = out;

  // 0. weight transpose+bf16 conversions
  wtrans_kernel<<<dim3(72,24),256,0,stream>>>(Wqkv, WqkvT, 768, 2304);
  wtrans_kernel<<<dim3(24,24),256,0,stream>>>(Wproj, WprojT, 768, 768);
  wtrans_kernel<<<dim3(96,24),256,0,stream>>>(W1, W1T, 768, 3072);
  wtrans_kernel<<<dim3(24,96),256,0,stream>>>(W2, W2T, 3072, 768);
  wcprep_kernel<<<8,256,0,stream>>>(Wcq, Wck, WcqT, WckT);
  // 1. h = LN(x) -> bf16
  ln_kernel<<<12608,256,0,stream>>>(x,g1,b1,hbuf);
  // 2. qkv = h @ Wqkv (bf16 out)
  gemm256_bf16<0,0,1><<<dim3(18,50),512,0,stream>>>(hbuf,WqkvT,nullptr,nullptr,qkv,12608,768,2304);
  // 3. fused cheap path v3 (MFMA kp/qp)
  cheap_kernel<<<768,512,0,stream>>>(qkv,WcqT,bcq,WckT,bck,proj_n,coef);
  // 4. basis
  basis_kernel<<<19,256,0,stream>>>(proj_back_n,basis);
  // 5. approx_attn + budget mask (8 rows/wave deep-interleaved radix)
  mask7_kernel<<<4728,256,0,stream>>>(coef,basis,maskw);
  // 6. masked attention (MFMA)
  attn3_kernel<<<768,512,0,stream>>>(qkv,maskw,attn_out);
  // 7. x1 = x + attn_out @ Wproj + bproj   (x1 == d_out)
  gemm_bf16<0,1,0><<<dim3(6,99),256,0,stream>>>(attn_out,WprojT,bproj,x,x1,12608,768,768);
  // 8. h2 = LN(x1) -> bf16 (reuse hbuf)
  ln_kernel<<<12608,256,0,stream>>>(x1,g2,b2,hbuf);
  // 9. hidden = gelu(h2 @ W1 + bfc1) -> bf16
  gemm256_bf16<1,0,1><<<dim3(24,50),512,0,stream>>>(hbuf,W1T,bfc1,nullptr,hidden,12608,768,3072);
  // 10. out = x1 + hidden @ W2 + bfc2
  gemm_bf16<0,1,0><<<dim3(6,99),256,0,stream>>>(hidden,W2T,bfc2,x1,out,12608,3072,768);
}

// Round 22
// 649.505 us; speedup vs baseline: 1.0959x; 1.0052x over previous
//
#include <hip/hip_runtime.h>
#include <math.h>
#include <float.h>

#define B_ 64
#define N_ 197
#define C_ 768
#define H_ 12
#define CH_ 64
#define RC_ 32
#define RN_ 24

typedef __attribute__((ext_vector_type(8))) short short8;
typedef __attribute__((ext_vector_type(4))) float f32x4;
typedef __attribute__((address_space(3))) void  lds_void;
typedef __attribute__((address_space(1))) const void g_void;

__device__ __forceinline__ float warp_sum(float v){
  #pragma unroll
  for(int o=32;o>=1;o>>=1) v += __shfl_xor(v,o);
  return v;
}
__device__ __forceinline__ float warp_max(float v){
  #pragma unroll
  for(int o=32;o>=1;o>>=1) v = fmaxf(v,__shfl_xor(v,o));
  return v;
}
__device__ __forceinline__ unsigned short f2bf(float f){
  union{float f; unsigned u;} c; c.f = f;
  unsigned r = c.u + 0x7FFF + ((c.u>>16)&1);
  return (unsigned short)(r>>16);
}
__device__ __forceinline__ float bf2f(unsigned short u){
  union{unsigned u; float f;} c; c.u = ((unsigned)u)<<16; return c.f;
}
// bijective XCD-aware block swizzle (m204)
__device__ __forceinline__ int2 xcd_swz(int gx, int gy){
  int nwg = gx*gy;
  int id = blockIdx.x + gx*blockIdx.y;
  int xcd = id & 7, loc = id >> 3;
  int q = nwg >> 3, r = nwg & 7;
  int swz = (xcd < r ? xcd*(q+1) : r*(q+1) + (xcd-r)*q) + loc;
  return make_int2(swz % gx, swz / gx);
}

// ---------------- LayerNorm: one block per row of 768, bf16 out ----------------
__global__ __launch_bounds__(256) void ln_kernel(const float* __restrict__ x,
    const float* __restrict__ g, const float* __restrict__ bb, unsigned short* __restrict__ out){
  int r = blockIdx.x; int tid = threadIdx.x;
  const float* xr = x + (size_t)r*C_;
  float v0=xr[tid], v1=xr[tid+256], v2=xr[tid+512];
  __shared__ float red[8];
  float s = warp_sum(v0+v1+v2);
  if((tid&63)==0) red[tid>>6]=s;
  __syncthreads();
  float mu = (red[0]+red[1]+red[2]+red[3]) * (1.f/768.f);
  float d0=v0-mu,d1=v1-mu,d2=v2-mu;
  float s2 = warp_sum(d0*d0+d1*d1+d2*d2);
  if((tid&63)==0) red[4+(tid>>6)]=s2;
  __syncthreads();
  float rinv = rsqrtf((red[4]+red[5]+red[6]+red[7])*(1.f/768.f)+1e-5f);
  unsigned short* orow = out + (size_t)r*C_;
  orow[tid]     = f2bf(d0*rinv*g[tid]    +bb[tid]);
  orow[tid+256] = f2bf(d1*rinv*g[tid+256]+bb[tid+256]);
  orow[tid+512] = f2bf(d2*rinv*g[tid+512]+bb[tid+512]);
}

// ---------------- transpose+convert: in f32 [K][N] -> out bf16 [N][K] ----------------
__global__ __launch_bounds__(256) void wtrans_kernel(const float* __restrict__ in,
    unsigned short* __restrict__ out, int K, int N){
  __shared__ float tile[32][33];
  int n0 = blockIdx.x*32, k0 = blockIdx.y*32;
  int tx = threadIdx.x&31, ty = threadIdx.x>>5;
  #pragma unroll
  for(int i=0;i<4;++i) tile[ty+8*i][tx] = in[(size_t)(k0+ty+8*i)*N + n0+tx];
  __syncthreads();
  #pragma unroll
  for(int i=0;i<4;++i) out[(size_t)(n0+ty+8*i)*K + k0+tx] = f2bf(tile[tx][ty+8*i]);
}

// ---------------- Wcq/Wck f32[64][32] -> bf16 transposed [32][64] ----------------
__global__ __launch_bounds__(256) void wcprep_kernel(const float* __restrict__ Wcq,
    const float* __restrict__ Wck, unsigned short* __restrict__ WcqT,
    unsigned short* __restrict__ WckT){
  int t = blockIdx.x*256 + threadIdx.x;
  if(t < 2048){
    int c = t>>6, k = t&63;
    WcqT[t] = f2bf(Wcq[k*32+c]);
    WckT[t] = f2bf(Wck[k*32+c]);
  }
}

// ---------------- bf16 MFMA GEMM 128x128, BK=32, dbuf + XCD swz + chunk-XOR bank swizzle ----------------
// Bank fix: LDS[row][c] = global[row][c ^ ((row>>1)&3)] via inverse-swizzled
// SOURCE + linear gload_lds dest; frag reads XOR lg with ((lm>>1)&3).
// 16-lane frag read -> 8 distinct banks x 2 lanes = free (2-way). Bit-identical.
template<int ACT, int RESID, int OUTBF16>
__global__ __launch_bounds__(256) void gemm_bf16(
    const unsigned short* __restrict__ A, const unsigned short* __restrict__ WT,
    const float* __restrict__ bias, const float* __restrict__ resid,
    void* __restrict__ Cout, int M, int K, int Nc){
  __shared__ unsigned short As[2*128*32];
  __shared__ unsigned short Bs[2*128*32];
  int tid = threadIdx.x, lane = tid&63, wid = tid>>6;
  int2 bxy = xcd_swz(gridDim.x, gridDim.y);
  int m0 = bxy.y*128, n0 = bxy.x*128;
  int wr = wid>>1, wc = wid&1;
  int lm = lane&15, lg = lane>>4;
  int lgs = lg ^ ((lm>>1)&3);               // swizzled read chunk (constant/lane)
  int row0 = tid>>2,         kc0 = (((tid&3) ^ ((tid>>3)&3)))*8;
  int row1 = (256+tid)>>2,   kc1 = kc0;     // same swizzle ((row1>>1)&3 == (tid>>3)&3)
  int ar0 = m0+row0; if(ar0 > M-1) ar0 = M-1;
  int ar1 = m0+row1; if(ar1 > M-1) ar1 = M-1;
  const unsigned short* gA0 = A  + (size_t)ar0*K + kc0;
  const unsigned short* gA1 = A  + (size_t)ar1*K + kc1;
  const unsigned short* gB0 = WT + (size_t)(n0+row0)*K + kc0;
  const unsigned short* gB1 = WT + (size_t)(n0+row1)*K + kc1;
  unsigned short* lA0 = As + (wid*64)*8;
  unsigned short* lA1 = As + (256 + wid*64)*8;
  unsigned short* lB0 = Bs + (wid*64)*8;
  unsigned short* lB1 = Bs + (256 + wid*64)*8;

#define STAGE_(buf, kt) do{ \
    __builtin_amdgcn_global_load_lds((g_void*)(gA0 + (kt)), (lds_void*)(lA0 + (buf)*4096), 16, 0, 0); \
    __builtin_amdgcn_global_load_lds((g_void*)(gB0 + (kt)), (lds_void*)(lB0 + (buf)*4096), 16, 0, 0); \
    __builtin_amdgcn_global_load_lds((g_void*)(gA1 + (kt)), (lds_void*)(lA1 + (buf)*4096), 16, 0, 0); \
    __builtin_amdgcn_global_load_lds((g_void*)(gB1 + (kt)), (lds_void*)(lB1 + (buf)*4096), 16, 0, 0); \
  }while(0)

  f32x4 acc[4][4] = {};
  const int nt = K/32;
  STAGE_(0, 0);
  __syncthreads();
  for(int t=0; t<nt; t+=2){
    STAGE_(1, (t+1)*32);
    {
      short8 af[4], bfv[4];
      #pragma unroll
      for(int i=0;i<4;++i){
        af[i]  = *(const short8*)(As + (64*wr + 16*i + lm)*32 + lgs*8);
        bfv[i] = *(const short8*)(Bs + (64*wc + 16*i + lm)*32 + lgs*8);
      }
      #pragma unroll
      for(int i=0;i<4;++i)
        #pragma unroll
        for(int j=0;j<4;++j)
          acc[i][j] = __builtin_amdgcn_mfma_f32_16x16x32_bf16(af[i], bfv[j], acc[i][j], 0,0,0);
    }
    __syncthreads();
    if(t+2 < nt) STAGE_(0, (t+2)*32);
    {
      short8 af[4], bfv[4];
      #pragma unroll
      for(int i=0;i<4;++i){
        af[i]  = *(const short8*)(As + 4096 + (64*wr + 16*i + lm)*32 + lgs*8);
        bfv[i] = *(const short8*)(Bs + 4096 + (64*wc + 16*i + lm)*32 + lgs*8);
      }
      #pragma unroll
      for(int i=0;i<4;++i)
        #pragma unroll
        for(int j=0;j<4;++j)
          acc[i][j] = __builtin_amdgcn_mfma_f32_16x16x32_bf16(af[i], bfv[j], acc[i][j], 0,0,0);
    }
    __syncthreads();
  }
#undef STAGE_
  #pragma unroll
  for(int i=0;i<4;++i){
    #pragma unroll
    for(int j=0;j<4;++j){
      int gcol = n0 + 64*wc + 16*j + lm;
      float bv = bias ? bias[gcol] : 0.f;
      #pragma unroll
      for(int r=0;r<4;++r){
        int grow = m0 + 64*wr + 16*i + lg*4 + r;
        if(grow < M){
          float cv = acc[i][j][r] + bv;
          if(ACT==1){
            float xx = cv;
            float p = xx*fmaf(xx*xx, 0.10294517f, 2.3022079f);
            float q = exp2f(p);
            cv = xx - xx*__builtin_amdgcn_rcpf(1.0f+q);
          }
          if(RESID) cv += resid[(size_t)grow*Nc + gcol];
          if(OUTBF16) ((unsigned short*)Cout)[(size_t)grow*Nc+gcol] = f2bf(cv);
          else        ((float*)Cout)[(size_t)grow*Nc+gcol] = cv;
        }
      }
    }
  }
}

// ---------------- bf16 MFMA GEMM 256x128, BK=32, 8 waves, dbuf + XCD swz + bank swizzle ----------------
template<int ACT, int RESID, int OUTBF16>
__global__ __launch_bounds__(512, 4) void gemm256_bf16(
    const unsigned short* __restrict__ A, const unsigned short* __restrict__ WT,
    const float* __restrict__ bias, const float* __restrict__ resid,
    void* __restrict__ Cout, int M, int K, int Nc){
  __shared__ unsigned short As[2*256*32];   // 32 KB
  __shared__ unsigned short Bs[2*128*32];   // 16 KB
  int tid = threadIdx.x, lane = tid&63, wid = tid>>6;
  int2 bxy = xcd_swz(gridDim.x, gridDim.y);
  int m0 = bxy.y*256, n0 = bxy.x*128;
  int wm = wid>>1, wn = wid&1;
  int lm = lane&15, lg = lane>>4;
  int lgs = lg ^ ((lm>>1)&3);
  int rowA0 = tid>>2, rowA1 = 128 + (tid>>2), rowB = tid>>2;
  int kc = (((tid&3) ^ ((tid>>3)&3)))*8;    // swizzled source chunk (same for all 3 rows)
  int arA0 = m0+rowA0; if(arA0 > M-1) arA0 = M-1;
  int arA1 = m0+rowA1; if(arA1 > M-1) arA1 = M-1;
  const unsigned short* gA0 = A  + (size_t)arA0*K + kc;
  const unsigned short* gA1 = A  + (size_t)arA1*K + kc;
  const unsigned short* gB0 = WT + (size_t)(n0+rowB)*K + kc;
  unsigned short* lA0 = As + wid*512;
  unsigned short* lA1 = As + 4096 + wid*512;
  unsigned short* lB0 = Bs + wid*512;

#define STAGE2_(buf, kt) do{ \
    __builtin_amdgcn_global_load_lds((g_void*)(gA0 + (kt)), (lds_void*)(lA0 + (buf)*8192), 16, 0, 0); \
    __builtin_amdgcn_global_load_lds((g_void*)(gB0 + (kt)), (lds_void*)(lB0 + (buf)*4096), 16, 0, 0); \
    __builtin_amdgcn_global_load_lds((g_void*)(gA1 + (kt)), (lds_void*)(lA1 + (buf)*8192), 16, 0, 0); \
  }while(0)

  f32x4 acc[4][4] = {};
  const int nt = K/32;
  STAGE2_(0, 0);
  __syncthreads();
  for(int t=0; t<nt; ++t){
    int buf = t&1;
    if(t+1 < nt) STAGE2_(buf^1, (t+1)*32);
    const unsigned short* abase = As + buf*8192;
    const unsigned short* bbase = Bs + buf*4096;
    short8 af[4], bfv[4];
    #pragma unroll
    for(int i=0;i<4;++i)
      af[i] = *(const short8*)(abase + (wm*64 + i*16 + lm)*32 + lgs*8);
    #pragma unroll
    for(int j=0;j<4;++j)
      bfv[j] = *(const short8*)(bbase + (wn*64 + j*16 + lm)*32 + lgs*8);
    __builtin_amdgcn_s_setprio(1);
    #pragma unroll
    for(int i=0;i<4;++i)
      #pragma unroll
      for(int j=0;j<4;++j)
        acc[i][j] = __builtin_amdgcn_mfma_f32_16x16x32_bf16(af[i], bfv[j], acc[i][j], 0,0,0);
    __builtin_amdgcn_s_setprio(0);
    __syncthreads();
  }
#undef STAGE2_
  #pragma unroll
  for(int i=0;i<4;++i){
    #pragma unroll
    for(int j=0;j<4;++j){
      int gcol = n0 + wn*64 + j*16 + lm;
      float bv = bias ? bias[gcol] : 0.f;
      #pragma unroll
      for(int r=0;r<4;++r){
        int grow = m0 + wm*64 + i*16 + lg*4 + r;
        if(grow < M){
          float cv = acc[i][j][r] + bv;
          if(ACT==1){
            float xx = cv;
            float p = xx*fmaf(xx*xx, 0.10294517f, 2.3022079f);
            float q = exp2f(p);
            cv = xx - xx*__builtin_amdgcn_rcpf(1.0f+q);
          }
          if(RESID) cv += resid[(size_t)grow*Nc + gcol];
          if(OUTBF16) ((unsigned short*)Cout)[(size_t)grow*Nc+gcol] = f2bf(cv);
          else        ((float*)Cout)[(size_t)grow*Nc+gcol] = cv;
        }
      }
    }
  }
}

// ---------------- fused cheap path v3: MFMA kp/qp + float4 kk + 2-row coef ----------------
__global__ __launch_bounds__(512) void cheap_kernel(
    const unsigned short* __restrict__ qkv,
    const unsigned short* __restrict__ WcqT, const float* __restrict__ bcq,
    const unsigned short* __restrict__ WckT, const float* __restrict__ bck,
    const float* __restrict__ proj_n, float* __restrict__ coef){
  int bh = blockIdx.x; int b = bh/H_, h = bh%H_;
  int tid = threadIdx.x, lane = tid&63, wv = tid>>6;
  int lm = lane&15, lg = lane>>4;
  __shared__ __align__(16) unsigned short KQ[208*64];
  __shared__ __align__(16) float P2T[32*212];
  __shared__ __align__(16) float PNT[24*200];
  __shared__ float KK[768];
  const unsigned short* Kbase = qkv + ((size_t)(b*N_)*3 + 1)*C_ + h*CH_;
  const unsigned short* Qbase = qkv + ((size_t)(b*N_)*3 + 0)*C_ + h*CH_;
  for(int idx = tid; idx < 208*32; idx += 512){
    int k = idx>>5, cp = idx&31;
    unsigned v = (k < N_) ? *(const unsigned*)(Kbase + (size_t)k*3*C_ + cp*2) : 0u;
    unsigned off = (unsigned)(k*128 + cp*4) ^ ((unsigned)(k&7)<<4);
    *(unsigned*)((char*)KQ + off) = v;
  }
  for(int idx = tid; idx < 24*200; idx += 512){
    int r = idx/200, n = idx - r*200;
    PNT[idx] = (n < N_) ? proj_n[n*24+r] : 0.f;
  }
  __syncthreads();
  {
    short8 bfr[2][2];
    #pragma unroll
    for(int j=0;j<2;++j)
      #pragma unroll
      for(int s=0;s<2;++s)
        bfr[j][s] = *(const short8*)(WckT + (j*16+lm)*64 + s*32 + lg*8);
    float bias[2] = { bck[lm], bck[16+lm] };
    for(int t=wv; t<13; t+=8){
      int row = t*16 + lm;
      unsigned o0 = (unsigned)(row*128 + lg*16) ^ ((unsigned)(row&7)<<4);
      unsigned o1 = (unsigned)(row*128 + 64 + lg*16) ^ ((unsigned)(row&7)<<4);
      short8 a0 = *(const short8*)((char*)KQ + o0);
      short8 a1 = *(const short8*)((char*)KQ + o1);
      #pragma unroll
      for(int j=0;j<2;++j){
        f32x4 acc = (f32x4){0.f,0.f,0.f,0.f};
        acc = __builtin_amdgcn_mfma_f32_16x16x32_bf16(a0, bfr[j][0], acc, 0,0,0);
        acc = __builtin_amdgcn_mfma_f32_16x16x32_bf16(a1, bfr[j][1], acc, 0,0,0);
        #pragma unroll
        for(int r=0;r<4;++r)
          P2T[(j*16+lm)*212 + t*16 + lg*4 + r] = acc[r] + bias[j];
      }
    }
  }
  __syncthreads();
  {
    int i0 = tid, i1 = tid + 512;
    bool has1 = (i1 < 768);
    int c0 = i0/24, r0 = i0 - c0*24;
    int c1 = has1 ? i1/24 : 0, r1 = has1 ? (i1 - (i1/24)*24) : 0;
    float a0=0.f, a1=0.f;
    for(int n=0;n<200;n+=4){
      float4 x0 = *(const float4*)&P2T[c0*212+n];
      float4 p0 = *(const float4*)&PNT[r0*200+n];
      a0 += x0.x*p0.x; a0 += x0.y*p0.y; a0 += x0.z*p0.z; a0 += x0.w*p0.w;
      if(has1){
        float4 x1 = *(const float4*)&P2T[c1*212+n];
        float4 p1 = *(const float4*)&PNT[r1*200+n];
        a1 += x1.x*p1.x; a1 += x1.y*p1.y; a1 += x1.z*p1.z; a1 += x1.w*p1.w;
      }
    }
    KK[i0] = a0;
    if(has1) KK[i1] = a1;
    for(int idx = tid; idx < 197*32; idx += 512){
      int k = idx>>5, cp = idx&31;
      unsigned v = *(const unsigned*)(Qbase + (size_t)k*3*C_ + cp*2);
      unsigned off = (unsigned)(k*128 + cp*4) ^ ((unsigned)(k&7)<<4);
      *(unsigned*)((char*)KQ + off) = v;
    }
  }
  __syncthreads();
  float* QP = P2T;
  {
    short8 bfr[2][2];
    #pragma unroll
    for(int j=0;j<2;++j)
      #pragma unroll
      for(int s=0;s<2;++s)
        bfr[j][s] = *(const short8*)(WcqT + (j*16+lm)*64 + s*32 + lg*8);
    float bias[2] = { bcq[lm], bcq[16+lm] };
    for(int t=wv; t<13; t+=8){
      int row = t*16 + lm;
      unsigned o0 = (unsigned)(row*128 + lg*16) ^ ((unsigned)(row&7)<<4);
      unsigned o1 = (unsigned)(row*128 + 64 + lg*16) ^ ((unsigned)(row&7)<<4);
      short8 a0 = *(const short8*)((char*)KQ + o0);
      short8 a1 = *(const short8*)((char*)KQ + o1);
      #pragma unroll
      for(int j=0;j<2;++j){
        f32x4 acc = (f32x4){0.f,0.f,0.f,0.f};
        acc = __builtin_amdgcn_mfma_f32_16x16x32_bf16(a0, bfr[j][0], acc, 0,0,0);
        acc = __builtin_amdgcn_mfma_f32_16x16x32_bf16(a1, bfr[j][1], acc, 0,0,0);
        #pragma unroll
        for(int r=0;r<4;++r)
          QP[(t*16 + lg*4 + r)*32 + j*16 + lm] = acc[r] + bias[j];
      }
    }
  }
  __syncthreads();
  int l32 = lane & 31, half = lane >> 5;
  bool act = l32 < RN_;
  int ll = act ? l32 : 0;
  float kkreg[32];
  #pragma unroll
  for(int c=0;c<32;++c) kkreg[c] = KK[c*24 + ll];
  for(int i2 = wv*2; i2 < 196; i2 += 16){
    int i = i2 + half;
    int n = i + 1;
    float accv = 0.f;
    #pragma unroll
    for(int q=0;q<8;++q){
      float4 v4 = *(const float4*)&QP[n*32 + q*4];
      accv += v4.x*kkreg[q*4];   accv += v4.y*kkreg[q*4+1];
      accv += v4.z*kkreg[q*4+2]; accv += v4.w*kkreg[q*4+3];
    }
    float val = act ? accv * 0.28867513459481287f : -INFINITY;
    float m = val;
    #pragma unroll
    for(int o=16;o>=1;o>>=1) m = fmaxf(m, __shfl_xor(m, o));
    float e = act ? expf(val - m) : 0.f;
    float ssum = e;
    #pragma unroll
    for(int o=16;o>=1;o>>=1) ssum += __shfl_xor(ssum, o);
    float p = e/ssum;
    unsigned u = __float_as_uint(e);
    unsigned pL=0, pH=0;
    #pragma unroll
    for(int bit=30; bit>=0; --bit){
      unsigned tL = pL | (1u<<bit), tH = pH | (1u<<bit);
      unsigned thr = half ? tH : tL;
      unsigned long long bal = __ballot(u >= thr);
      int cL = __popcll(bal & 0xFFFFFFull);
      int cH = __popcll((bal>>32) & 0xFFFFFFull);
      if(cL>=8) pL=tL;
      if(cH>=8) pH=tH;
    }
    unsigned myp = half ? pH : pL;
    if(act) coef[((size_t)bh*196 + i)*24 + l32] = (u >= myp) ? p : 0.f;
  }
}

// ---------------- basis[r][j] = thresh(|proj_back_n[j][r]|) ----------------
__global__ __launch_bounds__(256) void basis_kernel(const float* __restrict__ pb,
    float* __restrict__ basis){
  int t = blockIdx.x*256 + threadIdx.x;
  if(t < RN_*N_){
    int r = t/N_, j = t%N_;
    float v = fabsf(pb[(size_t)j*RN_ + r]);
    basis[t] = (v > 0.02f) ? v : 0.f;
  }
}

// ---------------- mask v7: 8 rows per wave (deep-interleaved radix + early exit) ----------------
__global__ __launch_bounds__(256) void mask7_kernel(const float* __restrict__ coef,
    const float* __restrict__ basis, unsigned int* __restrict__ maskw){
  __shared__ float Bs[24*256];
  int tid = threadIdx.x, lane = tid&63, wv = tid>>6;
  for(int idx = tid; idx < 24*256; idx += 256){
    int r = idx>>8, q = idx&255;
    int e = ((q&3)<<6) | (q>>2);
    Bs[idx] = (e < N_) ? basis[r*N_ + e] : 0.f;
  }
  __syncthreads();
  int rowbase = blockIdx.x*32 + wv*8;
  float4 av[8];
  unsigned done = 0;
  #pragma unroll
  for(int j=0;j<8;++j){
    int row = rowbase + j;
    int qi = row % N_; int bh = row / N_;
    if(qi==0){
      if(lane<8){
        unsigned v = (lane<6)?0xFFFFFFFFu:((lane==6)?0x1Fu:0u);
        maskw[(size_t)row*8+lane]=v;
      }
      av[j] = make_float4(0.f,0.f,0.f,0.f);
      done |= (1u<<j);
    } else {
      float cfv = (lane<24) ? coef[((size_t)bh*196 + (qi-1))*24 + lane] : 0.f;
      unsigned long long nz = __ballot(cfv != 0.f);
      float4 a = make_float4(0.f,0.f,0.f,0.f);
      while(nz){
        int r = __ffsll((unsigned long long)nz) - 1;
        nz &= nz - 1;
        float c = __uint_as_float(__builtin_amdgcn_readlane(__float_as_uint(cfv), r));
        float4 bv = *(const float4*)&Bs[r*256 + lane*4];
        a.x += c*bv.x; a.y += c*bv.y; a.z += c*bv.z; a.w += c*bv.w;
      }
      av[j] = a;
    }
  }
  unsigned u[8][4];
  #pragma unroll
  for(int j=0;j<8;++j){
    u[j][0]=__float_as_uint(av[j].x); u[j][1]=__float_as_uint(av[j].y);
    u[j][2]=__float_as_uint(av[j].z); u[j][3]=__float_as_uint(av[j].w);
  }
  unsigned prefix[8] = {0,0,0,0,0,0,0,0};
  for(int bit=30; bit>=0; --bit){
    if(done == 0xFFu) break;
    #pragma unroll
    for(int j=0;j<8;++j){
      unsigned t = prefix[j] | (1u<<bit);
      int c = __popcll(__ballot(u[j][0] >= t)) + __popcll(__ballot(u[j][1] >= t))
            + __popcll(__ballot(u[j][2] >= t)) + __popcll(__ballot(u[j][3] >= t));
      bool actj = !((done>>j)&1u);
      if(actj && c >= 50) prefix[j] = t;
      if(actj && c == 50) done |= (1u<<j);
    }
  }
  #pragma unroll
  for(int j=0;j<8;++j){
    int row = rowbase + j;
    if(row % N_ == 0) continue;
    #pragma unroll
    for(int r=0;r<4;++r){
      bool valid = (r<3) | (lane<5);
      bool keep = valid && (u[j][r] >= prefix[j]);
      unsigned long long bal = __ballot(keep);
      if(lane==0){
        maskw[(size_t)row*8 + 2*r]   = (unsigned)(bal & 0xFFFFFFFFull);
        maskw[(size_t)row*8 + 2*r+1] = (unsigned)(bal>>32);
      }
    }
  }
}

// ---------------- masked attention v3: MFMA flash-style, one block per (b,h) ----------------
__global__ __launch_bounds__(512) void attn3_kernel(const unsigned short* __restrict__ qkv,
    const unsigned int* __restrict__ maskw, unsigned short* __restrict__ attn_out){
  int bh = blockIdx.x; int b = bh/H_, h = bh%H_;
  int tid = threadIdx.x, lane = tid&63, wv = tid>>6;
  int g = lane>>4, c16 = lane&15;
  __shared__ unsigned short Kb[208*64];
  __shared__ unsigned short Vt[64*220];
  __shared__ unsigned short Pl[8*16*224];
  __shared__ unsigned int   Ml[8][16][8];
  const unsigned short* Kbase = qkv + ((size_t)(b*N_)*3 + 1)*C_ + h*CH_;
  const unsigned short* Vbase = qkv + ((size_t)(b*N_)*3 + 2)*C_ + h*CH_;
  for(int idx = tid; idx < 208*32; idx += 512){
    int k = idx>>5, cp = idx&31;
    unsigned pk = 0;
    if(k < N_) pk = *(const unsigned*)(Kbase + (size_t)k*3*C_ + cp*2);
    unsigned off = (unsigned)(k*128 + cp*4) ^ ((unsigned)(k&7)<<4);
    *(unsigned*)((char*)Kb + off) = pk;
  }
  for(int idx = tid; idx < 64*110; idx += 512){
    int kp = idx>>6, c = idx&63;
    int k0 = kp*2, k1 = kp*2+1;
    unsigned v0 = (k0<N_) ? Vbase[(size_t)k0*3*C_ + c] : 0;
    unsigned v1 = (k1<N_) ? Vbase[(size_t)k1*3*C_ + c] : 0;
    *(unsigned*)((char*)Vt + c*440 + kp*4) = v0 | (v1<<16);
  }
  __syncthreads();
  size_t pbase = (size_t)wv*16*448;
  for(int i=lane;i<128;i+=64){
    int ql = i>>3; int kk = 208 + (i&7)*2;
    unsigned off = (unsigned)(ql*448 + kk*2) ^ ((unsigned)(ql&7)<<4);
    *(unsigned*)((char*)Pl + pbase + off) = 0u;
  }
  for(int t = wv; t < 13; t += 8){
    int qb = t*16;
    for(int i = lane; i < 128; i += 64){
      int row = i>>3, word = i&7;
      int qr = qb+row; if(qr>196) qr=196;
      Ml[wv][row][word] = maskw[(size_t)(bh*N_+qr)*8 + word];
    }
    int qrow = qb + c16; if(qrow>196) qrow=196;
    const unsigned short* Qr = qkv + ((size_t)(b*N_+qrow)*3)*C_ + h*CH_ + g*8;
    short8 af[2];
    af[0] = *(const short8*)(Qr);
    af[1] = *(const short8*)(Qr + 32);
    f32x4 sf[13];
    #pragma unroll
    for(int f=0;f<13;++f){
      sf[f] = (f32x4){0.f,0.f,0.f,0.f};
      #pragma unroll
      for(int s=0;s<2;++s){
        int row = f*16 + c16;
        unsigned off = (unsigned)(row*128 + s*64 + g*16) ^ ((unsigned)(row&7)<<4);
        short8 bfr = *(const short8*)((char*)Kb + off);
        sf[f] = __builtin_amdgcn_mfma_f32_16x16x32_bf16(af[s], bfr, sf[f], 0,0,0);
      }
      sf[f][0]*=0.125f; sf[f][1]*=0.125f; sf[f][2]*=0.125f; sf[f][3]*=0.125f;
    }
    unsigned keep[4] = {0,0,0,0};
    float m[4] = {-FLT_MAX,-FLT_MAX,-FLT_MAX,-FLT_MAX};
    #pragma unroll
    for(int f=0;f<13;++f)
      #pragma unroll
      for(int r=0;r<4;++r){
        unsigned bit = (Ml[wv][g*4+r][f>>1] >> ((f&1)*16 + c16)) & 1u;
        keep[r] |= bit<<f;
        if(bit) m[r] = fmaxf(m[r], sf[f][r]);
      }
    #pragma unroll
    for(int r=0;r<4;++r){
      #pragma unroll
      for(int o=8;o>=1;o>>=1) m[r] = fmaxf(m[r], __shfl_xor(m[r], o));
    }
    float sum[4] = {0,0,0,0};
    #pragma unroll
    for(int f=0;f<13;++f)
      #pragma unroll
      for(int r=0;r<4;++r){
        float e = ((keep[r]>>f)&1u) ? expf(sf[f][r]-m[r]) : 0.f;
        sf[f][r] = e; sum[r] += e;
      }
    #pragma unroll
    for(int r=0;r<4;++r){
      #pragma unroll
      for(int o=8;o>=1;o>>=1) sum[r] += __shfl_xor(sum[r], o);
      sum[r] = 1.f/sum[r];
    }
    #pragma unroll
    for(int f=0;f<13;++f)
      #pragma unroll
      for(int r=0;r<4;++r){
        int ql = g*4+r;
        unsigned off = (unsigned)(ql*448 + (f*16+c16)*2) ^ ((unsigned)(ql&7)<<4);
        *(unsigned short*)((char*)Pl + pbase + off) = f2bf(sf[f][r]*sum[r]);
      }
    #pragma unroll
    for(int ct=0;ct<4;++ct){
      f32x4 oa = (f32x4){0.f,0.f,0.f,0.f};
      #pragma unroll
      for(int ks=0;ks<7;++ks){
        unsigned offa = (unsigned)(c16*448 + (ks*32+g*8)*2) ^ ((unsigned)(c16&7)<<4);
        short8 pa = *(const short8*)((char*)Pl + pbase + offa);
        short8 vb = *(const short8*)((char*)Vt + (size_t)(ct*16+c16)*440 + (ks*32+g*8)*2);
        oa = __builtin_amdgcn_mfma_f32_16x16x32_bf16(pa, vb, oa, 0,0,0);
      }
      #pragma unroll
      for(int r=0;r<4;++r){
        int qq = qb + g*4 + r;
        if(qq < N_)
          attn_out[((size_t)(b*N_+qq))*C_ + h*CH_ + ct*16 + c16] = f2bf(oa[r]);
      }
    }
  }
}

extern "C" void kernel_launch(void* const* d_in, const int* in_sizes, int n_in,
                              void* d_out, int out_size, void* d_ws, size_t ws_size,
                              hipStream_t stream){
  const float* x    =(const float*)d_in[0];
  const float* Wqkv =(const float*)d_in[1];
  const float* Wcq  =(const float*)d_in[2];
  const float* bcq  =(const float*)d_in[3];
  const float* Wck  =(const float*)d_in[4];
  const float* bck  =(const float*)d_in[5];
  const float* proj_n=(const float*)d_in[6];
  const float* proj_back_n=(const float*)d_in[7];
  const float* Wproj=(const float*)d_in[8];
  const float* bproj=(const float*)d_in[9];
  const float* g1=(const float*)d_in[10];
  const float* b1=(const float*)d_in[11];
  const float* g2=(const float*)d_in[12];
  const float* b2=(const float*)d_in[13];
  const float* W1=(const float*)d_in[14];
  const float* bfc1=(const float*)d_in[15];
  const float* W2=(const float*)d_in[16];
  const float* bfc2=(const float*)d_in[17];
  float* out=(float*)d_out;

  float* ws=(float*)d_ws;
  size_t off=0;
  unsigned short* hbuf = (unsigned short*)(ws+off); off += (size_t)12608*768/2;
  size_t qkv_off = off;
  unsigned short* qkv = (unsigned short*)(ws+off); off += (size_t)12608*2304/2;
  off += (size_t)768*197*32;   // padding (hidden alias headroom)
  off += (size_t)768*197*32;
  off += (size_t)768*32*24;
  float* coef = ws+off;        off += (size_t)768*196*24;
  float* basis= ws+off;        off += 4736;
  unsigned int* maskw=(unsigned int*)(ws+off); off += (size_t)768*197*8;
  unsigned short* WqkvT = (unsigned short*)(ws+off); off += (size_t)2304*768/2;
  unsigned short* WprojT= (unsigned short*)(ws+off); off += (size_t)768*768/2;
  unsigned short* W1T   = (unsigned short*)(ws+off); off += (size_t)3072*768/2;
  unsigned short* W2T   = (unsigned short*)(ws+off); off += (size_t)768*3072/2;
  unsigned short* WcqT  = (unsigned short*)(ws+off); off += 1024;
  unsigned short* WckT  = (unsigned short*)(ws+off); off += 1024;
  unsigned short* attn_out = hbuf;                    // alias (hbuf dead after qkv GEMM)
  unsigned short* hidden = (unsigned short*)(ws+qkv_off); // alias (qkv dead by MLP)
  float* x1 = out;

  // 0. weight transpose+bf16 conversions
  wtrans_kernel<<<dim3(72,24),256,0,stream>>>(Wqkv, WqkvT, 768, 2304);
  wtrans_kernel<<<dim3(24,24),256,0,stream>>>(Wproj, WprojT, 768, 768);
  wtrans_kernel<<<dim3(96,24),256,0,stream>>>(W1, W1T, 768, 3072);
  wtrans_kernel<<<dim3(24,96),256,0,stream>>>(W2, W2T, 3072, 768);
  wcprep_kernel<<<8,256,0,stream>>>(Wcq, Wck, WcqT, WckT);
  // 1. h = LN(x) -> bf16
  ln_kernel<<<12608,256,0,stream>>>(x,g1,b1,hbuf);
  // 2. qkv = h @ Wqkv (bf16 out)
  gemm256_bf16<0,0,1><<<dim3(18,50),512,0,stream>>>(hbuf,WqkvT,nullptr,nullptr,qkv,12608,768,2304);
  // 3. fused cheap path v3 (MFMA kp/qp)
  cheap_kernel<<<768,512,0,stream>>>(qkv,WcqT,bcq,WckT,bck,proj_n,coef);
  // 4. basis
  basis_kernel<<<19,256,0,stream>>>(proj_back_n,basis);
  // 5. approx_attn + budget mask (8 rows/wave deep-interleaved radix)
  mask7_kernel<<<4728,256,0,stream>>>(coef,basis,maskw);
  // 6. masked attention (MFMA)
  attn3_kernel<<<768,512,0,stream>>>(qkv,maskw,attn_out);
  // 7. x1 = x + attn_out @ Wproj + bproj   (x1 == d_out)
  gemm_bf16<0,1,0><<<dim3(6,99),256,0,stream>>>(attn_out,WprojT,bproj,x,x1,12608,768,768);
  // 8. h2 = LN(x1) -> bf16 (reuse hbuf)
  ln_kernel<<<12608,256,0,stream>>>(x1,g2,b2,hbuf);
  // 9. hidden = gelu(h2 @ W1 + bfc1) -> bf16
  gemm256_bf16<1,0,1><<<dim3(24,50),512,0,stream>>>(hbuf,W1T,bfc1,nullptr,hidden,12608,768,3072);
  // 10. out = x1 + hidden @ W2 + bfc2
  gemm_bf16<0,1,0><<<dim3(6,99),256,0,stream>>>(hidden,W2T,bfc2,x1,out,12608,3072,768);
}

// Round 23
// 642.342 us; speedup vs baseline: 1.1081x; 1.0112x over previous
//
#include <hip/hip_runtime.h>
#include <math.h>
#include <float.h>

#define B_ 64
#define N_ 197
#define C_ 768
#define H_ 12
#define CH_ 64
#define RC_ 32
#define RN_ 24

typedef __attribute__((ext_vector_type(8))) short short8;
typedef __attribute__((ext_vector_type(4))) float f32x4;
typedef __attribute__((address_space(3))) void  lds_void;
typedef __attribute__((address_space(1))) const void g_void;

__device__ __forceinline__ float warp_sum(float v){
  #pragma unroll
  for(int o=32;o>=1;o>>=1) v += __shfl_xor(v,o);
  return v;
}
__device__ __forceinline__ float warp_max(float v){
  #pragma unroll
  for(int o=32;o>=1;o>>=1) v = fmaxf(v,__shfl_xor(v,o));
  return v;
}
__device__ __forceinline__ unsigned short f2bf(float f){
  union{float f; unsigned u;} c; c.f = f;
  unsigned r = c.u + 0x7FFF + ((c.u>>16)&1);
  return (unsigned short)(r>>16);
}
__device__ __forceinline__ float bf2f(unsigned short u){
  union{unsigned u; float f;} c; c.u = ((unsigned)u)<<16; return c.f;
}
// bijective XCD-aware block swizzle (m204)
__device__ __forceinline__ int2 xcd_swz(int gx, int gy){
  int nwg = gx*gy;
  int id = blockIdx.x + gx*blockIdx.y;
  int xcd = id & 7, loc = id >> 3;
  int q = nwg >> 3, r = nwg & 7;
  int swz = (xcd < r ? xcd*(q+1) : r*(q+1) + (xcd-r)*q) + loc;
  return make_int2(swz % gx, swz / gx);
}

// ---------------- LayerNorm: one block per row of 768, bf16 out ----------------
__global__ __launch_bounds__(256) void ln_kernel(const float* __restrict__ x,
    const float* __restrict__ g, const float* __restrict__ bb, unsigned short* __restrict__ out){
  int r = blockIdx.x; int tid = threadIdx.x;
  const float* xr = x + (size_t)r*C_;
  float v0=xr[tid], v1=xr[tid+256], v2=xr[tid+512];
  __shared__ float red[8];
  float s = warp_sum(v0+v1+v2);
  if((tid&63)==0) red[tid>>6]=s;
  __syncthreads();
  float mu = (red[0]+red[1]+red[2]+red[3]) * (1.f/768.f);
  float d0=v0-mu,d1=v1-mu,d2=v2-mu;
  float s2 = warp_sum(d0*d0+d1*d1+d2*d2);
  if((tid&63)==0) red[4+(tid>>6)]=s2;
  __syncthreads();
  float rinv = rsqrtf((red[4]+red[5]+red[6]+red[7])*(1.f/768.f)+1e-5f);
  unsigned short* orow = out + (size_t)r*C_;
  orow[tid]     = f2bf(d0*rinv*g[tid]    +bb[tid]);
  orow[tid+256] = f2bf(d1*rinv*g[tid+256]+bb[tid+256]);
  orow[tid+512] = f2bf(d2*rinv*g[tid+512]+bb[tid+512]);
}

// ---------------- transpose+convert: in f32 [K][N] -> out bf16 [N][K] ----------------
__global__ __launch_bounds__(256) void wtrans_kernel(const float* __restrict__ in,
    unsigned short* __restrict__ out, int K, int N){
  __shared__ float tile[32][33];
  int n0 = blockIdx.x*32, k0 = blockIdx.y*32;
  int tx = threadIdx.x&31, ty = threadIdx.x>>5;
  #pragma unroll
  for(int i=0;i<4;++i) tile[ty+8*i][tx] = in[(size_t)(k0+ty+8*i)*N + n0+tx];
  __syncthreads();
  #pragma unroll
  for(int i=0;i<4;++i) out[(size_t)(n0+ty+8*i)*K + k0+tx] = f2bf(tile[tx][ty+8*i]);
}

// ---------------- Wcq/Wck f32[64][32] -> bf16 transposed [32][64] ----------------
__global__ __launch_bounds__(256) void wcprep_kernel(const float* __restrict__ Wcq,
    const float* __restrict__ Wck, unsigned short* __restrict__ WcqT,
    unsigned short* __restrict__ WckT){
  int t = blockIdx.x*256 + threadIdx.x;
  if(t < 2048){
    int c = t>>6, k = t&63;
    WcqT[t] = f2bf(Wcq[k*32+c]);
    WckT[t] = f2bf(Wck[k*32+c]);
  }
}

// ---------------- bf16 MFMA GEMM 128x128, BK=32, dbuf + XCD swz + chunk-XOR bank swizzle ----------------
template<int ACT, int RESID, int OUTBF16>
__global__ __launch_bounds__(256) void gemm_bf16(
    const unsigned short* __restrict__ A, const unsigned short* __restrict__ WT,
    const float* __restrict__ bias, const float* __restrict__ resid,
    void* __restrict__ Cout, int M, int K, int Nc){
  __shared__ unsigned short As[2*128*32];
  __shared__ unsigned short Bs[2*128*32];
  int tid = threadIdx.x, lane = tid&63, wid = tid>>6;
  int2 bxy = xcd_swz(gridDim.x, gridDim.y);
  int m0 = bxy.y*128, n0 = bxy.x*128;
  int wr = wid>>1, wc = wid&1;
  int lm = lane&15, lg = lane>>4;
  int lgs = lg ^ ((lm>>1)&3);
  int row0 = tid>>2,         kc0 = (((tid&3) ^ ((tid>>3)&3)))*8;
  int row1 = (256+tid)>>2,   kc1 = kc0;
  int ar0 = m0+row0; if(ar0 > M-1) ar0 = M-1;
  int ar1 = m0+row1; if(ar1 > M-1) ar1 = M-1;
  const unsigned short* gA0 = A  + (size_t)ar0*K + kc0;
  const unsigned short* gA1 = A  + (size_t)ar1*K + kc1;
  const unsigned short* gB0 = WT + (size_t)(n0+row0)*K + kc0;
  const unsigned short* gB1 = WT + (size_t)(n0+row1)*K + kc1;
  unsigned short* lA0 = As + (wid*64)*8;
  unsigned short* lA1 = As + (256 + wid*64)*8;
  unsigned short* lB0 = Bs + (wid*64)*8;
  unsigned short* lB1 = Bs + (256 + wid*64)*8;

#define STAGE_(buf, kt) do{ \
    __builtin_amdgcn_global_load_lds((g_void*)(gA0 + (kt)), (lds_void*)(lA0 + (buf)*4096), 16, 0, 0); \
    __builtin_amdgcn_global_load_lds((g_void*)(gB0 + (kt)), (lds_void*)(lB0 + (buf)*4096), 16, 0, 0); \
    __builtin_amdgcn_global_load_lds((g_void*)(gA1 + (kt)), (lds_void*)(lA1 + (buf)*4096), 16, 0, 0); \
    __builtin_amdgcn_global_load_lds((g_void*)(gB1 + (kt)), (lds_void*)(lB1 + (buf)*4096), 16, 0, 0); \
  }while(0)

  f32x4 acc[4][4] = {};
  const int nt = K/32;
  STAGE_(0, 0);
  __syncthreads();
  for(int t=0; t<nt; t+=2){
    STAGE_(1, (t+1)*32);
    {
      short8 af[4], bfv[4];
      #pragma unroll
      for(int i=0;i<4;++i){
        af[i]  = *(const short8*)(As + (64*wr + 16*i + lm)*32 + lgs*8);
        bfv[i] = *(const short8*)(Bs + (64*wc + 16*i + lm)*32 + lgs*8);
      }
      #pragma unroll
      for(int i=0;i<4;++i)
        #pragma unroll
        for(int j=0;j<4;++j)
          acc[i][j] = __builtin_amdgcn_mfma_f32_16x16x32_bf16(af[i], bfv[j], acc[i][j], 0,0,0);
    }
    __syncthreads();
    if(t+2 < nt) STAGE_(0, (t+2)*32);
    {
      short8 af[4], bfv[4];
      #pragma unroll
      for(int i=0;i<4;++i){
        af[i]  = *(const short8*)(As + 4096 + (64*wr + 16*i + lm)*32 + lgs*8);
        bfv[i] = *(const short8*)(Bs + 4096 + (64*wc + 16*i + lm)*32 + lgs*8);
      }
      #pragma unroll
      for(int i=0;i<4;++i)
        #pragma unroll
        for(int j=0;j<4;++j)
          acc[i][j] = __builtin_amdgcn_mfma_f32_16x16x32_bf16(af[i], bfv[j], acc[i][j], 0,0,0);
    }
    __syncthreads();
  }
#undef STAGE_
  #pragma unroll
  for(int i=0;i<4;++i){
    #pragma unroll
    for(int j=0;j<4;++j){
      int gcol = n0 + 64*wc + 16*j + lm;
      float bv = bias ? bias[gcol] : 0.f;
      #pragma unroll
      for(int r=0;r<4;++r){
        int grow = m0 + 64*wr + 16*i + lg*4 + r;
        if(grow < M){
          float cv = acc[i][j][r] + bv;
          if(ACT==1){
            float xx = cv;
            float p = xx*fmaf(xx*xx, 0.10294517f, 2.3022079f);
            float q = exp2f(p);
            cv = xx - xx*__builtin_amdgcn_rcpf(1.0f+q);
          }
          if(RESID) cv += resid[(size_t)grow*Nc + gcol];
          if(OUTBF16) ((unsigned short*)Cout)[(size_t)grow*Nc+gcol] = f2bf(cv);
          else        ((float*)Cout)[(size_t)grow*Nc+gcol] = cv;
        }
      }
    }
  }
}

// ---------------- bf16 MFMA GEMM 256x128, BK=32, 8 waves, dbuf + XCD swz + bank swizzle ----------------
template<int ACT, int RESID, int OUTBF16>
__global__ __launch_bounds__(512, 4) void gemm256_bf16(
    const unsigned short* __restrict__ A, const unsigned short* __restrict__ WT,
    const float* __restrict__ bias, const float* __restrict__ resid,
    void* __restrict__ Cout, int M, int K, int Nc){
  __shared__ unsigned short As[2*256*32];   // 32 KB
  __shared__ unsigned short Bs[2*128*32];   // 16 KB
  int tid = threadIdx.x, lane = tid&63, wid = tid>>6;
  int2 bxy = xcd_swz(gridDim.x, gridDim.y);
  int m0 = bxy.y*256, n0 = bxy.x*128;
  int wm = wid>>1, wn = wid&1;
  int lm = lane&15, lg = lane>>4;
  int lgs = lg ^ ((lm>>1)&3);
  int rowA0 = tid>>2, rowA1 = 128 + (tid>>2), rowB = tid>>2;
  int kc = (((tid&3) ^ ((tid>>3)&3)))*8;
  int arA0 = m0+rowA0; if(arA0 > M-1) arA0 = M-1;
  int arA1 = m0+rowA1; if(arA1 > M-1) arA1 = M-1;
  const unsigned short* gA0 = A  + (size_t)arA0*K + kc;
  const unsigned short* gA1 = A  + (size_t)arA1*K + kc;
  const unsigned short* gB0 = WT + (size_t)(n0+rowB)*K + kc;
  unsigned short* lA0 = As + wid*512;
  unsigned short* lA1 = As + 4096 + wid*512;
  unsigned short* lB0 = Bs + wid*512;

#define STAGE2_(buf, kt) do{ \
    __builtin_amdgcn_global_load_lds((g_void*)(gA0 + (kt)), (lds_void*)(lA0 + (buf)*8192), 16, 0, 0); \
    __builtin_amdgcn_global_load_lds((g_void*)(gB0 + (kt)), (lds_void*)(lB0 + (buf)*4096), 16, 0, 0); \
    __builtin_amdgcn_global_load_lds((g_void*)(gA1 + (kt)), (lds_void*)(lA1 + (buf)*8192), 16, 0, 0); \
  }while(0)

  f32x4 acc[4][4] = {};
  const int nt = K/32;
  STAGE2_(0, 0);
  __syncthreads();
  for(int t=0; t<nt; ++t){
    int buf = t&1;
    if(t+1 < nt) STAGE2_(buf^1, (t+1)*32);
    const unsigned short* abase = As + buf*8192;
    const unsigned short* bbase = Bs + buf*4096;
    short8 af[4], bfv[4];
    #pragma unroll
    for(int i=0;i<4;++i)
      af[i] = *(const short8*)(abase + (wm*64 + i*16 + lm)*32 + lgs*8);
    #pragma unroll
    for(int j=0;j<4;++j)
      bfv[j] = *(const short8*)(bbase + (wn*64 + j*16 + lm)*32 + lgs*8);
    __builtin_amdgcn_s_setprio(1);
    #pragma unroll
    for(int i=0;i<4;++i)
      #pragma unroll
      for(int j=0;j<4;++j)
        acc[i][j] = __builtin_amdgcn_mfma_f32_16x16x32_bf16(af[i], bfv[j], acc[i][j], 0,0,0);
    __builtin_amdgcn_s_setprio(0);
    __syncthreads();
  }
#undef STAGE2_
  #pragma unroll
  for(int i=0;i<4;++i){
    #pragma unroll
    for(int j=0;j<4;++j){
      int gcol = n0 + wn*64 + j*16 + lm;
      float bv = bias ? bias[gcol] : 0.f;
      #pragma unroll
      for(int r=0;r<4;++r){
        int grow = m0 + wm*64 + i*16 + lg*4 + r;
        if(grow < M){
          float cv = acc[i][j][r] + bv;
          if(ACT==1){
            float xx = cv;
            float p = xx*fmaf(xx*xx, 0.10294517f, 2.3022079f);
            float q = exp2f(p);
            cv = xx - xx*__builtin_amdgcn_rcpf(1.0f+q);
          }
          if(RESID) cv += resid[(size_t)grow*Nc + gcol];
          if(OUTBF16) ((unsigned short*)Cout)[(size_t)grow*Nc+gcol] = f2bf(cv);
          else        ((float*)Cout)[(size_t)grow*Nc+gcol] = cv;
        }
      }
    }
  }
}

// ---------------- fused cheap path v3: MFMA kp/qp + float4 kk + 2-row coef ----------------
__global__ __launch_bounds__(512) void cheap_kernel(
    const unsigned short* __restrict__ qkv,
    const unsigned short* __restrict__ WcqT, const float* __restrict__ bcq,
    const unsigned short* __restrict__ WckT, const float* __restrict__ bck,
    const float* __restrict__ proj_n, float* __restrict__ coef){
  int bh = blockIdx.x; int b = bh/H_, h = bh%H_;
  int tid = threadIdx.x, lane = tid&63, wv = tid>>6;
  int lm = lane&15, lg = lane>>4;
  __shared__ __align__(16) unsigned short KQ[208*64];
  __shared__ __align__(16) float P2T[32*212];
  __shared__ __align__(16) float PNT[24*200];
  __shared__ float KK[768];
  const unsigned short* Kbase = qkv + ((size_t)(b*N_)*3 + 1)*C_ + h*CH_;
  const unsigned short* Qbase = qkv + ((size_t)(b*N_)*3 + 0)*C_ + h*CH_;
  for(int idx = tid; idx < 208*32; idx += 512){
    int k = idx>>5, cp = idx&31;
    unsigned v = (k < N_) ? *(const unsigned*)(Kbase + (size_t)k*3*C_ + cp*2) : 0u;
    unsigned off = (unsigned)(k*128 + cp*4) ^ ((unsigned)(k&7)<<4);
    *(unsigned*)((char*)KQ + off) = v;
  }
  for(int idx = tid; idx < 24*200; idx += 512){
    int r = idx/200, n = idx - r*200;
    PNT[idx] = (n < N_) ? proj_n[n*24+r] : 0.f;
  }
  __syncthreads();
  {
    short8 bfr[2][2];
    #pragma unroll
    for(int j=0;j<2;++j)
      #pragma unroll
      for(int s=0;s<2;++s)
        bfr[j][s] = *(const short8*)(WckT + (j*16+lm)*64 + s*32 + lg*8);
    float bias[2] = { bck[lm], bck[16+lm] };
    for(int t=wv; t<13; t+=8){
      int row = t*16 + lm;
      unsigned o0 = (unsigned)(row*128 + lg*16) ^ ((unsigned)(row&7)<<4);
      unsigned o1 = (unsigned)(row*128 + 64 + lg*16) ^ ((unsigned)(row&7)<<4);
      short8 a0 = *(const short8*)((char*)KQ + o0);
      short8 a1 = *(const short8*)((char*)KQ + o1);
      #pragma unroll
      for(int j=0;j<2;++j){
        f32x4 acc = (f32x4){0.f,0.f,0.f,0.f};
        acc = __builtin_amdgcn_mfma_f32_16x16x32_bf16(a0, bfr[j][0], acc, 0,0,0);
        acc = __builtin_amdgcn_mfma_f32_16x16x32_bf16(a1, bfr[j][1], acc, 0,0,0);
        #pragma unroll
        for(int r=0;r<4;++r)
          P2T[(j*16+lm)*212 + t*16 + lg*4 + r] = acc[r] + bias[j];
      }
    }
  }
  __syncthreads();
  {
    int i0 = tid, i1 = tid + 512;
    bool has1 = (i1 < 768);
    int c0 = i0/24, r0 = i0 - c0*24;
    int c1 = has1 ? i1/24 : 0, r1 = has1 ? (i1 - (i1/24)*24) : 0;
    float a0=0.f, a1=0.f;
    for(int n=0;n<200;n+=4){
      float4 x0 = *(const float4*)&P2T[c0*212+n];
      float4 p0 = *(const float4*)&PNT[r0*200+n];
      a0 += x0.x*p0.x; a0 += x0.y*p0.y; a0 += x0.z*p0.z; a0 += x0.w*p0.w;
      if(has1){
        float4 x1 = *(const float4*)&P2T[c1*212+n];
        float4 p1 = *(const float4*)&PNT[r1*200+n];
        a1 += x1.x*p1.x; a1 += x1.y*p1.y; a1 += x1.z*p1.z; a1 += x1.w*p1.w;
      }
    }
    KK[i0] = a0;
    if(has1) KK[i1] = a1;
    for(int idx = tid; idx < 197*32; idx += 512){
      int k = idx>>5, cp = idx&31;
      unsigned v = *(const unsigned*)(Qbase + (size_t)k*3*C_ + cp*2);
      unsigned off = (unsigned)(k*128 + cp*4) ^ ((unsigned)(k&7)<<4);
      *(unsigned*)((char*)KQ + off) = v;
    }
  }
  __syncthreads();
  float* QP = P2T;
  {
    short8 bfr[2][2];
    #pragma unroll
    for(int j=0;j<2;++j)
      #pragma unroll
      for(int s=0;s<2;++s)
        bfr[j][s] = *(const short8*)(WcqT + (j*16+lm)*64 + s*32 + lg*8);
    float bias[2] = { bcq[lm], bcq[16+lm] };
    for(int t=wv; t<13; t+=8){
      int row = t*16 + lm;
      unsigned o0 = (unsigned)(row*128 + lg*16) ^ ((unsigned)(row&7)<<4);
      unsigned o1 = (unsigned)(row*128 + 64 + lg*16) ^ ((unsigned)(row&7)<<4);
      short8 a0 = *(const short8*)((char*)KQ + o0);
      short8 a1 = *(const short8*)((char*)KQ + o1);
      #pragma unroll
      for(int j=0;j<2;++j){
        f32x4 acc = (f32x4){0.f,0.f,0.f,0.f};
        acc = __builtin_amdgcn_mfma_f32_16x16x32_bf16(a0, bfr[j][0], acc, 0,0,0);
        acc = __builtin_amdgcn_mfma_f32_16x16x32_bf16(a1, bfr[j][1], acc, 0,0,0);
        #pragma unroll
        for(int r=0;r<4;++r)
          QP[(t*16 + lg*4 + r)*32 + j*16 + lm] = acc[r] + bias[j];
      }
    }
  }
  __syncthreads();
  int l32 = lane & 31, half = lane >> 5;
  bool act = l32 < RN_;
  int ll = act ? l32 : 0;
  float kkreg[32];
  #pragma unroll
  for(int c=0;c<32;++c) kkreg[c] = KK[c*24 + ll];
  for(int i2 = wv*2; i2 < 196; i2 += 16){
    int i = i2 + half;
    int n = i + 1;
    float accv = 0.f;
    #pragma unroll
    for(int q=0;q<8;++q){
      float4 v4 = *(const float4*)&QP[n*32 + q*4];
      accv += v4.x*kkreg[q*4];   accv += v4.y*kkreg[q*4+1];
      accv += v4.z*kkreg[q*4+2]; accv += v4.w*kkreg[q*4+3];
    }
    float val = act ? accv * 0.28867513459481287f : -INFINITY;
    float m = val;
    #pragma unroll
    for(int o=16;o>=1;o>>=1) m = fmaxf(m, __shfl_xor(m, o));
    float e = act ? expf(val - m) : 0.f;
    float ssum = e;
    #pragma unroll
    for(int o=16;o>=1;o>>=1) ssum += __shfl_xor(ssum, o);
    float p = e/ssum;
    unsigned u = __float_as_uint(e);
    unsigned pL=0, pH=0;
    #pragma unroll
    for(int bit=30; bit>=0; --bit){
      unsigned tL = pL | (1u<<bit), tH = pH | (1u<<bit);
      unsigned thr = half ? tH : tL;
      unsigned long long bal = __ballot(u >= thr);
      int cL = __popcll(bal & 0xFFFFFFull);
      int cH = __popcll((bal>>32) & 0xFFFFFFull);
      if(cL>=8) pL=tL;
      if(cH>=8) pH=tH;
    }
    unsigned myp = half ? pH : pL;
    if(act) coef[((size_t)bh*196 + i)*24 + l32] = (u >= myp) ? p : 0.f;
  }
}

// ---------------- basis[r][j] = thresh(|proj_back_n[j][r]|) ----------------
__global__ __launch_bounds__(256) void basis_kernel(const float* __restrict__ pb,
    float* __restrict__ basis){
  int t = blockIdx.x*256 + threadIdx.x;
  if(t < RN_*N_){
    int r = t/N_, j = t%N_;
    float v = fabsf(pb[(size_t)j*RN_ + r]);
    basis[t] = (v > 0.02f) ? v : 0.f;
  }
}

// ---------------- mask v8: 8 rows/wave + per-row ballot SKIP once done ----------------
// done is wave-uniform -> the continue is a scalar branch; selection identical
// (once done, prefix never changes; skipping the dead ballots changes nothing).
__global__ __launch_bounds__(256) void mask8_kernel(const float* __restrict__ coef,
    const float* __restrict__ basis, unsigned int* __restrict__ maskw){
  __shared__ float Bs[24*256];
  int tid = threadIdx.x, lane = tid&63, wv = tid>>6;
  for(int idx = tid; idx < 24*256; idx += 256){
    int r = idx>>8, q = idx&255;
    int e = ((q&3)<<6) | (q>>2);
    Bs[idx] = (e < N_) ? basis[r*N_ + e] : 0.f;
  }
  __syncthreads();
  int rowbase = blockIdx.x*32 + wv*8;
  float4 av[8];
  unsigned done = 0;
  #pragma unroll
  for(int j=0;j<8;++j){
    int row = rowbase + j;
    int qi = row % N_; int bh = row / N_;
    if(qi==0){
      if(lane<8){
        unsigned v = (lane<6)?0xFFFFFFFFu:((lane==6)?0x1Fu:0u);
        maskw[(size_t)row*8+lane]=v;
      }
      av[j] = make_float4(0.f,0.f,0.f,0.f);
      done |= (1u<<j);
    } else {
      float cfv = (lane<24) ? coef[((size_t)bh*196 + (qi-1))*24 + lane] : 0.f;
      unsigned long long nz = __ballot(cfv != 0.f);
      float4 a = make_float4(0.f,0.f,0.f,0.f);
      while(nz){
        int r = __ffsll((unsigned long long)nz) - 1;
        nz &= nz - 1;
        float c = __uint_as_float(__builtin_amdgcn_readlane(__float_as_uint(cfv), r));
        float4 bv = *(const float4*)&Bs[r*256 + lane*4];
        a.x += c*bv.x; a.y += c*bv.y; a.z += c*bv.z; a.w += c*bv.w;
      }
      av[j] = a;
    }
  }
  unsigned u[8][4];
  #pragma unroll
  for(int j=0;j<8;++j){
    u[j][0]=__float_as_uint(av[j].x); u[j][1]=__float_as_uint(av[j].y);
    u[j][2]=__float_as_uint(av[j].z); u[j][3]=__float_as_uint(av[j].w);
  }
  unsigned prefix[8] = {0,0,0,0,0,0,0,0};
  for(int bit=30; bit>=0; --bit){
    if(done == 0xFFu) break;
    #pragma unroll
    for(int j=0;j<8;++j){
      if((done>>j)&1u) continue;          // wave-uniform scalar skip
      unsigned t = prefix[j] | (1u<<bit);
      int c = __popcll(__ballot(u[j][0] >= t)) + __popcll(__ballot(u[j][1] >= t))
            + __popcll(__ballot(u[j][2] >= t)) + __popcll(__ballot(u[j][3] >= t));
      if(c >= 50) prefix[j] = t;
      if(c == 50) done |= (1u<<j);
    }
  }
  #pragma unroll
  for(int j=0;j<8;++j){
    int row = rowbase + j;
    if(row % N_ == 0) continue;
    #pragma unroll
    for(int r=0;r<4;++r){
      bool valid = (r<3) | (lane<5);
      bool keep = valid && (u[j][r] >= prefix[j]);
      unsigned long long bal = __ballot(keep);
      if(lane==0){
        maskw[(size_t)row*8 + 2*r]   = (unsigned)(bal & 0xFFFFFFFFull);
        maskw[(size_t)row*8 + 2*r+1] = (unsigned)(bal>>32);
      }
    }
  }
}

// ---------------- masked attention v3: MFMA flash-style, one block per (b,h) ----------------
__global__ __launch_bounds__(512) void attn3_kernel(const unsigned short* __restrict__ qkv,
    const unsigned int* __restrict__ maskw, unsigned short* __restrict__ attn_out){
  int bh = blockIdx.x; int b = bh/H_, h = bh%H_;
  int tid = threadIdx.x, lane = tid&63, wv = tid>>6;
  int g = lane>>4, c16 = lane&15;
  __shared__ unsigned short Kb[208*64];
  __shared__ unsigned short Vt[64*220];
  __shared__ unsigned short Pl[8*16*224];
  __shared__ unsigned int   Ml[8][16][8];
  const unsigned short* Kbase = qkv + ((size_t)(b*N_)*3 + 1)*C_ + h*CH_;
  const unsigned short* Vbase = qkv + ((size_t)(b*N_)*3 + 2)*C_ + h*CH_;
  for(int idx = tid; idx < 208*32; idx += 512){
    int k = idx>>5, cp = idx&31;
    unsigned pk = 0;
    if(k < N_) pk = *(const unsigned*)(Kbase + (size_t)k*3*C_ + cp*2);
    unsigned off = (unsigned)(k*128 + cp*4) ^ ((unsigned)(k&7)<<4);
    *(unsigned*)((char*)Kb + off) = pk;
  }
  for(int idx = tid; idx < 64*110; idx += 512){
    int kp = idx>>6, c = idx&63;
    int k0 = kp*2, k1 = kp*2+1;
    unsigned v0 = (k0<N_) ? Vbase[(size_t)k0*3*C_ + c] : 0;
    unsigned v1 = (k1<N_) ? Vbase[(size_t)k1*3*C_ + c] : 0;
    *(unsigned*)((char*)Vt + c*440 + kp*4) = v0 | (v1<<16);
  }
  __syncthreads();
  size_t pbase = (size_t)wv*16*448;
  for(int i=lane;i<128;i+=64){
    int ql = i>>3; int kk = 208 + (i&7)*2;
    unsigned off = (unsigned)(ql*448 + kk*2) ^ ((unsigned)(ql&7)<<4);
    *(unsigned*)((char*)Pl + pbase + off) = 0u;
  }
  for(int t = wv; t < 13; t += 8){
    int qb = t*16;
    for(int i = lane; i < 128; i += 64){
      int row = i>>3, word = i&7;
      int qr = qb+row; if(qr>196) qr=196;
      Ml[wv][row][word] = maskw[(size_t)(bh*N_+qr)*8 + word];
    }
    int qrow = qb + c16; if(qrow>196) qrow=196;
    const unsigned short* Qr = qkv + ((size_t)(b*N_+qrow)*3)*C_ + h*CH_ + g*8;
    short8 af[2];
    af[0] = *(const short8*)(Qr);
    af[1] = *(const short8*)(Qr + 32);
    f32x4 sf[13];
    #pragma unroll
    for(int f=0;f<13;++f){
      sf[f] = (f32x4){0.f,0.f,0.f,0.f};
      #pragma unroll
      for(int s=0;s<2;++s){
        int row = f*16 + c16;
        unsigned off = (unsigned)(row*128 + s*64 + g*16) ^ ((unsigned)(row&7)<<4);
        short8 bfr = *(const short8*)((char*)Kb + off);
        sf[f] = __builtin_amdgcn_mfma_f32_16x16x32_bf16(af[s], bfr, sf[f], 0,0,0);
      }
      sf[f][0]*=0.125f; sf[f][1]*=0.125f; sf[f][2]*=0.125f; sf[f][3]*=0.125f;
    }
    unsigned keep[4] = {0,0,0,0};
    float m[4] = {-FLT_MAX,-FLT_MAX,-FLT_MAX,-FLT_MAX};
    #pragma unroll
    for(int f=0;f<13;++f)
      #pragma unroll
      for(int r=0;r<4;++r){
        unsigned bit = (Ml[wv][g*4+r][f>>1] >> ((f&1)*16 + c16)) & 1u;
        keep[r] |= bit<<f;
        if(bit) m[r] = fmaxf(m[r], sf[f][r]);
      }
    #pragma unroll
    for(int r=0;r<4;++r){
      #pragma unroll
      for(int o=8;o>=1;o>>=1) m[r] = fmaxf(m[r], __shfl_xor(m[r], o));
    }
    float sum[4] = {0,0,0,0};
    #pragma unroll
    for(int f=0;f<13;++f)
      #pragma unroll
      for(int r=0;r<4;++r){
        float e = ((keep[r]>>f)&1u) ? expf(sf[f][r]-m[r]) : 0.f;
        sf[f][r] = e; sum[r] += e;
      }
    #pragma unroll
    for(int r=0;r<4;++r){
      #pragma unroll
      for(int o=8;o>=1;o>>=1) sum[r] += __shfl_xor(sum[r], o);
      sum[r] = 1.f/sum[r];
    }
    #pragma unroll
    for(int f=0;f<13;++f)
      #pragma unroll
      for(int r=0;r<4;++r){
        int ql = g*4+r;
        unsigned off = (unsigned)(ql*448 + (f*16+c16)*2) ^ ((unsigned)(ql&7)<<4);
        *(unsigned short*)((char*)Pl + pbase + off) = f2bf(sf[f][r]*sum[r]);
      }
    #pragma unroll
    for(int ct=0;ct<4;++ct){
      f32x4 oa = (f32x4){0.f,0.f,0.f,0.f};
      #pragma unroll
      for(int ks=0;ks<7;++ks){
        unsigned offa = (unsigned)(c16*448 + (ks*32+g*8)*2) ^ ((unsigned)(c16&7)<<4);
        short8 pa = *(const short8*)((char*)Pl + pbase + offa);
        short8 vb = *(const short8*)((char*)Vt + (size_t)(ct*16+c16)*440 + (ks*32+g*8)*2);
        oa = __builtin_amdgcn_mfma_f32_16x16x32_bf16(pa, vb, oa, 0,0,0);
      }
      #pragma unroll
      for(int r=0;r<4;++r){
        int qq = qb + g*4 + r;
        if(qq < N_)
          attn_out[((size_t)(b*N_+qq))*C_ + h*CH_ + ct*16 + c16] = f2bf(oa[r]);
      }
    }
  }
}

extern "C" void kernel_launch(void* const* d_in, const int* in_sizes, int n_in,
                              void* d_out, int out_size, void* d_ws, size_t ws_size,
                              hipStream_t stream){
  const float* x    =(const float*)d_in[0];
  const float* Wqkv =(const float*)d_in[1];
  const float* Wcq  =(const float*)d_in[2];
  const float* bcq  =(const float*)d_in[3];
  const float* Wck  =(const float*)d_in[4];
  const float* bck  =(const float*)d_in[5];
  const float* proj_n=(const float*)d_in[6];
  const float* proj_back_n=(const float*)d_in[7];
  const float* Wproj=(const float*)d_in[8];
  const float* bproj=(const float*)d_in[9];
  const float* g1=(const float*)d_in[10];
  const float* b1=(const float*)d_in[11];
  const float* g2=(const float*)d_in[12];
  const float* b2=(const float*)d_in[13];
  const float* W1=(const float*)d_in[14];
  const float* bfc1=(const float*)d_in[15];
  const float* W2=(const float*)d_in[16];
  const float* bfc2=(const float*)d_in[17];
  float* out=(float*)d_out;

  float* ws=(float*)d_ws;
  size_t off=0;
  unsigned short* hbuf = (unsigned short*)(ws+off); off += (size_t)12608*768/2;
  size_t qkv_off = off;
  unsigned short* qkv = (unsigned short*)(ws+off); off += (size_t)12608*2304/2;
  off += (size_t)768*197*32;   // padding (hidden alias headroom)
  off += (size_t)768*197*32;
  off += (size_t)768*32*24;
  float* coef = ws+off;        off += (size_t)768*196*24;
  float* basis= ws+off;        off += 4736;
  unsigned int* maskw=(unsigned int*)(ws+off); off += (size_t)768*197*8;
  unsigned short* WqkvT = (unsigned short*)(ws+off); off += (size_t)2304*768/2;
  unsigned short* WprojT= (unsigned short*)(ws+off); off += (size_t)768*768/2;
  unsigned short* W1T   = (unsigned short*)(ws+off); off += (size_t)3072*768/2;
  unsigned short* W2T   = (unsigned short*)(ws+off); off += (size_t)768*3072/2;
  unsigned short* WcqT  = (unsigned short*)(ws+off); off += 1024;
  unsigned short* WckT  = (unsigned short*)(ws+off); off += 1024;
  unsigned short* attn_out = hbuf;                    // alias (hbuf dead after qkv GEMM)
  unsigned short* hidden = (unsigned short*)(ws+qkv_off); // alias (qkv dead by MLP)
  float* x1 = out;

  // 0. weight transpose+bf16 conversions
  wtrans_kernel<<<dim3(72,24),256,0,stream>>>(Wqkv, WqkvT, 768, 2304);
  wtrans_kernel<<<dim3(24,24),256,0,stream>>>(Wproj, WprojT, 768, 768);
  wtrans_kernel<<<dim3(96,24),256,0,stream>>>(W1, W1T, 768, 3072);
  wtrans_kernel<<<dim3(24,96),256,0,stream>>>(W2, W2T, 3072, 768);
  wcprep_kernel<<<8,256,0,stream>>>(Wcq, Wck, WcqT, WckT);
  // 1. h = LN(x) -> bf16
  ln_kernel<<<12608,256,0,stream>>>(x,g1,b1,hbuf);
  // 2. qkv = h @ Wqkv (bf16 out)
  gemm256_bf16<0,0,1><<<dim3(18,50),512,0,stream>>>(hbuf,WqkvT,nullptr,nullptr,qkv,12608,768,2304);
  // 3. fused cheap path v3 (MFMA kp/qp)
  cheap_kernel<<<768,512,0,stream>>>(qkv,WcqT,bcq,WckT,bck,proj_n,coef);
  // 4. basis
  basis_kernel<<<19,256,0,stream>>>(proj_back_n,basis);
  // 5. approx_attn + budget mask (8 rows/wave + per-row ballot skip)
  mask8_kernel<<<4728,256,0,stream>>>(coef,basis,maskw);
  // 6. masked attention (MFMA)
  attn3_kernel<<<768,512,0,stream>>>(qkv,maskw,attn_out);
  // 7. x1 = x + attn_out @ Wproj + bproj   (x1 == d_out)
  gemm_bf16<0,1,0><<<dim3(6,99),256,0,stream>>>(attn_out,WprojT,bproj,x,x1,12608,768,768);
  // 8. h2 = LN(x1) -> bf16 (reuse hbuf)
  ln_kernel<<<12608,256,0,stream>>>(x1,g2,b2,hbuf);
  // 9. hidden = gelu(h2 @ W1 + bfc1) -> bf16
  gemm256_bf16<1,0,1><<<dim3(24,50),512,0,stream>>>(hbuf,W1T,bfc1,nullptr,hidden,12608,768,3072);
  // 10. out = x1 + hidden @ W2 + bfc2
  gemm_bf16<0,1,0><<<dim3(6,99),256,0,stream>>>(hidden,W2T,bfc2,x1,out,12608,3072,768);
}

// Round 24
// 642.228 us; speedup vs baseline: 1.1083x; 1.0002x over previous
//
#include <hip/hip_runtime.h>
#include <math.h>
#include <float.h>

#define B_ 64
#define N_ 197
#define C_ 768
#define H_ 12
#define CH_ 64
#define RC_ 32
#define RN_ 24

typedef __attribute__((ext_vector_type(8))) short short8;
typedef __attribute__((ext_vector_type(4))) float f32x4;
typedef __attribute__((address_space(3))) void  lds_void;
typedef __attribute__((address_space(1))) const void g_void;

__device__ __forceinline__ float warp_sum(float v){
  #pragma unroll
  for(int o=32;o>=1;o>>=1) v += __shfl_xor(v,o);
  return v;
}
__device__ __forceinline__ float warp_max(float v){
  #pragma unroll
  for(int o=32;o>=1;o>>=1) v = fmaxf(v,__shfl_xor(v,o));
  return v;
}
__device__ __forceinline__ unsigned short f2bf(float f){
  union{float f; unsigned u;} c; c.f = f;
  unsigned r = c.u + 0x7FFF + ((c.u>>16)&1);
  return (unsigned short)(r>>16);
}
__device__ __forceinline__ float bf2f(unsigned short u){
  union{unsigned u; float f;} c; c.u = ((unsigned)u)<<16; return c.f;
}
// bijective XCD-aware block swizzle (m204)
__device__ __forceinline__ int2 xcd_swz(int gx, int gy){
  int nwg = gx*gy;
  int id = blockIdx.x + gx*blockIdx.y;
  int xcd = id & 7, loc = id >> 3;
  int q = nwg >> 3, r = nwg & 7;
  int swz = (xcd < r ? xcd*(q+1) : r*(q+1) + (xcd-r)*q) + loc;
  return make_int2(swz % gx, swz / gx);
}

// ---------------- LayerNorm: one block per row of 768, bf16 out ----------------
__global__ __launch_bounds__(256) void ln_kernel(const float* __restrict__ x,
    const float* __restrict__ g, const float* __restrict__ bb, unsigned short* __restrict__ out){
  int r = blockIdx.x; int tid = threadIdx.x;
  const float* xr = x + (size_t)r*C_;
  float v0=xr[tid], v1=xr[tid+256], v2=xr[tid+512];
  __shared__ float red[8];
  float s = warp_sum(v0+v1+v2);
  if((tid&63)==0) red[tid>>6]=s;
  __syncthreads();
  float mu = (red[0]+red[1]+red[2]+red[3]) * (1.f/768.f);
  float d0=v0-mu,d1=v1-mu,d2=v2-mu;
  float s2 = warp_sum(d0*d0+d1*d1+d2*d2);
  if((tid&63)==0) red[4+(tid>>6)]=s2;
  __syncthreads();
  float rinv = rsqrtf((red[4]+red[5]+red[6]+red[7])*(1.f/768.f)+1e-5f);
  unsigned short* orow = out + (size_t)r*C_;
  orow[tid]     = f2bf(d0*rinv*g[tid]    +bb[tid]);
  orow[tid+256] = f2bf(d1*rinv*g[tid+256]+bb[tid+256]);
  orow[tid+512] = f2bf(d2*rinv*g[tid+512]+bb[tid+512]);
}

// ---------------- transpose+convert: in f32 [K][N] -> out bf16 [N][K] ----------------
__global__ __launch_bounds__(256) void wtrans_kernel(const float* __restrict__ in,
    unsigned short* __restrict__ out, int K, int N){
  __shared__ float tile[32][33];
  int n0 = blockIdx.x*32, k0 = blockIdx.y*32;
  int tx = threadIdx.x&31, ty = threadIdx.x>>5;
  #pragma unroll
  for(int i=0;i<4;++i) tile[ty+8*i][tx] = in[(size_t)(k0+ty+8*i)*N + n0+tx];
  __syncthreads();
  #pragma unroll
  for(int i=0;i<4;++i) out[(size_t)(n0+ty+8*i)*K + k0+tx] = f2bf(tile[tx][ty+8*i]);
}

// ---------------- Wcq/Wck f32[64][32] -> bf16 transposed [32][64] ----------------
__global__ __launch_bounds__(256) void wcprep_kernel(const float* __restrict__ Wcq,
    const float* __restrict__ Wck, unsigned short* __restrict__ WcqT,
    unsigned short* __restrict__ WckT){
  int t = blockIdx.x*256 + threadIdx.x;
  if(t < 2048){
    int c = t>>6, k = t&63;
    WcqT[t] = f2bf(Wcq[k*32+c]);
    WckT[t] = f2bf(Wck[k*32+c]);
  }
}

// ---------------- bf16 MFMA GEMM 64x128, BK=32, dbuf + XCD swz + bank swizzle ----------------
// For grid-limited N=768 GEMMs (proj/fc2): doubles block count vs 128^2 ->
// 4.6 blocks/CU TLP to cover the barrier drain. 4 waves each own 64x32
// (acc[4][2]=32 VGPR). 24 KB LDS dbuf. Same K order -> bit-identical.
template<int ACT, int RESID, int OUTBF16>
__global__ __launch_bounds__(256) void gemm64_bf16(
    const unsigned short* __restrict__ A, const unsigned short* __restrict__ WT,
    const float* __restrict__ bias, const float* __restrict__ resid,
    void* __restrict__ Cout, int M, int K, int Nc){
  __shared__ unsigned short As[2*64*32];    // 8 KB
  __shared__ unsigned short Bs[2*128*32];   // 16 KB
  int tid = threadIdx.x, lane = tid&63, wid = tid>>6;
  int2 bxy = xcd_swz(gridDim.x, gridDim.y);
  int m0 = bxy.y*64, n0 = bxy.x*128;
  int wc = wid;                             // wave owns 32-col panel wc*32
  int lm = lane&15, lg = lane>>4;
  int lgs = lg ^ ((lm>>1)&3);
  // staging: A 256 chunks (cid=tid), B 512 chunks (cid=tid, tid+256)
  int rowA = tid>>2;
  int kc   = (((tid&3) ^ ((tid>>3)&3)))*8;  // same key for all rows handled by this thread
  int arA = m0+rowA; if(arA > M-1) arA = M-1;
  const unsigned short* gA0 = A  + (size_t)arA*K + kc;
  const unsigned short* gB0 = WT + (size_t)(n0 + (tid>>2))*K + kc;
  const unsigned short* gB1 = WT + (size_t)(n0 + 64 + (tid>>2))*K + kc;
  unsigned short* lA0 = As + wid*512;
  unsigned short* lB0 = Bs + wid*512;
  unsigned short* lB1 = Bs + 2048 + wid*512;

#define STAGE64_(buf, kt) do{ \
    __builtin_amdgcn_global_load_lds((g_void*)(gA0 + (kt)), (lds_void*)(lA0 + (buf)*2048), 16, 0, 0); \
    __builtin_amdgcn_global_load_lds((g_void*)(gB0 + (kt)), (lds_void*)(lB0 + (buf)*4096), 16, 0, 0); \
    __builtin_amdgcn_global_load_lds((g_void*)(gB1 + (kt)), (lds_void*)(lB1 + (buf)*4096), 16, 0, 0); \
  }while(0)

  f32x4 acc[4][2] = {};
  const int nt = K/32;
  STAGE64_(0, 0);
  __syncthreads();
  for(int t=0; t<nt; ++t){
    int buf = t&1;
    if(t+1 < nt) STAGE64_(buf^1, (t+1)*32);
    const unsigned short* abase = As + buf*2048;
    const unsigned short* bbase = Bs + buf*4096;
    short8 af[4], bfv[2];
    #pragma unroll
    for(int i=0;i<4;++i)
      af[i] = *(const short8*)(abase + (16*i + lm)*32 + lgs*8);
    #pragma unroll
    for(int j=0;j<2;++j)
      bfv[j] = *(const short8*)(bbase + (wc*32 + 16*j + lm)*32 + lgs*8);
    __builtin_amdgcn_s_setprio(1);
    #pragma unroll
    for(int i=0;i<4;++i)
      #pragma unroll
      for(int j=0;j<2;++j)
        acc[i][j] = __builtin_amdgcn_mfma_f32_16x16x32_bf16(af[i], bfv[j], acc[i][j], 0,0,0);
    __builtin_amdgcn_s_setprio(0);
    __syncthreads();
  }
#undef STAGE64_
  #pragma unroll
  for(int i=0;i<4;++i){
    #pragma unroll
    for(int j=0;j<2;++j){
      int gcol = n0 + wc*32 + 16*j + lm;
      float bv = bias ? bias[gcol] : 0.f;
      #pragma unroll
      for(int r=0;r<4;++r){
        int grow = m0 + 16*i + lg*4 + r;
        if(grow < M){
          float cv = acc[i][j][r] + bv;
          if(ACT==1){
            float xx = cv;
            float p = xx*fmaf(xx*xx, 0.10294517f, 2.3022079f);
            float q = exp2f(p);
            cv = xx - xx*__builtin_amdgcn_rcpf(1.0f+q);
          }
          if(RESID) cv += resid[(size_t)grow*Nc + gcol];
          if(OUTBF16) ((unsigned short*)Cout)[(size_t)grow*Nc+gcol] = f2bf(cv);
          else        ((float*)Cout)[(size_t)grow*Nc+gcol] = cv;
        }
      }
    }
  }
}

// ---------------- bf16 MFMA GEMM 256x128, BK=32, 8 waves, dbuf + XCD swz + bank swizzle ----------------
template<int ACT, int RESID, int OUTBF16>
__global__ __launch_bounds__(512, 4) void gemm256_bf16(
    const unsigned short* __restrict__ A, const unsigned short* __restrict__ WT,
    const float* __restrict__ bias, const float* __restrict__ resid,
    void* __restrict__ Cout, int M, int K, int Nc){
  __shared__ unsigned short As[2*256*32];   // 32 KB
  __shared__ unsigned short Bs[2*128*32];   // 16 KB
  int tid = threadIdx.x, lane = tid&63, wid = tid>>6;
  int2 bxy = xcd_swz(gridDim.x, gridDim.y);
  int m0 = bxy.y*256, n0 = bxy.x*128;
  int wm = wid>>1, wn = wid&1;
  int lm = lane&15, lg = lane>>4;
  int lgs = lg ^ ((lm>>1)&3);
  int rowA0 = tid>>2, rowA1 = 128 + (tid>>2), rowB = tid>>2;
  int kc = (((tid&3) ^ ((tid>>3)&3)))*8;
  int arA0 = m0+rowA0; if(arA0 > M-1) arA0 = M-1;
  int arA1 = m0+rowA1; if(arA1 > M-1) arA1 = M-1;
  const unsigned short* gA0 = A  + (size_t)arA0*K + kc;
  const unsigned short* gA1 = A  + (size_t)arA1*K + kc;
  const unsigned short* gB0 = WT + (size_t)(n0+rowB)*K + kc;
  unsigned short* lA0 = As + wid*512;
  unsigned short* lA1 = As + 4096 + wid*512;
  unsigned short* lB0 = Bs + wid*512;

#define STAGE2_(buf, kt) do{ \
    __builtin_amdgcn_global_load_lds((g_void*)(gA0 + (kt)), (lds_void*)(lA0 + (buf)*8192), 16, 0, 0); \
    __builtin_amdgcn_global_load_lds((g_void*)(gB0 + (kt)), (lds_void*)(lB0 + (buf)*4096), 16, 0, 0); \
    __builtin_amdgcn_global_load_lds((g_void*)(gA1 + (kt)), (lds_void*)(lA1 + (buf)*8192), 16, 0, 0); \
  }while(0)

  f32x4 acc[4][4] = {};
  const int nt = K/32;
  STAGE2_(0, 0);
  __syncthreads();
  for(int t=0; t<nt; ++t){
    int buf = t&1;
    if(t+1 < nt) STAGE2_(buf^1, (t+1)*32);
    const unsigned short* abase = As + buf*8192;
    const unsigned short* bbase = Bs + buf*4096;
    short8 af[4], bfv[4];
    #pragma unroll
    for(int i=0;i<4;++i)
      af[i] = *(const short8*)(abase + (wm*64 + i*16 + lm)*32 + lgs*8);
    #pragma unroll
    for(int j=0;j<4;++j)
      bfv[j] = *(const short8*)(bbase + (wn*64 + j*16 + lm)*32 + lgs*8);
    __builtin_amdgcn_s_setprio(1);
    #pragma unroll
    for(int i=0;i<4;++i)
      #pragma unroll
      for(int j=0;j<4;++j)
        acc[i][j] = __builtin_amdgcn_mfma_f32_16x16x32_bf16(af[i], bfv[j], acc[i][j], 0,0,0);
    __builtin_amdgcn_s_setprio(0);
    __syncthreads();
  }
#undef STAGE2_
  #pragma unroll
  for(int i=0;i<4;++i){
    #pragma unroll
    for(int j=0;j<4;++j){
      int gcol = n0 + wn*64 + j*16 + lm;
      float bv = bias ? bias[gcol] : 0.f;
      #pragma unroll
      for(int r=0;r<4;++r){
        int grow = m0 + wm*64 + i*16 + lg*4 + r;
        if(grow < M){
          float cv = acc[i][j][r] + bv;
          if(ACT==1){
            float xx = cv;
            float p = xx*fmaf(xx*xx, 0.10294517f, 2.3022079f);
            float q = exp2f(p);
            cv = xx - xx*__builtin_amdgcn_rcpf(1.0f+q);
          }
          if(RESID) cv += resid[(size_t)grow*Nc + gcol];
          if(OUTBF16) ((unsigned short*)Cout)[(size_t)grow*Nc+gcol] = f2bf(cv);
          else        ((float*)Cout)[(size_t)grow*Nc+gcol] = cv;
        }
      }
    }
  }
}

// ---------------- fused cheap path v3: MFMA kp/qp + float4 kk + 2-row coef ----------------
__global__ __launch_bounds__(512) void cheap_kernel(
    const unsigned short* __restrict__ qkv,
    const unsigned short* __restrict__ WcqT, const float* __restrict__ bcq,
    const unsigned short* __restrict__ WckT, const float* __restrict__ bck,
    const float* __restrict__ proj_n, float* __restrict__ coef){
  int bh = blockIdx.x; int b = bh/H_, h = bh%H_;
  int tid = threadIdx.x, lane = tid&63, wv = tid>>6;
  int lm = lane&15, lg = lane>>4;
  __shared__ __align__(16) unsigned short KQ[208*64];
  __shared__ __align__(16) float P2T[32*212];
  __shared__ __align__(16) float PNT[24*200];
  __shared__ float KK[768];
  const unsigned short* Kbase = qkv + ((size_t)(b*N_)*3 + 1)*C_ + h*CH_;
  const unsigned short* Qbase = qkv + ((size_t)(b*N_)*3 + 0)*C_ + h*CH_;
  for(int idx = tid; idx < 208*32; idx += 512){
    int k = idx>>5, cp = idx&31;
    unsigned v = (k < N_) ? *(const unsigned*)(Kbase + (size_t)k*3*C_ + cp*2) : 0u;
    unsigned off = (unsigned)(k*128 + cp*4) ^ ((unsigned)(k&7)<<4);
    *(unsigned*)((char*)KQ + off) = v;
  }
  for(int idx = tid; idx < 24*200; idx += 512){
    int r = idx/200, n = idx - r*200;
    PNT[idx] = (n < N_) ? proj_n[n*24+r] : 0.f;
  }
  __syncthreads();
  {
    short8 bfr[2][2];
    #pragma unroll
    for(int j=0;j<2;++j)
      #pragma unroll
      for(int s=0;s<2;++s)
        bfr[j][s] = *(const short8*)(WckT + (j*16+lm)*64 + s*32 + lg*8);
    float bias[2] = { bck[lm], bck[16+lm] };
    for(int t=wv; t<13; t+=8){
      int row = t*16 + lm;
      unsigned o0 = (unsigned)(row*128 + lg*16) ^ ((unsigned)(row&7)<<4);
      unsigned o1 = (unsigned)(row*128 + 64 + lg*16) ^ ((unsigned)(row&7)<<4);
      short8 a0 = *(const short8*)((char*)KQ + o0);
      short8 a1 = *(const short8*)((char*)KQ + o1);
      #pragma unroll
      for(int j=0;j<2;++j){
        f32x4 acc = (f32x4){0.f,0.f,0.f,0.f};
        acc = __builtin_amdgcn_mfma_f32_16x16x32_bf16(a0, bfr[j][0], acc, 0,0,0);
        acc = __builtin_amdgcn_mfma_f32_16x16x32_bf16(a1, bfr[j][1], acc, 0,0,0);
        #pragma unroll
        for(int r=0;r<4;++r)
          P2T[(j*16+lm)*212 + t*16 + lg*4 + r] = acc[r] + bias[j];
      }
    }
  }
  __syncthreads();
  {
    int i0 = tid, i1 = tid + 512;
    bool has1 = (i1 < 768);
    int c0 = i0/24, r0 = i0 - c0*24;
    int c1 = has1 ? i1/24 : 0, r1 = has1 ? (i1 - (i1/24)*24) : 0;
    float a0=0.f, a1=0.f;
    for(int n=0;n<200;n+=4){
      float4 x0 = *(const float4*)&P2T[c0*212+n];
      float4 p0 = *(const float4*)&PNT[r0*200+n];
      a0 += x0.x*p0.x; a0 += x0.y*p0.y; a0 += x0.z*p0.z; a0 += x0.w*p0.w;
      if(has1){
        float4 x1 = *(const float4*)&P2T[c1*212+n];
        float4 p1 = *(const float4*)&PNT[r1*200+n];
        a1 += x1.x*p1.x; a1 += x1.y*p1.y; a1 += x1.z*p1.z; a1 += x1.w*p1.w;
      }
    }
    KK[i0] = a0;
    if(has1) KK[i1] = a1;
    for(int idx = tid; idx < 197*32; idx += 512){
      int k = idx>>5, cp = idx&31;
      unsigned v = *(const unsigned*)(Qbase + (size_t)k*3*C_ + cp*2);
      unsigned off = (unsigned)(k*128 + cp*4) ^ ((unsigned)(k&7)<<4);
      *(unsigned*)((char*)KQ + off) = v;
    }
  }
  __syncthreads();
  float* QP = P2T;
  {
    short8 bfr[2][2];
    #pragma unroll
    for(int j=0;j<2;++j)
      #pragma unroll
      for(int s=0;s<2;++s)
        bfr[j][s] = *(const short8*)(WcqT + (j*16+lm)*64 + s*32 + lg*8);
    float bias[2] = { bcq[lm], bcq[16+lm] };
    for(int t=wv; t<13; t+=8){
      int row = t*16 + lm;
      unsigned o0 = (unsigned)(row*128 + lg*16) ^ ((unsigned)(row&7)<<4);
      unsigned o1 = (unsigned)(row*128 + 64 + lg*16) ^ ((unsigned)(row&7)<<4);
      short8 a0 = *(const short8*)((char*)KQ + o0);
      short8 a1 = *(const short8*)((char*)KQ + o1);
      #pragma unroll
      for(int j=0;j<2;++j){
        f32x4 acc = (f32x4){0.f,0.f,0.f,0.f};
        acc = __builtin_amdgcn_mfma_f32_16x16x32_bf16(a0, bfr[j][0], acc, 0,0,0);
        acc = __builtin_amdgcn_mfma_f32_16x16x32_bf16(a1, bfr[j][1], acc, 0,0,0);
        #pragma unroll
        for(int r=0;r<4;++r)
          QP[(t*16 + lg*4 + r)*32 + j*16 + lm] = acc[r] + bias[j];
      }
    }
  }
  __syncthreads();
  int l32 = lane & 31, half = lane >> 5;
  bool act = l32 < RN_;
  int ll = act ? l32 : 0;
  float kkreg[32];
  #pragma unroll
  for(int c=0;c<32;++c) kkreg[c] = KK[c*24 + ll];
  for(int i2 = wv*2; i2 < 196; i2 += 16){
    int i = i2 + half;
    int n = i + 1;
    float accv = 0.f;
    #pragma unroll
    for(int q=0;q<8;++q){
      float4 v4 = *(const float4*)&QP[n*32 + q*4];
      accv += v4.x*kkreg[q*4];   accv += v4.y*kkreg[q*4+1];
      accv += v4.z*kkreg[q*4+2]; accv += v4.w*kkreg[q*4+3];
    }
    float val = act ? accv * 0.28867513459481287f : -INFINITY;
    float m = val;
    #pragma unroll
    for(int o=16;o>=1;o>>=1) m = fmaxf(m, __shfl_xor(m, o));
    float e = act ? expf(val - m) : 0.f;
    float ssum = e;
    #pragma unroll
    for(int o=16;o>=1;o>>=1) ssum += __shfl_xor(ssum, o);
    float p = e/ssum;
    unsigned u = __float_as_uint(e);
    unsigned pL=0, pH=0;
    #pragma unroll
    for(int bit=30; bit>=0; --bit){
      unsigned tL = pL | (1u<<bit), tH = pH | (1u<<bit);
      unsigned thr = half ? tH : tL;
      unsigned long long bal = __ballot(u >= thr);
      int cL = __popcll(bal & 0xFFFFFFull);
      int cH = __popcll((bal>>32) & 0xFFFFFFull);
      if(cL>=8) pL=tL;
      if(cH>=8) pH=tH;
    }
    unsigned myp = half ? pH : pL;
    if(act) coef[((size_t)bh*196 + i)*24 + l32] = (u >= myp) ? p : 0.f;
  }
}

// ---------------- basis[r][j] = thresh(|proj_back_n[j][r]|) ----------------
__global__ __launch_bounds__(256) void basis_kernel(const float* __restrict__ pb,
    float* __restrict__ basis){
  int t = blockIdx.x*256 + threadIdx.x;
  if(t < RN_*N_){
    int r = t/N_, j = t%N_;
    float v = fabsf(pb[(size_t)j*RN_ + r]);
    basis[t] = (v > 0.02f) ? v : 0.f;
  }
}

// ---------------- mask v8: 8 rows/wave + per-row ballot SKIP once done ----------------
__global__ __launch_bounds__(256) void mask8_kernel(const float* __restrict__ coef,
    const float* __restrict__ basis, unsigned int* __restrict__ maskw){
  __shared__ float Bs[24*256];
  int tid = threadIdx.x, lane = tid&63, wv = tid>>6;
  for(int idx = tid; idx < 24*256; idx += 256){
    int r = idx>>8, q = idx&255;
    int e = ((q&3)<<6) | (q>>2);
    Bs[idx] = (e < N_) ? basis[r*N_ + e] : 0.f;
  }
  __syncthreads();
  int rowbase = blockIdx.x*32 + wv*8;
  float4 av[8];
  unsigned done = 0;
  #pragma unroll
  for(int j=0;j<8;++j){
    int row = rowbase + j;
    int qi = row % N_; int bh = row / N_;
    if(qi==0){
      if(lane<8){
        unsigned v = (lane<6)?0xFFFFFFFFu:((lane==6)?0x1Fu:0u);
        maskw[(size_t)row*8+lane]=v;
      }
      av[j] = make_float4(0.f,0.f,0.f,0.f);
      done |= (1u<<j);
    } else {
      float cfv = (lane<24) ? coef[((size_t)bh*196 + (qi-1))*24 + lane] : 0.f;
      unsigned long long nz = __ballot(cfv != 0.f);
      float4 a = make_float4(0.f,0.f,0.f,0.f);
      while(nz){
        int r = __ffsll((unsigned long long)nz) - 1;
        nz &= nz - 1;
        float c = __uint_as_float(__builtin_amdgcn_readlane(__float_as_uint(cfv), r));
        float4 bv = *(const float4*)&Bs[r*256 + lane*4];
        a.x += c*bv.x; a.y += c*bv.y; a.z += c*bv.z; a.w += c*bv.w;
      }
      av[j] = a;
    }
  }
  unsigned u[8][4];
  #pragma unroll
  for(int j=0;j<8;++j){
    u[j][0]=__float_as_uint(av[j].x); u[j][1]=__float_as_uint(av[j].y);
    u[j][2]=__float_as_uint(av[j].z); u[j][3]=__float_as_uint(av[j].w);
  }
  unsigned prefix[8] = {0,0,0,0,0,0,0,0};
  for(int bit=30; bit>=0; --bit){
    if(done == 0xFFu) break;
    #pragma unroll
    for(int j=0;j<8;++j){
      if((done>>j)&1u) continue;
      unsigned t = prefix[j] | (1u<<bit);
      int c = __popcll(__ballot(u[j][0] >= t)) + __popcll(__ballot(u[j][1] >= t))
            + __popcll(__ballot(u[j][2] >= t)) + __popcll(__ballot(u[j][3] >= t));
      if(c >= 50) prefix[j] = t;
      if(c == 50) done |= (1u<<j);
    }
  }
  #pragma unroll
  for(int j=0;j<8;++j){
    int row = rowbase + j;
    if(row % N_ == 0) continue;
    #pragma unroll
    for(int r=0;r<4;++r){
      bool valid = (r<3) | (lane<5);
      bool keep = valid && (u[j][r] >= prefix[j]);
      unsigned long long bal = __ballot(keep);
      if(lane==0){
        maskw[(size_t)row*8 + 2*r]   = (unsigned)(bal & 0xFFFFFFFFull);
        maskw[(size_t)row*8 + 2*r+1] = (unsigned)(bal>>32);
      }
    }
  }
}

// ---------------- masked attention v3: MFMA flash-style, one block per (b,h) ----------------
__global__ __launch_bounds__(512) void attn3_kernel(const unsigned short* __restrict__ qkv,
    const unsigned int* __restrict__ maskw, unsigned short* __restrict__ attn_out){
  int bh = blockIdx.x; int b = bh/H_, h = bh%H_;
  int tid = threadIdx.x, lane = tid&63, wv = tid>>6;
  int g = lane>>4, c16 = lane&15;
  __shared__ unsigned short Kb[208*64];
  __shared__ unsigned short Vt[64*220];
  __shared__ unsigned short Pl[8*16*224];
  __shared__ unsigned int   Ml[8][16][8];
  const unsigned short* Kbase = qkv + ((size_t)(b*N_)*3 + 1)*C_ + h*CH_;
  const unsigned short* Vbase = qkv + ((size_t)(b*N_)*3 + 2)*C_ + h*CH_;
  for(int idx = tid; idx < 208*32; idx += 512){
    int k = idx>>5, cp = idx&31;
    unsigned pk = 0;
    if(k < N_) pk = *(const unsigned*)(Kbase + (size_t)k*3*C_ + cp*2);
    unsigned off = (unsigned)(k*128 + cp*4) ^ ((unsigned)(k&7)<<4);
    *(unsigned*)((char*)Kb + off) = pk;
  }
  for(int idx = tid; idx < 64*110; idx += 512){
    int kp = idx>>6, c = idx&63;
    int k0 = kp*2, k1 = kp*2+1;
    unsigned v0 = (k0<N_) ? Vbase[(size_t)k0*3*C_ + c] : 0;
    unsigned v1 = (k1<N_) ? Vbase[(size_t)k1*3*C_ + c] : 0;
    *(unsigned*)((char*)Vt + c*440 + kp*4) = v0 | (v1<<16);
  }
  __syncthreads();
  size_t pbase = (size_t)wv*16*448;
  for(int i=lane;i<128;i+=64){
    int ql = i>>3; int kk = 208 + (i&7)*2;
    unsigned off = (unsigned)(ql*448 + kk*2) ^ ((unsigned)(ql&7)<<4);
    *(unsigned*)((char*)Pl + pbase + off) = 0u;
  }
  for(int t = wv; t < 13; t += 8){
    int qb = t*16;
    for(int i = lane; i < 128; i += 64){
      int row = i>>3, word = i&7;
      int qr = qb+row; if(qr>196) qr=196;
      Ml[wv][row][word] = maskw[(size_t)(bh*N_+qr)*8 + word];
    }
    int qrow = qb + c16; if(qrow>196) qrow=196;
    const unsigned short* Qr = qkv + ((size_t)(b*N_+qrow)*3)*C_ + h*CH_ + g*8;
    short8 af[2];
    af[0] = *(const short8*)(Qr);
    af[1] = *(const short8*)(Qr + 32);
    f32x4 sf[13];
    #pragma unroll
    for(int f=0;f<13;++f){
      sf[f] = (f32x4){0.f,0.f,0.f,0.f};
      #pragma unroll
      for(int s=0;s<2;++s){
        int row = f*16 + c16;
        unsigned off = (unsigned)(row*128 + s*64 + g*16) ^ ((unsigned)(row&7)<<4);
        short8 bfr = *(const short8*)((char*)Kb + off);
        sf[f] = __builtin_amdgcn_mfma_f32_16x16x32_bf16(af[s], bfr, sf[f], 0,0,0);
      }
      sf[f][0]*=0.125f; sf[f][1]*=0.125f; sf[f][2]*=0.125f; sf[f][3]*=0.125f;
    }
    unsigned keep[4] = {0,0,0,0};
    float m[4] = {-FLT_MAX,-FLT_MAX,-FLT_MAX,-FLT_MAX};
    #pragma unroll
    for(int f=0;f<13;++f)
      #pragma unroll
      for(int r=0;r<4;++r){
        unsigned bit = (Ml[wv][g*4+r][f>>1] >> ((f&1)*16 + c16)) & 1u;
        keep[r] |= bit<<f;
        if(bit) m[r] = fmaxf(m[r], sf[f][r]);
      }
    #pragma unroll
    for(int r=0;r<4;++r){
      #pragma unroll
      for(int o=8;o>=1;o>>=1) m[r] = fmaxf(m[r], __shfl_xor(m[r], o));
    }
    float sum[4] = {0,0,0,0};
    #pragma unroll
    for(int f=0;f<13;++f)
      #pragma unroll
      for(int r=0;r<4;++r){
        float e = ((keep[r]>>f)&1u) ? expf(sf[f][r]-m[r]) : 0.f;
        sf[f][r] = e; sum[r] += e;
      }
    #pragma unroll
    for(int r=0;r<4;++r){
      #pragma unroll
      for(int o=8;o>=1;o>>=1) sum[r] += __shfl_xor(sum[r], o);
      sum[r] = 1.f/sum[r];
    }
    #pragma unroll
    for(int f=0;f<13;++f)
      #pragma unroll
      for(int r=0;r<4;++r){
        int ql = g*4+r;
        unsigned off = (unsigned)(ql*448 + (f*16+c16)*2) ^ ((unsigned)(ql&7)<<4);
        *(unsigned short*)((char*)Pl + pbase + off) = f2bf(sf[f][r]*sum[r]);
      }
    #pragma unroll
    for(int ct=0;ct<4;++ct){
      f32x4 oa = (f32x4){0.f,0.f,0.f,0.f};
      #pragma unroll
      for(int ks=0;ks<7;++ks){
        unsigned offa = (unsigned)(c16*448 + (ks*32+g*8)*2) ^ ((unsigned)(c16&7)<<4);
        short8 pa = *(const short8*)((char*)Pl + pbase + offa);
        short8 vb = *(const short8*)((char*)Vt + (size_t)(ct*16+c16)*440 + (ks*32+g*8)*2);
        oa = __builtin_amdgcn_mfma_f32_16x16x32_bf16(pa, vb, oa, 0,0,0);
      }
      #pragma unroll
      for(int r=0;r<4;++r){
        int qq = qb + g*4 + r;
        if(qq < N_)
          attn_out[((size_t)(b*N_+qq))*C_ + h*CH_ + ct*16 + c16] = f2bf(oa[r]);
      }
    }
  }
}

extern "C" void kernel_launch(void* const* d_in, const int* in_sizes, int n_in,
                              void* d_out, int out_size, void* d_ws, size_t ws_size,
                              hipStream_t stream){
  const float* x    =(const float*)d_in[0];
  const float* Wqkv =(const float*)d_in[1];
  const float* Wcq  =(const float*)d_in[2];
  const float* bcq  =(const float*)d_in[3];
  const float* Wck  =(const float*)d_in[4];
  const float* bck  =(const float*)d_in[5];
  const float* proj_n=(const float*)d_in[6];
  const float* proj_back_n=(const float*)d_in[7];
  const float* Wproj=(const float*)d_in[8];
  const float* bproj=(const float*)d_in[9];
  const float* g1=(const float*)d_in[10];
  const float* b1=(const float*)d_in[11];
  const float* g2=(const float*)d_in[12];
  const float* b2=(const float*)d_in[13];
  const float* W1=(const float*)d_in[14];
  const float* bfc1=(const float*)d_in[15];
  const float* W2=(const float*)d_in[16];
  const float* bfc2=(const float*)d_in[17];
  float* out=(float*)d_out;

  float* ws=(float*)d_ws;
  size_t off=0;
  unsigned short* hbuf = (unsigned short*)(ws+off); off += (size_t)12608*768/2;
  size_t qkv_off = off;
  unsigned short* qkv = (unsigned short*)(ws+off); off += (size_t)12608*2304/2;
  off += (size_t)768*197*32;   // padding (hidden alias headroom)
  off += (size_t)768*197*32;
  off += (size_t)768*32*24;
  float* coef = ws+off;        off += (size_t)768*196*24;
  float* basis= ws+off;        off += 4736;
  unsigned int* maskw=(unsigned int*)(ws+off); off += (size_t)768*197*8;
  unsigned short* WqkvT = (unsigned short*)(ws+off); off += (size_t)2304*768/2;
  unsigned short* WprojT= (unsigned short*)(ws+off); off += (size_t)768*768/2;
  unsigned short* W1T   = (unsigned short*)(ws+off); off += (size_t)3072*768/2;
  unsigned short* W2T   = (unsigned short*)(ws+off); off += (size_t)768*3072/2;
  unsigned short* WcqT  = (unsigned short*)(ws+off); off += 1024;
  unsigned short* WckT  = (unsigned short*)(ws+off); off += 1024;
  unsigned short* attn_out = hbuf;                    // alias (hbuf dead after qkv GEMM)
  unsigned short* hidden = (unsigned short*)(ws+qkv_off); // alias (qkv dead by MLP)
  float* x1 = out;

  // 0. weight transpose+bf16 conversions
  wtrans_kernel<<<dim3(72,24),256,0,stream>>>(Wqkv, WqkvT, 768, 2304);
  wtrans_kernel<<<dim3(24,24),256,0,stream>>>(Wproj, WprojT, 768, 768);
  wtrans_kernel<<<dim3(96,24),256,0,stream>>>(W1, W1T, 768, 3072);
  wtrans_kernel<<<dim3(24,96),256,0,stream>>>(W2, W2T, 3072, 768);
  wcprep_kernel<<<8,256,0,stream>>>(Wcq, Wck, WcqT, WckT);
  // 1. h = LN(x) -> bf16
  ln_kernel<<<12608,256,0,stream>>>(x,g1,b1,hbuf);
  // 2. qkv = h @ Wqkv (bf16 out)
  gemm256_bf16<0,0,1><<<dim3(18,50),512,0,stream>>>(hbuf,WqkvT,nullptr,nullptr,qkv,12608,768,2304);
  // 3. fused cheap path v3 (MFMA kp/qp)
  cheap_kernel<<<768,512,0,stream>>>(qkv,WcqT,bcq,WckT,bck,proj_n,coef);
  // 4. basis
  basis_kernel<<<19,256,0,stream>>>(proj_back_n,basis);
  // 5. approx_attn + budget mask
  mask8_kernel<<<4728,256,0,stream>>>(coef,basis,maskw);
  // 6. masked attention (MFMA)
  attn3_kernel<<<768,512,0,stream>>>(qkv,maskw,attn_out);
  // 7. x1 = x + attn_out @ Wproj + bproj   (x1 == d_out) [64x128 tiles: 6 x 197]
  gemm64_bf16<0,1,0><<<dim3(6,197),256,0,stream>>>(attn_out,WprojT,bproj,x,x1,12608,768,768);
  // 8. h2 = LN(x1) -> bf16 (reuse hbuf)
  ln_kernel<<<12608,256,0,stream>>>(x1,g2,b2,hbuf);
  // 9. hidden = gelu(h2 @ W1 + bfc1) -> bf16
  gemm256_bf16<1,0,1><<<dim3(24,50),512,0,stream>>>(hbuf,W1T,bfc1,nullptr,hidden,12608,768,3072);
  // 10. out = x1 + hidden @ W2 + bfc2 [64x128 tiles: 6 x 197]
  gemm64_bf16<0,1,0><<<dim3(6,197),256,0,stream>>>(hidden,W2T,bfc2,x1,out,12608,3072,768);
}